// Round 1
// baseline (1089.297 us; speedup 1.0000x reference)
//
#include <hip/hip_runtime.h>
#include <math.h>

#define Bb 2
#define Tt 8
#define Cc 16
#define Hh 64
#define Ww 64
#define Dd 32
#define HID 128
#define WF 33
#define NPIX 4096
#define NIMG 256   // B*T*C

__device__ __forceinline__ float sp_f(float x) {           // softplus
    return (x > 20.f) ? x : log1pf(expf(x));
}
__device__ __forceinline__ float sigf(float z) { return 1.f / (1.f + expf(-z)); }

// ---------------- K1: x1 = x + conv3x3(x) + b (applied to re and im) ----------------
__global__ __launch_bounds__(256)
void k_conv(const float* __restrict__ xr, const float* __restrict__ xi,
            const float* __restrict__ cw, const float* __restrict__ cb,
            float2* __restrict__ x1) {
    int blk = blockIdx.x;
    int bt = blk >> 4;
    int tile = blk & 15;
    int ty0 = (tile >> 2) * 16, tx0 = (tile & 3) * 16;
    __shared__ float sre[Cc][18][18];
    __shared__ float sim[Cc][18][18];
    __shared__ float swt[Cc * Cc * 9];
    __shared__ float sb[Cc];
    int tid = threadIdx.x;
    for (int i = tid; i < Cc * Cc * 9; i += 256) swt[i] = cw[i];
    if (tid < Cc) sb[tid] = cb[tid];
    for (int i = tid; i < Cc * 18 * 18; i += 256) {
        int ci = i / 324; int r = i % 324; int y = r / 18, x = r % 18;
        int gy = ty0 + y - 1, gx = tx0 + x - 1;
        float vr = 0.f, vi = 0.f;
        if (gy >= 0 && gy < Hh && gx >= 0 && gx < Ww) {
            int gidx = (bt * Cc + ci) * NPIX + gy * Ww + gx;
            vr = xr[gidx]; vi = xi[gidx];
        }
        sre[ci][y][x] = vr; sim[ci][y][x] = vi;
    }
    __syncthreads();
    int py = tid >> 4, px = tid & 15;
    int gy = ty0 + py, gx = tx0 + px;
    for (int co = 0; co < Cc; ++co) {
        float bcv = sb[co];
        float ar = sre[co][py + 1][px + 1] + bcv;   // x itself + conv bias (re)
        float ai = sim[co][py + 1][px + 1] + bcv;   // conv bias also added to imag conv
        for (int ci = 0; ci < Cc; ++ci) {
            const float* wp = &swt[(co * Cc + ci) * 9];
            #pragma unroll
            for (int dy = 0; dy < 3; ++dy)
            #pragma unroll
            for (int dx = 0; dx < 3; ++dx) {
                float w = wp[dy * 3 + dx];
                ar += w * sre[ci][py + dy][px + dx];
                ai += w * sim[ci][py + dy][px + dx];
            }
        }
        x1[(bt * Cc + co) * NPIX + gy * Ww + gx] = make_float2(ar, ai);
    }
}

// ---------------- 64-point in-LDS FFT (DIF + bit reversal). twiddles encode direction. ----
__device__ void fft64(float* re, float* im, int base, int stride,
                      const float* twr, const float* twi) {
    for (int s = 0; s < 6; ++s) {
        const int hm = 32 >> s;
        const int m = 64 >> s;
        for (int g0 = 0; g0 < 64; g0 += m) {
            for (int j = 0; j < hm; ++j) {
                const int i1 = base + (g0 + j) * stride;
                const int i2 = i1 + hm * stride;
                float ar = re[i1], ai = im[i1];
                float br = re[i2], bi = im[i2];
                re[i1] = ar + br; im[i1] = ai + bi;
                float tr = ar - br, ti = ai - bi;
                float wr = twr[j << s], wi = twi[j << s];
                re[i2] = tr * wr - ti * wi;
                im[i2] = tr * wi + ti * wr;
            }
        }
    }
    for (int k = 1; k < 64; ++k) {
        int r = (int)(__brev((unsigned)k) >> 26);
        if (r > k) {
            int ik = base + k * stride, ir = base + r * stride;
            float t = re[ik]; re[ik] = re[ir]; re[ir] = t;
            t = im[ik]; im[ik] = im[ir]; im[ir] = t;
        }
    }
}

// ---------------- K2: X2f = fft2_std(x1) * (1 + filt) ----------------
__global__ __launch_bounds__(64)
void k_fft_fwd(const float2* __restrict__ x1,
               const float* __restrict__ spec_re, const float* __restrict__ spec_im,
               float2* __restrict__ X2f) {
    int img = blockIdx.x;                 // ((b*T+t)*C + c)
    int c = img % Cc;
    int tid = threadIdx.x;
    __shared__ float re[64 * 65], im[64 * 65];
    __shared__ float twr[32], twi[32];
    if (tid < 32) {
        float ang = -0.098174770424681038798f * (float)tid;  // -2*pi*t/64
        twr[tid] = cosf(ang); twi[tid] = sinf(ang);
    }
    const float2* src = x1 + (size_t)img * NPIX;
    for (int idx = tid; idx < NPIX; idx += 64) {
        int h = idx >> 6, w = idx & 63;
        float2 v = src[idx];
        re[h * 65 + w] = v.x; im[h * 65 + w] = v.y;
    }
    __syncthreads();
    fft64(re, im, tid * 65, 1, twr, twi);
    __syncthreads();
    fft64(re, im, tid, 65, twr, twi);
    __syncthreads();
    const float* fr = spec_re + c * NPIX;
    const float* fi = spec_im + c * NPIX;
    float2* dst = X2f + (size_t)img * NPIX;
    for (int idx = tid; idx < NPIX; idx += 64) {
        int h = idx >> 6, w = idx & 63;
        float xr_ = re[h * 65 + w], xi_ = im[h * 65 + w];
        float gr = 1.f + fr[idx], gi = fi[idx];
        dst[idx] = make_float2(xr_ * gr - xi_ * gi, xi_ * gr + xr_ * gi);
    }
}

// ---------------- K3: Hermitian split + diagonal SSM scan over T (half-spectrum) -------
__global__ __launch_bounds__(256)
void k_scan(const float2* __restrict__ X2f,
            const float* __restrict__ lam_re, const float* __restrict__ lam_im,
            const float* __restrict__ dt_param, const float* __restrict__ dtp,
            float2* __restrict__ Gre, float2* __restrict__ Gim) {
    int id = blockIdx.x * 256 + threadIdx.x;
    const int NB = Bb * Cc * Hh * WF;     // 67584
    if (id >= NB) return;
    int w = id % WF; int r = id / WF;
    int h = r % Hh; r /= Hh;
    int c = r % Cc; int b = r / Cc;
    float dte = dtp[0] * sp_f(dt_param[c]);
    float ea = expf(-sp_f(lam_re[c]) * dte);
    float ph = lam_im[c] * dte;
    float Ar = ea * cosf(ph), Ai = ea * sinf(ph);
    int hm = (64 - h) & 63, wm = (64 - w) & 63;
    float gr_r = 0.f, gr_i = 0.f, gi_r = 0.f, gi_i = 0.f;
    for (int t = 0; t < Tt; ++t) {
        int ib = ((b * Tt + t) * Cc + c) * NPIX;
        float2 Z = X2f[ib + h * 64 + w];
        float2 Zm = X2f[ib + hm * 64 + wm];
        float ur_r = 0.5f * (Z.x + Zm.x), ur_i = 0.5f * (Z.y - Zm.y);
        float ui_r = 0.5f * (Z.y + Zm.y), ui_i = 0.5f * (Zm.x - Z.x);
        float nr = Ar * gr_r - Ai * gr_i + ur_r;
        float ni = Ar * gr_i + Ai * gr_r + ur_i;
        gr_r = nr; gr_i = ni;
        nr = Ar * gi_r - Ai * gi_i + ui_r;
        ni = Ar * gi_i + Ai * gi_r + ui_i;
        gi_r = nr; gi_i = ni;
        int ig = ((b * Tt + t) * Cc + c) * (Hh * WF) + h * WF + w;
        Gre[ig] = make_float2(gr_r, gr_i);
        Gim[ig] = make_float2(gi_r, gi_i);
    }
}

// ---------------- K4: S = X2f + HermitianExtend(sym(Gre) + i*sym(Gim)), in place -------
__global__ __launch_bounds__(256)
void k_assemble(float2* __restrict__ X2f,
                const float2* __restrict__ Gre, const float2* __restrict__ Gim) {
    int idx = blockIdx.x * 256 + threadIdx.x;     // < 1048576
    int pix = idx & (NPIX - 1); int img = idx >> 12;
    int h = pix >> 6, w = pix & 63;
    int hm = (64 - h) & 63;
    int base = img * (Hh * WF);
    float zr, zi;
    if (w <= 32) {
        float2 a = Gre[base + h * WF + w];
        float2 bb = Gim[base + h * WF + w];
        if (w == 0 || w == 32) {   // symmetrize self-conjugate columns (numpy irfft behavior)
            float2 a2 = Gre[base + hm * WF + w];
            float2 b2 = Gim[base + hm * WF + w];
            a = make_float2(0.5f * (a.x + a2.x), 0.5f * (a.y - a2.y));
            bb = make_float2(0.5f * (bb.x + b2.x), 0.5f * (bb.y - b2.y));
        }
        zr = a.x - bb.y; zi = a.y + bb.x;            // g_re + i*g_im
    } else {
        int wf = 64 - w;
        float2 a = Gre[base + hm * WF + wf];
        float2 bb = Gim[base + hm * WF + wf];
        zr = a.x + bb.y; zi = bb.x - a.y;            // conj(g_re) + i*conj(g_im)
    }
    float2 s = X2f[idx];
    X2f[idx] = make_float2(s.x + zr, s.y + zi);
}

// ---------------- K5: field = ifft2_std(S) + noise ----------------
__global__ __launch_bounds__(64)
void k_fft_inv(const float2* __restrict__ S,
               const float* __restrict__ noise_r, const float* __restrict__ noise_i,
               const float* __restrict__ sigma_p, const float* __restrict__ dtp,
               const float* __restrict__ dt_param,
               float2* __restrict__ xf) {
    int img = blockIdx.x; int tid = threadIdx.x;
    __shared__ float re[64 * 65], im[64 * 65];
    __shared__ float twr[32], twi[32];
    if (tid < 32) {
        float ang = 0.098174770424681038798f * (float)tid;   // +2*pi*t/64 (inverse)
        twr[tid] = cosf(ang); twi[tid] = sinf(ang);
    }
    const float2* src = S + (size_t)img * NPIX;
    for (int idx = tid; idx < NPIX; idx += 64) {
        int h = idx >> 6, w = idx & 63;
        float2 v = src[idx];
        re[h * 65 + w] = v.x; im[h * 65 + w] = v.y;
    }
    __syncthreads();
    fft64(re, im, tid * 65, 1, twr, twi);
    __syncthreads();
    fft64(re, im, tid, 65, twr, twi);
    __syncthreads();
    float dts = 0.f;
    for (int c = 0; c < Cc; ++c) dts += sp_f(dt_param[c]);
    dts = dtp[0] * dts * (1.f / Cc);
    float ns = sigma_p[0] * sqrtf(dts);
    const float inv = 1.f / 4096.f;
    float2* dst = xf + (size_t)img * NPIX;
    const float* nr = noise_r + (size_t)img * NPIX;
    const float* ni = noise_i + (size_t)img * NPIX;
    for (int idx = tid; idx < NPIX; idx += 64) {
        int h = idx >> 6, w = idx & 63;
        dst[idx] = make_float2(re[h * 65 + w] * inv + ns * nr[idx],
                               im[h * 65 + w] * inv + ns * ni[idx]);
    }
}

// ---------------- K6: Port-Hamiltonian layer ----------------
__global__ __launch_bounds__(256, 1)
void k_ph(const float2* __restrict__ xf,
          const float* __restrict__ ln_g, const float* __restrict__ ln_b,
          const float* __restrict__ W1, const float* __restrict__ b1,
          const float* __restrict__ w2,
          const float* __restrict__ JgW, const float* __restrict__ Jgb,
          const float* __restrict__ RgW, const float* __restrict__ Rgb,
          const float* __restrict__ dtp, const float* __restrict__ dt_param,
          float* __restrict__ out) {
    __shared__ float g_s[Dd * 256];     // grads, runtime-indexable per row
    __shared__ float t_s[Dd * 256];     // mg during M pass, then pg during P passes
    int tid = threadIdx.x;
    int bt = blockIdx.x >> 4;
    int pix = ((blockIdx.x & 15) << 8) + tid;
    const float2* src = xf + (size_t)bt * (Cc * NPIX);

    float x[Dd];
    #pragma unroll
    for (int c = 0; c < Cc; ++c) {
        float2 v = src[c * NPIX + pix];
        x[c] = v.x; x[c + Cc] = v.y;
    }
    float mu = 0.f;
    #pragma unroll
    for (int d = 0; d < Dd; ++d) mu += x[d];
    mu *= 0.03125f;
    float var = 0.f;
    #pragma unroll
    for (int d = 0; d < Dd; ++d) { float t = x[d] - mu; var += t * t; }
    var *= 0.03125f;
    float rs = rsqrtf(var + 1e-5f);
    float xin[Dd];
    #pragma unroll
    for (int d = 0; d < Dd; ++d) xin[d] = (x[d] - mu) * rs * ln_g[d] + ln_b[d];

    // grads of potential: g = W1 @ (silu'(xin@W1+b1) * w2)
    float g[Dd];
    #pragma unroll
    for (int d = 0; d < Dd; ++d) g[d] = 0.f;
    const float4* W14 = (const float4*)W1;
    for (int h4 = 0; h4 < HID / 4; ++h4) {
        float z0 = b1[h4 * 4 + 0], z1 = b1[h4 * 4 + 1], z2 = b1[h4 * 4 + 2], z3 = b1[h4 * 4 + 3];
        #pragma unroll
        for (int d = 0; d < Dd; ++d) {
            float4 wv = W14[d * (HID / 4) + h4];
            z0 += xin[d] * wv.x; z1 += xin[d] * wv.y; z2 += xin[d] * wv.z; z3 += xin[d] * wv.w;
        }
        float s0 = sigf(z0), s1 = sigf(z1), s2 = sigf(z2), s3 = sigf(z3);
        float t0 = s0 * (1.f + z0 * (1.f - s0)) * w2[h4 * 4 + 0];
        float t1 = s1 * (1.f + z1 * (1.f - s1)) * w2[h4 * 4 + 1];
        float t2 = s2 * (1.f + z2 * (1.f - s2)) * w2[h4 * 4 + 2];
        float t3 = s3 * (1.f + z3 * (1.f - s3)) * w2[h4 * 4 + 3];
        #pragma unroll
        for (int d = 0; d < Dd; ++d) {
            float4 wv = W14[d * (HID / 4) + h4];
            g[d] += t0 * wv.x + t1 * wv.y + t2 * wv.z + t3 * wv.w;
        }
    }
    #pragma unroll
    for (int d = 0; d < Dd; ++d) g_s[d * 256 + tid] = g[d];

    float upd[Dd];
    #pragma unroll
    for (int d = 0; d < Dd; ++d) upd[d] = -1e-4f * g[d];

    const float4* Jg4 = (const float4*)JgW;
    const float4* Rg4 = (const float4*)RgW;

    // ---- M pass: upd[i] += (Mg)_i ; upd[j] -= M_ij * g_i ----
    for (int i = 0; i < Dd; ++i) {
        float m[Dd];
        #pragma unroll
        for (int j = 0; j < Dd; ++j) m[j] = Jgb[i * Dd + j];
        #pragma unroll
        for (int d = 0; d < Dd; ++d) {
            float xd = xin[d];
            #pragma unroll
            for (int j4 = 0; j4 < Dd / 4; ++j4) {
                float4 wv = Jg4[(d * 1024 + i * Dd) / 4 + j4];
                m[j4 * 4 + 0] += xd * wv.x; m[j4 * 4 + 1] += xd * wv.y;
                m[j4 * 4 + 2] += xd * wv.z; m[j4 * 4 + 3] += xd * wv.w;
            }
        }
        float gi = g_s[i * 256 + tid];
        float dot = 0.f;
        #pragma unroll
        for (int j = 0; j < Dd; ++j) { dot += m[j] * g[j]; upd[j] -= m[j] * gi; }
        t_s[i * 256 + tid] = dot;
    }
    #pragma unroll
    for (int i = 0; i < Dd; ++i) upd[i] += t_s[i * 256 + tid];   // consume mg, free t_s

    // ---- P pass 1: pg_k = (Pg)_k ----
    for (int k = 0; k < Dd; ++k) {
        float p[Dd];
        #pragma unroll
        for (int j = 0; j < Dd; ++j) p[j] = Rgb[k * Dd + j];
        #pragma unroll
        for (int d = 0; d < Dd; ++d) {
            float xd = xin[d];
            #pragma unroll
            for (int j4 = 0; j4 < Dd / 4; ++j4) {
                float4 wv = Rg4[(d * 1024 + k * Dd) / 4 + j4];
                p[j4 * 4 + 0] += xd * wv.x; p[j4 * 4 + 1] += xd * wv.y;
                p[j4 * 4 + 2] += xd * wv.z; p[j4 * 4 + 3] += xd * wv.w;
            }
        }
        float dot = 0.f;
        #pragma unroll
        for (int j = 0; j < Dd; ++j) dot += p[j] * g[j];
        t_s[k * 256 + tid] = dot;
    }
    // ---- P pass 2: upd[j] -= P_kj * pg_k ----
    for (int k = 0; k < Dd; ++k) {
        float p[Dd];
        #pragma unroll
        for (int j = 0; j < Dd; ++j) p[j] = Rgb[k * Dd + j];
        #pragma unroll
        for (int d = 0; d < Dd; ++d) {
            float xd = xin[d];
            #pragma unroll
            for (int j4 = 0; j4 < Dd / 4; ++j4) {
                float4 wv = Rg4[(d * 1024 + k * Dd) / 4 + j4];
                p[j4 * 4 + 0] += xd * wv.x; p[j4 * 4 + 1] += xd * wv.y;
                p[j4 * 4 + 2] += xd * wv.z; p[j4 * 4 + 3] += xd * wv.w;
            }
        }
        float pk = t_s[k * 256 + tid];
        #pragma unroll
        for (int j = 0; j < Dd; ++j) upd[j] -= p[j] * pk;
    }

    float dts = 0.f;
    for (int c = 0; c < Cc; ++c) dts += sp_f(dt_param[c]);
    dts = dtp[0] * dts * (1.f / Cc);

    float* o = out + (size_t)bt * (Dd * NPIX);
    #pragma unroll
    for (int c = 0; c < Cc; ++c) {
        float2 v = src[c * NPIX + pix];
        o[c * NPIX + pix] = v.x + dts * upd[c];
        o[(c + Cc) * NPIX + pix] = v.y + dts * upd[c + Cc];
    }
}

extern "C" void kernel_launch(void* const* d_in, const int* in_sizes, int n_in,
                              void* d_out, int out_size, void* d_ws, size_t ws_size,
                              hipStream_t stream) {
    const float* x_real   = (const float*)d_in[0];
    const float* x_imag   = (const float*)d_in[1];
    const float* dt       = (const float*)d_in[2];
    const float* conv_w   = (const float*)d_in[3];
    const float* conv_b   = (const float*)d_in[4];
    const float* spec_re  = (const float*)d_in[5];
    const float* spec_im  = (const float*)d_in[6];
    const float* lam_re   = (const float*)d_in[7];
    const float* lam_im   = (const float*)d_in[8];
    const float* dt_param = (const float*)d_in[9];
    const float* sigma    = (const float*)d_in[10];
    const float* noise_r  = (const float*)d_in[11];
    const float* noise_i  = (const float*)d_in[12];
    const float* ln_g     = (const float*)d_in[13];
    const float* ln_b     = (const float*)d_in[14];
    const float* W1       = (const float*)d_in[15];
    const float* b1       = (const float*)d_in[16];
    const float* w2       = (const float*)d_in[17];
    // d_in[18] = b2 (unused: constant in potential, no gradient)
    const float* Jg_W     = (const float*)d_in[19];
    const float* Jg_b     = (const float*)d_in[20];
    const float* Rg_W     = (const float*)d_in[21];
    const float* Rg_b     = (const float*)d_in[22];

    float2* wsA = (float2*)d_ws;              // x1, later final field (1048576 float2)
    float2* wsB = wsA + 1048576;              // X2f / assembled spectrum
    float2* wsC = wsB + 1048576;              // Gre (540672 float2)
    float2* wsD = wsC + 540672;               // Gim

    k_conv<<<256, 256, 0, stream>>>(x_real, x_imag, conv_w, conv_b, wsA);
    k_fft_fwd<<<NIMG, 64, 0, stream>>>(wsA, spec_re, spec_im, wsB);
    k_scan<<<264, 256, 0, stream>>>(wsB, lam_re, lam_im, dt_param, dt, wsC, wsD);
    k_assemble<<<4096, 256, 0, stream>>>(wsB, wsC, wsD);
    k_fft_inv<<<NIMG, 64, 0, stream>>>(wsB, noise_r, noise_i, sigma, dt, dt_param, wsA);
    k_ph<<<256, 256, 0, stream>>>(wsA, ln_g, ln_b, W1, b1, w2,
                                  Jg_W, Jg_b, Rg_W, Rg_b, dt, dt_param, (float*)d_out);
}

// Round 2
// 311.467 us; speedup vs baseline: 3.4973x; 3.4973x over previous
//
#include <hip/hip_runtime.h>
#include <math.h>

#define Bb 2
#define Tt 8
#define Cc 16
#define Hh 64
#define Ww 64
#define Dd 32
#define HID 128
#define WF 33
#define NPIX 4096
#define NIMG 256   // B*T*C

typedef unsigned short ushort_t;
typedef unsigned int uint_t;
typedef __attribute__((ext_vector_type(8))) short short8;
typedef __attribute__((ext_vector_type(4))) float f32x4;
union U16 { uint4 u; short8 s; };

__device__ __forceinline__ float sp_f(float x) {           // softplus
    return (x > 20.f) ? x : log1pf(expf(x));
}
__device__ __forceinline__ float sigf(float z) { return 1.f / (1.f + expf(-z)); }

__device__ __forceinline__ ushort_t f2bf(float f) {        // round-to-nearest-even
    uint_t u = __float_as_uint(f);
    uint_t r = (u + 0x7fffu + ((u >> 16) & 1u)) >> 16;
    return (ushort_t)r;
}
__device__ __forceinline__ float bf2f(ushort_t h) { return __uint_as_float(((uint_t)h) << 16); }

// multiply packed pair of bf16 by scalar, repack (truncation)
__device__ __forceinline__ uint_t mulpack(uint_t gpair, float xf) {
    float lo = __uint_as_float(gpair << 16) * xf;
    float hi = __uint_as_float(gpair & 0xffff0000u) * xf;
    return (__float_as_uint(hi) & 0xffff0000u) | (__float_as_uint(lo) >> 16);
}

#define MFMA16(a, b, c) __builtin_amdgcn_mfma_f32_16x16x32_bf16((a), (b), (c), 0, 0, 0)

// ---------------- K1: x1 = x + conv3x3(x) + b (applied to re and im) ----------------
__global__ __launch_bounds__(256)
void k_conv(const float* __restrict__ xr, const float* __restrict__ xi,
            const float* __restrict__ cw, const float* __restrict__ cb,
            float2* __restrict__ x1) {
    int blk = blockIdx.x;
    int bt = blk >> 4;
    int tile = blk & 15;
    int ty0 = (tile >> 2) * 16, tx0 = (tile & 3) * 16;
    __shared__ float sre[Cc][18][18];
    __shared__ float sim[Cc][18][18];
    __shared__ float swt[Cc * Cc * 9];
    __shared__ float sb[Cc];
    int tid = threadIdx.x;
    for (int i = tid; i < Cc * Cc * 9; i += 256) swt[i] = cw[i];
    if (tid < Cc) sb[tid] = cb[tid];
    for (int i = tid; i < Cc * 18 * 18; i += 256) {
        int ci = i / 324; int r = i % 324; int y = r / 18, x = r % 18;
        int gy = ty0 + y - 1, gx = tx0 + x - 1;
        float vr = 0.f, vi = 0.f;
        if (gy >= 0 && gy < Hh && gx >= 0 && gx < Ww) {
            int gidx = (bt * Cc + ci) * NPIX + gy * Ww + gx;
            vr = xr[gidx]; vi = xi[gidx];
        }
        sre[ci][y][x] = vr; sim[ci][y][x] = vi;
    }
    __syncthreads();
    int py = tid >> 4, px = tid & 15;
    int gy = ty0 + py, gx = tx0 + px;
    for (int co = 0; co < Cc; ++co) {
        float bcv = sb[co];
        float ar = sre[co][py + 1][px + 1] + bcv;
        float ai = sim[co][py + 1][px + 1] + bcv;
        for (int ci = 0; ci < Cc; ++ci) {
            const float* wp = &swt[(co * Cc + ci) * 9];
            #pragma unroll
            for (int dy = 0; dy < 3; ++dy)
            #pragma unroll
            for (int dx = 0; dx < 3; ++dx) {
                float w = wp[dy * 3 + dx];
                ar += w * sre[ci][py + dy][px + dx];
                ai += w * sim[ci][py + dy][px + dx];
            }
        }
        x1[(bt * Cc + co) * NPIX + gy * Ww + gx] = make_float2(ar, ai);
    }
}

// ---------------- 64-point in-LDS FFT (DIF + bit reversal). twiddles encode direction. ----
__device__ void fft64(float* re, float* im, int base, int stride,
                      const float* twr, const float* twi) {
    for (int s = 0; s < 6; ++s) {
        const int hm = 32 >> s;
        const int m = 64 >> s;
        for (int g0 = 0; g0 < 64; g0 += m) {
            for (int j = 0; j < hm; ++j) {
                const int i1 = base + (g0 + j) * stride;
                const int i2 = i1 + hm * stride;
                float ar = re[i1], ai = im[i1];
                float br = re[i2], bi = im[i2];
                re[i1] = ar + br; im[i1] = ai + bi;
                float tr = ar - br, ti = ai - bi;
                float wr = twr[j << s], wi = twi[j << s];
                re[i2] = tr * wr - ti * wi;
                im[i2] = tr * wi + ti * wr;
            }
        }
    }
    for (int k = 1; k < 64; ++k) {
        int r = (int)(__brev((unsigned)k) >> 26);
        if (r > k) {
            int ik = base + k * stride, ir = base + r * stride;
            float t = re[ik]; re[ik] = re[ir]; re[ir] = t;
            t = im[ik]; im[ik] = im[ir]; im[ir] = t;
        }
    }
}

// ---------------- K2: X2f = fft2_std(x1) * (1 + filt) ----------------
__global__ __launch_bounds__(64)
void k_fft_fwd(const float2* __restrict__ x1,
               const float* __restrict__ spec_re, const float* __restrict__ spec_im,
               float2* __restrict__ X2f) {
    int img = blockIdx.x;
    int c = img % Cc;
    int tid = threadIdx.x;
    __shared__ float re[64 * 65], im[64 * 65];
    __shared__ float twr[32], twi[32];
    if (tid < 32) {
        float ang = -0.098174770424681038798f * (float)tid;
        twr[tid] = cosf(ang); twi[tid] = sinf(ang);
    }
    const float2* src = x1 + (size_t)img * NPIX;
    for (int idx = tid; idx < NPIX; idx += 64) {
        int h = idx >> 6, w = idx & 63;
        float2 v = src[idx];
        re[h * 65 + w] = v.x; im[h * 65 + w] = v.y;
    }
    __syncthreads();
    fft64(re, im, tid * 65, 1, twr, twi);
    __syncthreads();
    fft64(re, im, tid, 65, twr, twi);
    __syncthreads();
    const float* fr = spec_re + c * NPIX;
    const float* fi = spec_im + c * NPIX;
    float2* dst = X2f + (size_t)img * NPIX;
    for (int idx = tid; idx < NPIX; idx += 64) {
        int h = idx >> 6, w = idx & 63;
        float xr_ = re[h * 65 + w], xi_ = im[h * 65 + w];
        float gr = 1.f + fr[idx], gi = fi[idx];
        dst[idx] = make_float2(xr_ * gr - xi_ * gi, xi_ * gr + xr_ * gi);
    }
}

// ---------------- K3: Hermitian split + diagonal SSM scan over T (half-spectrum) -------
__global__ __launch_bounds__(256)
void k_scan(const float2* __restrict__ X2f,
            const float* __restrict__ lam_re, const float* __restrict__ lam_im,
            const float* __restrict__ dt_param, const float* __restrict__ dtp,
            float2* __restrict__ Gre, float2* __restrict__ Gim) {
    int id = blockIdx.x * 256 + threadIdx.x;
    const int NB = Bb * Cc * Hh * WF;
    if (id >= NB) return;
    int w = id % WF; int r = id / WF;
    int h = r % Hh; r /= Hh;
    int c = r % Cc; int b = r / Cc;
    float dte = dtp[0] * sp_f(dt_param[c]);
    float ea = expf(-sp_f(lam_re[c]) * dte);
    float ph = lam_im[c] * dte;
    float Ar = ea * cosf(ph), Ai = ea * sinf(ph);
    int hm = (64 - h) & 63, wm = (64 - w) & 63;
    float gr_r = 0.f, gr_i = 0.f, gi_r = 0.f, gi_i = 0.f;
    for (int t = 0; t < Tt; ++t) {
        int ib = ((b * Tt + t) * Cc + c) * NPIX;
        float2 Z = X2f[ib + h * 64 + w];
        float2 Zm = X2f[ib + hm * 64 + wm];
        float ur_r = 0.5f * (Z.x + Zm.x), ur_i = 0.5f * (Z.y - Zm.y);
        float ui_r = 0.5f * (Z.y + Zm.y), ui_i = 0.5f * (Zm.x - Z.x);
        float nr = Ar * gr_r - Ai * gr_i + ur_r;
        float ni = Ar * gr_i + Ai * gr_r + ur_i;
        gr_r = nr; gr_i = ni;
        nr = Ar * gi_r - Ai * gi_i + ui_r;
        ni = Ar * gi_i + Ai * gi_r + ui_i;
        gi_r = nr; gi_i = ni;
        int ig = ((b * Tt + t) * Cc + c) * (Hh * WF) + h * WF + w;
        Gre[ig] = make_float2(gr_r, gr_i);
        Gim[ig] = make_float2(gi_r, gi_i);
    }
}

// ---------------- K4: S = X2f + HermitianExtend(sym(Gre) + i*sym(Gim)), in place -------
__global__ __launch_bounds__(256)
void k_assemble(float2* __restrict__ X2f,
                const float2* __restrict__ Gre, const float2* __restrict__ Gim) {
    int idx = blockIdx.x * 256 + threadIdx.x;
    int pix = idx & (NPIX - 1); int img = idx >> 12;
    int h = pix >> 6, w = pix & 63;
    int hm = (64 - h) & 63;
    int base = img * (Hh * WF);
    float zr, zi;
    if (w <= 32) {
        float2 a = Gre[base + h * WF + w];
        float2 bb = Gim[base + h * WF + w];
        if (w == 0 || w == 32) {
            float2 a2 = Gre[base + hm * WF + w];
            float2 b2 = Gim[base + hm * WF + w];
            a = make_float2(0.5f * (a.x + a2.x), 0.5f * (a.y - a2.y));
            bb = make_float2(0.5f * (bb.x + b2.x), 0.5f * (bb.y - b2.y));
        }
        zr = a.x - bb.y; zi = a.y + bb.x;
    } else {
        int wf = 64 - w;
        float2 a = Gre[base + hm * WF + wf];
        float2 bb = Gim[base + hm * WF + wf];
        zr = a.x + bb.y; zi = bb.x - a.y;
    }
    float2 s = X2f[idx];
    X2f[idx] = make_float2(s.x + zr, s.y + zi);
}

// ---------------- K5: field = ifft2_std(S) + noise ----------------
__global__ __launch_bounds__(64)
void k_fft_inv(const float2* __restrict__ S,
               const float* __restrict__ noise_r, const float* __restrict__ noise_i,
               const float* __restrict__ sigma_p, const float* __restrict__ dtp,
               const float* __restrict__ dt_param,
               float2* __restrict__ xf) {
    int img = blockIdx.x; int tid = threadIdx.x;
    __shared__ float re[64 * 65], im[64 * 65];
    __shared__ float twr[32], twi[32];
    if (tid < 32) {
        float ang = 0.098174770424681038798f * (float)tid;
        twr[tid] = cosf(ang); twi[tid] = sinf(ang);
    }
    const float2* src = S + (size_t)img * NPIX;
    for (int idx = tid; idx < NPIX; idx += 64) {
        int h = idx >> 6, w = idx & 63;
        float2 v = src[idx];
        re[h * 65 + w] = v.x; im[h * 65 + w] = v.y;
    }
    __syncthreads();
    fft64(re, im, tid * 65, 1, twr, twi);
    __syncthreads();
    fft64(re, im, tid, 65, twr, twi);
    __syncthreads();
    float dts = 0.f;
    for (int c = 0; c < Cc; ++c) dts += sp_f(dt_param[c]);
    dts = dtp[0] * dts * (1.f / Cc);
    float ns = sigma_p[0] * sqrtf(dts);
    const float inv = 1.f / 4096.f;
    float2* dst = xf + (size_t)img * NPIX;
    const float* nr = noise_r + (size_t)img * NPIX;
    const float* ni = noise_i + (size_t)img * NPIX;
    for (int idx = tid; idx < NPIX; idx += 64) {
        int h = idx >> 6, w = idx & 63;
        dst[idx] = make_float2(re[h * 65 + w] * inv + ns * nr[idx],
                               im[h * 65 + w] * inv + ns * ni[idx]);
    }
}

// ---------------- K_prep: bf16 weight repack for MFMA PH layer ----------------
// B1t [96 n][1152 k]: n<32: +Mg rows; 32..63: Mt^g; 64..95: Pg. k = d*32+r (d<32),
// bias rows k=1024..1055, zero pad to 1152.  B2t [32][1152]: PtPg (natural R).
__global__ __launch_bounds__(256)
void k_prep(const float* __restrict__ JW, const float* __restrict__ Jb,
            const float* __restrict__ RW, const float* __restrict__ Rb,
            const float* __restrict__ W1, const float* __restrict__ dtp,
            const float* __restrict__ dt_param,
            ushort_t* __restrict__ B1t, ushort_t* __restrict__ B2t,
            ushort_t* __restrict__ w1n, ushort_t* __restrict__ w1t,
            float* __restrict__ dts_out) {
    const int N1 = 96 * 1152, N2 = 32 * 1152, N3 = 4096;
    int i = blockIdx.x * 256 + threadIdx.x;
    for (; i < N1 + N2 + N3; i += gridDim.x * 256) {
        if (i < N1) {
            int n = i / 1152, k = i % 1152;
            float v = 0.f;
            if (k < 1024) {
                int d = k >> 5, r = k & 31;
                if (n < 32)      v = JW[d * 1024 + n * 32 + r];
                else if (n < 64) v = JW[d * 1024 + r * 32 + (n - 32)];
                else             v = RW[d * 1024 + (n - 64) * 32 + r];
            } else if (k < 1056) {
                int r = k - 1024;
                if (n < 32)      v = Jb[n * 32 + r];
                else if (n < 64) v = Jb[r * 32 + (n - 32)];
                else             v = Rb[(n - 64) * 32 + r];
            }
            B1t[i] = f2bf(v);
        } else if (i < N1 + N2) {
            int i2 = i - N1;
            int n = i2 / 1152, k = i2 % 1152;
            float v = 0.f;
            if (k < 1024) {
                int d = k >> 5, kk = k & 31;
                v = RW[d * 1024 + kk * 32 + n];
            } else if (k < 1056) {
                v = Rb[(k - 1024) * 32 + n];
            }
            B2t[i2] = f2bf(v);
        } else {
            int i3 = i - N1 - N2;
            int d = i3 >> 7, h = i3 & 127;
            ushort_t v = f2bf(W1[i3]);
            w1n[i3] = v;
            w1t[h * 32 + d] = v;
        }
    }
    if (blockIdx.x == 0 && threadIdx.x == 0) {
        float s = 0.f;
        for (int c = 0; c < Cc; ++c) s += sp_f(dt_param[c]);
        dts_out[0] = dtp[0] * s * (1.f / Cc);
    }
}

// ---------------- K6: Port-Hamiltonian layer, MFMA version ----------------
// Per block: 128 positions. update = Mg - Mt^g - Pt^(Pg) - 1e-4 g as bilinear GEMMs
// over K=1056 (o_{dj}=x_d*g_j synthesized in registers), bf16 MFMA 16x16x32.
__global__ __launch_bounds__(256, 2)
void k_ph(const float2* __restrict__ field,
          const float* __restrict__ ln_g, const float* __restrict__ ln_b,
          const float* __restrict__ b1, const float* __restrict__ w2,
          const ushort_t* __restrict__ w1n, const ushort_t* __restrict__ w1t,
          const ushort_t* __restrict__ B1t, const ushort_t* __restrict__ B2t,
          const float* __restrict__ dts_p,
          float* __restrict__ out) {
    __shared__ ushort_t xin_s[128 * 40];   // bf16 LN output, pitch 40
    __shared__ ushort_t g_s[128 * 40];     // bf16 grads
    __shared__ ushort_t pg_s[128 * 40];    // bf16 Pg
    __shared__ ushort_t A_s[128 * 136];    // t (silu' * w2); aliased: LN scratch, upd f32

    int tid = threadIdx.x;
    int bt = blockIdx.x >> 5;
    int pix0 = (blockIdx.x & 31) << 7;

    // ---- Phase 1: load field, LayerNorm -> xin_s (bf16) ----
    int p = tid & 127, half = tid >> 7;
    const float2* fbase = field + ((size_t)bt * 16) * NPIX + pix0 + p;
    float2 xv[8];
    float s1 = 0.f, s2 = 0.f;
    #pragma unroll
    for (int j = 0; j < 8; ++j) {
        xv[j] = fbase[(half * 8 + j) * NPIX];
        s1 += xv[j].x + xv[j].y;
        s2 += xv[j].x * xv[j].x + xv[j].y * xv[j].y;
    }
    float2* red = (float2*)A_s;
    red[p * 2 + half] = make_float2(s1, s2);
    __syncthreads();
    float2 r0 = red[p * 2], r1 = red[p * 2 + 1];
    float mu = (r0.x + r1.x) * 0.03125f;
    float var = (r0.y + r1.y) * 0.03125f - mu * mu;
    float rs = rsqrtf(var + 1e-5f);
    #pragma unroll
    for (int j = 0; j < 8; ++j) {
        int cf = half * 8 + j;
        xin_s[p * 40 + cf]      = f2bf((xv[j].x - mu) * rs * ln_g[cf] + ln_b[cf]);
        xin_s[p * 40 + cf + 16] = f2bf((xv[j].y - mu) * rs * ln_g[cf + 16] + ln_b[cf + 16]);
    }
    __syncthreads();

    int lane = tid & 63, wv = tid >> 6;
    int quad = lane >> 4, l15 = lane & 15;
    int m0 = wv * 32;
    const f32x4 zero4 = {0.f, 0.f, 0.f, 0.f};

    // ---- z GEMM: z[128][128] = xin @ W1 (K=32, one mfma step) ----
    f32x4 zacc[2][8];
    #pragma unroll
    for (int mt = 0; mt < 2; ++mt)
        #pragma unroll
        for (int nt = 0; nt < 8; ++nt) zacc[mt][nt] = zero4;
    U16 az[2];
    #pragma unroll
    for (int mt = 0; mt < 2; ++mt)
        az[mt].u = *(const uint4*)&xin_s[(m0 + mt * 16 + l15) * 40 + quad * 8];
    #pragma unroll
    for (int nt = 0; nt < 8; ++nt) {
        U16 bz;
        bz.u = *(const uint4*)&w1t[(nt * 16 + l15) * 32 + quad * 8];
        zacc[0][nt] = MFMA16(az[0].s, bz.s, zacc[0][nt]);
        zacc[1][nt] = MFMA16(az[1].s, bz.s, zacc[1][nt]);
    }
    // t = silu'(z + b1) * w2 -> A_s (bf16)
    #pragma unroll
    for (int nt = 0; nt < 8; ++nt) {
        int col = nt * 16 + l15;
        float b1v = b1[col], w2v = w2[col];
        #pragma unroll
        for (int mt = 0; mt < 2; ++mt) {
            #pragma unroll
            for (int r = 0; r < 4; ++r) {
                int row = m0 + mt * 16 + quad * 4 + r;
                float z = zacc[mt][nt][r] + b1v;
                float s = 1.f / (1.f + expf(-z));
                float t = s * (1.f + z * (1.f - s)) * w2v;
                A_s[row * 136 + col] = f2bf(t);
            }
        }
    }

    // ---- g GEMM: g[128][32] = t @ W1^T (K=128) ----
    f32x4 gacc[2][2];
    #pragma unroll
    for (int mt = 0; mt < 2; ++mt)
        #pragma unroll
        for (int nt = 0; nt < 2; ++nt) gacc[mt][nt] = zero4;
    #pragma unroll
    for (int q = 0; q < 4; ++q) {
        U16 ag[2];
        #pragma unroll
        for (int mt = 0; mt < 2; ++mt)
            ag[mt].u = *(const uint4*)&A_s[(m0 + mt * 16 + l15) * 136 + q * 32 + quad * 8];
        #pragma unroll
        for (int nt = 0; nt < 2; ++nt) {
            U16 bg;
            bg.u = *(const uint4*)&w1n[(nt * 16 + l15) * 128 + q * 32 + quad * 8];
            gacc[0][nt] = MFMA16(ag[0].s, bg.s, gacc[0][nt]);
            gacc[1][nt] = MFMA16(ag[1].s, bg.s, gacc[1][nt]);
        }
    }
    #pragma unroll
    for (int mt = 0; mt < 2; ++mt)
        #pragma unroll
        for (int nt = 0; nt < 2; ++nt)
            #pragma unroll
            for (int r = 0; r < 4; ++r)
                g_s[(m0 + mt * 16 + quad * 4 + r) * 40 + nt * 16 + l15] = f2bf(gacc[mt][nt][r]);
    __syncthreads();   // all waves done reading A_s(t); also ensures below upd writes are safe

    // ---- pass 1: out96 = o @ B1t^T -> [mg | mtg | pg], K-steps s=0..32 (s=d, 32=bias) ----
    int xrow0 = m0 + l15, xrow1 = m0 + 16 + l15;
    uint4 gv0 = *(const uint4*)&g_s[xrow0 * 40 + quad * 8];
    uint4 gv1 = *(const uint4*)&g_s[xrow1 * 40 + quad * 8];
    f32x4 acc1[2][6];
    #pragma unroll
    for (int mt = 0; mt < 2; ++mt)
        #pragma unroll
        for (int nt = 0; nt < 6; ++nt) acc1[mt][nt] = zero4;
    uint4 bcur[6], bnext[6];
    #pragma unroll
    for (int nt = 0; nt < 6; ++nt)
        bcur[nt] = *(const uint4*)&B1t[(nt * 16 + l15) * 1152 + quad * 8];
    #pragma unroll 2
    for (int s = 0; s < 33; ++s) {
        U16 a0, a1;
        if (s < 32) {
            float x0 = bf2f(xin_s[xrow0 * 40 + s]);
            float x1 = bf2f(xin_s[xrow1 * 40 + s]);
            a0.u.x = mulpack(gv0.x, x0); a0.u.y = mulpack(gv0.y, x0);
            a0.u.z = mulpack(gv0.z, x0); a0.u.w = mulpack(gv0.w, x0);
            a1.u.x = mulpack(gv1.x, x1); a1.u.y = mulpack(gv1.y, x1);
            a1.u.z = mulpack(gv1.z, x1); a1.u.w = mulpack(gv1.w, x1);
        } else {
            a0.u = gv0; a1.u = gv1;
        }
        if (s < 32) {
            #pragma unroll
            for (int nt = 0; nt < 6; ++nt)
                bnext[nt] = *(const uint4*)&B1t[(nt * 16 + l15) * 1152 + (s + 1) * 32 + quad * 8];
        }
        #pragma unroll
        for (int nt = 0; nt < 6; ++nt) {
            U16 b; b.u = bcur[nt];
            acc1[0][nt] = MFMA16(a0.s, b.s, acc1[0][nt]);
            acc1[1][nt] = MFMA16(a1.s, b.s, acc1[1][nt]);
        }
        #pragma unroll
        for (int nt = 0; nt < 6; ++nt) bcur[nt] = bnext[nt];
    }
    // um = mg - mtg; pg -> pg_s
    f32x4 um[2][2];
    #pragma unroll
    for (int mt = 0; mt < 2; ++mt)
        #pragma unroll
        for (int nt = 0; nt < 2; ++nt) {
            um[mt][nt] = acc1[mt][nt] - acc1[mt][nt + 2];
            #pragma unroll
            for (int r = 0; r < 4; ++r)
                pg_s[(m0 + mt * 16 + quad * 4 + r) * 40 + nt * 16 + l15] = f2bf(acc1[mt][nt + 4][r]);
        }

    // ---- pass 2: ptpg = v @ B2t^T, v_{dk} = x_d * pg_k ----
    uint4 pgv0 = *(const uint4*)&pg_s[xrow0 * 40 + quad * 8];
    uint4 pgv1 = *(const uint4*)&pg_s[xrow1 * 40 + quad * 8];
    f32x4 acc2[2][2];
    #pragma unroll
    for (int mt = 0; mt < 2; ++mt)
        #pragma unroll
        for (int nt = 0; nt < 2; ++nt) acc2[mt][nt] = zero4;
    uint4 c2cur[2], c2next[2];
    #pragma unroll
    for (int nt = 0; nt < 2; ++nt)
        c2cur[nt] = *(const uint4*)&B2t[(nt * 16 + l15) * 1152 + quad * 8];
    #pragma unroll 2
    for (int s = 0; s < 33; ++s) {
        U16 a0, a1;
        if (s < 32) {
            float x0 = bf2f(xin_s[xrow0 * 40 + s]);
            float x1 = bf2f(xin_s[xrow1 * 40 + s]);
            a0.u.x = mulpack(pgv0.x, x0); a0.u.y = mulpack(pgv0.y, x0);
            a0.u.z = mulpack(pgv0.z, x0); a0.u.w = mulpack(pgv0.w, x0);
            a1.u.x = mulpack(pgv1.x, x1); a1.u.y = mulpack(pgv1.y, x1);
            a1.u.z = mulpack(pgv1.z, x1); a1.u.w = mulpack(pgv1.w, x1);
        } else {
            a0.u = pgv0; a1.u = pgv1;
        }
        if (s < 32) {
            #pragma unroll
            for (int nt = 0; nt < 2; ++nt)
                c2next[nt] = *(const uint4*)&B2t[(nt * 16 + l15) * 1152 + (s + 1) * 32 + quad * 8];
        }
        #pragma unroll
        for (int nt = 0; nt < 2; ++nt) {
            U16 b; b.u = c2cur[nt];
            acc2[0][nt] = MFMA16(a0.s, b.s, acc2[0][nt]);
            acc2[1][nt] = MFMA16(a1.s, b.s, acc2[1][nt]);
        }
        #pragma unroll
        for (int nt = 0; nt < 2; ++nt) c2cur[nt] = c2next[nt];
    }

    // ---- epilogue: upd = um - ptpg - 1e-4 g -> LDS (f32), then combine + write ----
    float* upd = (float*)A_s;   // [128][33], t is dead (sync3 above guarantees)
    #pragma unroll
    for (int mt = 0; mt < 2; ++mt)
        #pragma unroll
        for (int nt = 0; nt < 2; ++nt) {
            int col = nt * 16 + l15;
            #pragma unroll
            for (int r = 0; r < 4; ++r) {
                int row = m0 + mt * 16 + quad * 4 + r;
                float gval = bf2f(g_s[row * 40 + col]);
                upd[row * 33 + col] = um[mt][nt][r] - acc2[mt][nt][r] - 1e-4f * gval;
            }
        }
    __syncthreads();
    float dts = dts_p[0];
    #pragma unroll
    for (int cc = 0; cc < 16; ++cc) {
        int c = half * 16 + cc;
        float2 v = fbase[cc * NPIX];
        float xcv = half ? v.y : v.x;
        out[((size_t)bt * 32 + c) * NPIX + pix0 + p] = xcv + dts * upd[p * 33 + c];
    }
}

extern "C" void kernel_launch(void* const* d_in, const int* in_sizes, int n_in,
                              void* d_out, int out_size, void* d_ws, size_t ws_size,
                              hipStream_t stream) {
    const float* x_real   = (const float*)d_in[0];
    const float* x_imag   = (const float*)d_in[1];
    const float* dt       = (const float*)d_in[2];
    const float* conv_w   = (const float*)d_in[3];
    const float* conv_b   = (const float*)d_in[4];
    const float* spec_re  = (const float*)d_in[5];
    const float* spec_im  = (const float*)d_in[6];
    const float* lam_re   = (const float*)d_in[7];
    const float* lam_im   = (const float*)d_in[8];
    const float* dt_param = (const float*)d_in[9];
    const float* sigma    = (const float*)d_in[10];
    const float* noise_r  = (const float*)d_in[11];
    const float* noise_i  = (const float*)d_in[12];
    const float* ln_g     = (const float*)d_in[13];
    const float* ln_b     = (const float*)d_in[14];
    const float* W1       = (const float*)d_in[15];
    const float* b1       = (const float*)d_in[16];
    const float* w2       = (const float*)d_in[17];
    const float* Jg_W     = (const float*)d_in[19];
    const float* Jg_b     = (const float*)d_in[20];
    const float* Rg_W     = (const float*)d_in[21];
    const float* Rg_b     = (const float*)d_in[22];

    float2* wsA = (float2*)d_ws;              // x1, later final field (1048576 float2)
    float2* wsB = wsA + 1048576;              // X2f / assembled spectrum
    float2* wsC = wsB + 1048576;              // Gre (540672 float2)
    float2* wsD = wsC + 540672;               // Gim

    // bf16 weight region after wsD (~0.31 MB)
    ushort_t* B1t = (ushort_t*)(wsD + 540672);
    ushort_t* B2t = B1t + 96 * 1152;
    ushort_t* w1n = B2t + 32 * 1152;
    ushort_t* w1t = w1n + 4096;
    float*    dts = (float*)(w1t + 4096);

    k_prep<<<160, 256, 0, stream>>>(Jg_W, Jg_b, Rg_W, Rg_b, W1, dt, dt_param,
                                    B1t, B2t, w1n, w1t, dts);
    k_conv<<<256, 256, 0, stream>>>(x_real, x_imag, conv_w, conv_b, wsA);
    k_fft_fwd<<<NIMG, 64, 0, stream>>>(wsA, spec_re, spec_im, wsB);
    k_scan<<<264, 256, 0, stream>>>(wsB, lam_re, lam_im, dt_param, dt, wsC, wsD);
    k_assemble<<<4096, 256, 0, stream>>>(wsB, wsC, wsD);
    k_fft_inv<<<NIMG, 64, 0, stream>>>(wsB, noise_r, noise_i, sigma, dt, dt_param, wsA);
    k_ph<<<512, 256, 0, stream>>>(wsA, ln_g, ln_b, b1, w2, w1n, w1t, B1t, B2t, dts,
                                  (float*)d_out);
}

// Round 3
// 311.367 us; speedup vs baseline: 3.4984x; 1.0003x over previous
//
#include <hip/hip_runtime.h>
#include <math.h>

#define Bb 2
#define Tt 8
#define Cc 16
#define Hh 64
#define Ww 64
#define Dd 32
#define HID 128
#define WF 33
#define NPIX 4096
#define NIMG 256   // B*T*C

typedef unsigned short ushort_t;
typedef unsigned int uint_t;
typedef __attribute__((ext_vector_type(8))) short short8;
typedef __attribute__((ext_vector_type(4))) float f32x4;
union U16 { uint4 u; short8 s; };

__device__ __forceinline__ float sp_f(float x) {           // softplus
    return (x > 20.f) ? x : log1pf(expf(x));
}

__device__ __forceinline__ ushort_t f2bf(float f) {        // round-to-nearest-even
    uint_t u = __float_as_uint(f);
    uint_t r = (u + 0x7fffu + ((u >> 16) & 1u)) >> 16;
    return (ushort_t)r;
}
__device__ __forceinline__ float bf2f(ushort_t h) { return __uint_as_float(((uint_t)h) << 16); }

// multiply packed pair of bf16 by scalar, repack (truncation)
__device__ __forceinline__ uint_t mulpack(uint_t gpair, float xf) {
    float lo = __uint_as_float(gpair << 16) * xf;
    float hi = __uint_as_float(gpair & 0xffff0000u) * xf;
    return (__float_as_uint(hi) & 0xffff0000u) | (__float_as_uint(lo) >> 16);
}

__device__ __forceinline__ int rev6(int x) { return (int)(__brev((unsigned)x) >> 26); }

#define MFMA16(a, b, c) __builtin_amdgcn_mfma_f32_16x16x32_bf16((a), (b), (c), 0, 0, 0)

// ---------------- K1: x1 = x + conv3x3(x) + b (applied to re and im) ----------------
// 512 blocks: 16 bt-images x 16 tiles x 2 co-halves. Each thread: 8 output channels.
__global__ __launch_bounds__(256)
void k_conv(const float* __restrict__ xr, const float* __restrict__ xi,
            const float* __restrict__ cw, const float* __restrict__ cb,
            float2* __restrict__ x1) {
    int blk = blockIdx.x;
    int bt = blk >> 5;
    int sub = blk & 31;
    int tile = sub >> 1, cohalf = sub & 1;
    int ty0 = (tile >> 2) * 16, tx0 = (tile & 3) * 16;
    __shared__ float sre[Cc][18][18];
    __shared__ float sim[Cc][18][18];
    __shared__ float swt[8 * 16 * 12];     // 8 oc x 16 ci x 9 weights padded to 12
    __shared__ float sb[8];
    int tid = threadIdx.x;
    for (int i = tid; i < 8 * 16 * 9; i += 256) {
        int g = i / 9, k = i % 9;
        swt[g * 12 + k] = cw[cohalf * 8 * 144 + i];
    }
    if (tid < 8) sb[tid] = cb[cohalf * 8 + tid];
    for (int i = tid; i < Cc * 18 * 18; i += 256) {
        int ci = i / 324; int r = i % 324; int y = r / 18, x = r % 18;
        int gy = ty0 + y - 1, gx = tx0 + x - 1;
        float vr = 0.f, vi = 0.f;
        if (gy >= 0 && gy < Hh && gx >= 0 && gx < Ww) {
            int gidx = (bt * Cc + ci) * NPIX + gy * Ww + gx;
            vr = xr[gidx]; vi = xi[gidx];
        }
        sre[ci][y][x] = vr; sim[ci][y][x] = vi;
    }
    __syncthreads();
    int py = tid >> 4, px = tid & 15;
    int gy = ty0 + py, gx = tx0 + px;
    float ar[8], ai[8];
    #pragma unroll
    for (int oc = 0; oc < 8; ++oc) {
        int cg = cohalf * 8 + oc;
        ar[oc] = sre[cg][py + 1][px + 1] + sb[oc];
        ai[oc] = sim[cg][py + 1][px + 1] + sb[oc];
    }
    for (int ci = 0; ci < Cc; ++ci) {
        float nr[9], ni[9];
        #pragma unroll
        for (int dy = 0; dy < 3; ++dy)
            #pragma unroll
            for (int dx = 0; dx < 3; ++dx) {
                nr[dy * 3 + dx] = sre[ci][py + dy][px + dx];
                ni[dy * 3 + dx] = sim[ci][py + dy][px + dx];
            }
        #pragma unroll
        for (int oc = 0; oc < 8; ++oc) {
            const float* wp = &swt[(oc * 16 + ci) * 12];
            float4 w0 = *(const float4*)&wp[0];
            float4 w1 = *(const float4*)&wp[4];
            float w8 = wp[8];
            ar[oc] += w0.x * nr[0] + w0.y * nr[1] + w0.z * nr[2]
                    + w0.w * nr[3] + w1.x * nr[4] + w1.y * nr[5]
                    + w1.z * nr[6] + w1.w * nr[7] + w8 * nr[8];
            ai[oc] += w0.x * ni[0] + w0.y * ni[1] + w0.z * ni[2]
                    + w0.w * ni[3] + w1.x * ni[4] + w1.y * ni[5]
                    + w1.z * ni[6] + w1.w * ni[7] + w8 * ni[8];
        }
    }
    #pragma unroll
    for (int oc = 0; oc < 8; ++oc)
        x1[(bt * Cc + cohalf * 8 + oc) * NPIX + gy * Ww + gx] = make_float2(ar[oc], ai[oc]);
}

// ---------------- 2D 64x64 complex FFT core, 256 threads -----------------------------
// Rows: DIT (input pre-bit-reversed along w), natural output. Columns: DIF (output
// bit-reversed along h -> consumer reads row rev6(h)). Twiddle table encodes direction.
__device__ __forceinline__ void fft2d_256(float* re, float* im,
                                          const float* twr, const float* twi, int tid) {
    int lane = tid & 63;
    int wv = tid >> 6;
    // row pass: DIT
    for (int s = 0; s <= 5; ++s) {
        __syncthreads();
        int hm = 1 << s;
        #pragma unroll
        for (int jj = 0; jj < 8; ++jj) {
            int j = wv * 8 + jj;
            int g = j >> s;
            int pos = j & (hm - 1);
            int i1 = g * (hm << 1) + pos;
            int i2 = i1 + hm;
            int twx = pos << (5 - s);
            float wr = twr[twx], wi = twi[twx];
            int a1 = lane * 65 + i1, a2 = lane * 65 + i2;
            float ar = re[a1], ai = im[a1];
            float br = re[a2], bi = im[a2];
            float tr = br * wr - bi * wi;
            float ti = br * wi + bi * wr;
            re[a1] = ar + tr; im[a1] = ai + ti;
            re[a2] = ar - tr; im[a2] = ai - ti;
        }
    }
    // column pass: DIF
    for (int s = 0; s <= 5; ++s) {
        __syncthreads();
        int hm = 32 >> s;
        #pragma unroll
        for (int jj = 0; jj < 8; ++jj) {
            int j = wv * 8 + jj;
            int g = j >> (5 - s);
            int pos = j & (hm - 1);
            int i1 = g * (hm << 1) + pos;
            int i2 = i1 + hm;
            int twx = pos << s;
            float wr = twr[twx], wi = twi[twx];
            int a1 = i1 * 65 + lane, a2 = i2 * 65 + lane;
            float ar = re[a1], ai = im[a1];
            float br = re[a2], bi = im[a2];
            float sr = ar - br, si = ai - bi;
            re[a1] = ar + br; im[a1] = ai + bi;
            re[a2] = sr * wr - si * wi;
            im[a2] = sr * wi + si * wr;
        }
    }
    __syncthreads();
}

// ---------------- K2: X2f = fft2_std(x1) * (1 + filt) ----------------
__global__ __launch_bounds__(256)
void k_fft_fwd(const float2* __restrict__ x1,
               const float* __restrict__ spec_re, const float* __restrict__ spec_im,
               float2* __restrict__ X2f) {
    int img = blockIdx.x;
    int c = img % Cc;
    int tid = threadIdx.x;
    __shared__ float re[64 * 65], im[64 * 65];
    __shared__ float twr[32], twi[32];
    if (tid < 32) {
        float ang = -0.098174770424681038798f * (float)tid;  // forward: e^{-2pi i t/64}
        twr[tid] = cosf(ang); twi[tid] = sinf(ang);
    }
    const float2* src = x1 + (size_t)img * NPIX;
    for (int idx = tid; idx < NPIX; idx += 256) {
        int h = idx >> 6, w = idx & 63;
        float2 v = src[idx];
        int wr_ = rev6(w);
        re[h * 65 + wr_] = v.x; im[h * 65 + wr_] = v.y;
    }
    fft2d_256(re, im, twr, twi, tid);
    const float* fr = spec_re + c * NPIX;
    const float* fi = spec_im + c * NPIX;
    float2* dst = X2f + (size_t)img * NPIX;
    for (int idx = tid; idx < NPIX; idx += 256) {
        int h = idx >> 6, w = idx & 63;
        int hr = rev6(h);
        float xr_ = re[hr * 65 + w], xi_ = im[hr * 65 + w];
        float gr = 1.f + fr[idx], gi = fi[idx];
        dst[idx] = make_float2(xr_ * gr - xi_ * gi, xi_ * gr + xr_ * gi);
    }
}

// ---------------- K3: Hermitian split + diagonal SSM scan over T (half-spectrum) -------
__global__ __launch_bounds__(256)
void k_scan(const float2* __restrict__ X2f,
            const float* __restrict__ lam_re, const float* __restrict__ lam_im,
            const float* __restrict__ dt_param, const float* __restrict__ dtp,
            float2* __restrict__ Gre, float2* __restrict__ Gim) {
    int id = blockIdx.x * 256 + threadIdx.x;
    const int NB = Bb * Cc * Hh * WF;
    if (id >= NB) return;
    int w = id % WF; int r = id / WF;
    int h = r % Hh; r /= Hh;
    int c = r % Cc; int b = r / Cc;
    float dte = dtp[0] * sp_f(dt_param[c]);
    float ea = expf(-sp_f(lam_re[c]) * dte);
    float ph = lam_im[c] * dte;
    float Ar = ea * cosf(ph), Ai = ea * sinf(ph);
    int hm = (64 - h) & 63, wm = (64 - w) & 63;
    float gr_r = 0.f, gr_i = 0.f, gi_r = 0.f, gi_i = 0.f;
    for (int t = 0; t < Tt; ++t) {
        int ib = ((b * Tt + t) * Cc + c) * NPIX;
        float2 Z = X2f[ib + h * 64 + w];
        float2 Zm = X2f[ib + hm * 64 + wm];
        float ur_r = 0.5f * (Z.x + Zm.x), ur_i = 0.5f * (Z.y - Zm.y);
        float ui_r = 0.5f * (Z.y + Zm.y), ui_i = 0.5f * (Zm.x - Z.x);
        float nr = Ar * gr_r - Ai * gr_i + ur_r;
        float ni = Ar * gr_i + Ai * gr_r + ur_i;
        gr_r = nr; gr_i = ni;
        nr = Ar * gi_r - Ai * gi_i + ui_r;
        ni = Ar * gi_i + Ai * gi_r + ui_i;
        gi_r = nr; gi_i = ni;
        int ig = ((b * Tt + t) * Cc + c) * (Hh * WF) + h * WF + w;
        Gre[ig] = make_float2(gr_r, gr_i);
        Gim[ig] = make_float2(gi_r, gi_i);
    }
}

// ---------------- K5: field = ifft2_std(X2f + HermExt(sym(G))) + noise (assemble fused)
__global__ __launch_bounds__(256)
void k_fft_inv(const float2* __restrict__ X2f,
               const float2* __restrict__ Gre, const float2* __restrict__ Gim,
               const float* __restrict__ noise_r, const float* __restrict__ noise_i,
               const float* __restrict__ sigma_p, const float* __restrict__ dts_p,
               float2* __restrict__ xf) {
    int img = blockIdx.x; int tid = threadIdx.x;
    __shared__ float re[64 * 65], im[64 * 65];
    __shared__ float twr[32], twi[32];
    if (tid < 32) {
        float ang = 0.098174770424681038798f * (float)tid;   // inverse: e^{+2pi i t/64}
        twr[tid] = cosf(ang); twi[tid] = sinf(ang);
    }
    const float2* src = X2f + (size_t)img * NPIX;
    int base = img * (Hh * WF);
    for (int idx = tid; idx < NPIX; idx += 256) {
        int h = idx >> 6, w = idx & 63;
        int hm = (64 - h) & 63;
        float zr, zi;
        if (w <= 32) {
            float2 a = Gre[base + h * WF + w];
            float2 bb = Gim[base + h * WF + w];
            if (w == 0 || w == 32) {   // symmetrize self-conjugate columns (irfft behavior)
                float2 a2 = Gre[base + hm * WF + w];
                float2 b2 = Gim[base + hm * WF + w];
                a = make_float2(0.5f * (a.x + a2.x), 0.5f * (a.y - a2.y));
                bb = make_float2(0.5f * (bb.x + b2.x), 0.5f * (bb.y - b2.y));
            }
            zr = a.x - bb.y; zi = a.y + bb.x;
        } else {
            int wf = 64 - w;
            float2 a = Gre[base + hm * WF + wf];
            float2 bb = Gim[base + hm * WF + wf];
            zr = a.x + bb.y; zi = bb.x - a.y;
        }
        float2 s = src[idx];
        int wr_ = rev6(w);
        re[h * 65 + wr_] = s.x + zr; im[h * 65 + wr_] = s.y + zi;
    }
    fft2d_256(re, im, twr, twi, tid);
    float ns = sigma_p[0] * sqrtf(dts_p[0]);
    const float inv = 1.f / 4096.f;
    float2* dst = xf + (size_t)img * NPIX;
    const float* nr = noise_r + (size_t)img * NPIX;
    const float* ni = noise_i + (size_t)img * NPIX;
    for (int idx = tid; idx < NPIX; idx += 256) {
        int h = idx >> 6, w = idx & 63;
        int hr = rev6(h);
        dst[idx] = make_float2(re[hr * 65 + w] * inv + ns * nr[idx],
                               im[hr * 65 + w] * inv + ns * ni[idx]);
    }
}

// ---------------- K_prep: bf16 weight repack for MFMA PH layer ----------------
__global__ __launch_bounds__(256)
void k_prep(const float* __restrict__ JW, const float* __restrict__ Jb,
            const float* __restrict__ RW, const float* __restrict__ Rb,
            const float* __restrict__ W1, const float* __restrict__ dtp,
            const float* __restrict__ dt_param,
            ushort_t* __restrict__ B1t, ushort_t* __restrict__ B2t,
            ushort_t* __restrict__ w1n, ushort_t* __restrict__ w1t,
            float* __restrict__ dts_out) {
    const int N1 = 96 * 1152, N2 = 32 * 1152, N3 = 4096;
    int i = blockIdx.x * 256 + threadIdx.x;
    for (; i < N1 + N2 + N3; i += gridDim.x * 256) {
        if (i < N1) {
            int n = i / 1152, k = i % 1152;
            float v = 0.f;
            if (k < 1024) {
                int d = k >> 5, r = k & 31;
                if (n < 32)      v = JW[d * 1024 + n * 32 + r];
                else if (n < 64) v = JW[d * 1024 + r * 32 + (n - 32)];
                else             v = RW[d * 1024 + (n - 64) * 32 + r];
            } else if (k < 1056) {
                int r = k - 1024;
                if (n < 32)      v = Jb[n * 32 + r];
                else if (n < 64) v = Jb[r * 32 + (n - 32)];
                else             v = Rb[(n - 64) * 32 + r];
            }
            B1t[i] = f2bf(v);
        } else if (i < N1 + N2) {
            int i2 = i - N1;
            int n = i2 / 1152, k = i2 % 1152;
            float v = 0.f;
            if (k < 1024) {
                int d = k >> 5, kk = k & 31;
                v = RW[d * 1024 + kk * 32 + n];
            } else if (k < 1056) {
                v = Rb[(k - 1024) * 32 + n];
            }
            B2t[i2] = f2bf(v);
        } else {
            int i3 = i - N1 - N2;
            int d = i3 >> 7, h = i3 & 127;
            ushort_t v = f2bf(W1[i3]);
            w1n[i3] = v;
            w1t[h * 32 + d] = v;
        }
    }
    if (blockIdx.x == 0 && threadIdx.x == 0) {
        float s = 0.f;
        for (int c = 0; c < Cc; ++c) s += sp_f(dt_param[c]);
        dts_out[0] = dtp[0] * s * (1.f / Cc);
    }
}

// ---------------- K6: Port-Hamiltonian layer, MFMA, M=64/block ----------------
__global__ __launch_bounds__(256, 4)
void k_ph(const float2* __restrict__ field,
          const float* __restrict__ ln_g, const float* __restrict__ ln_b,
          const float* __restrict__ b1, const float* __restrict__ w2,
          const ushort_t* __restrict__ w1n, const ushort_t* __restrict__ w1t,
          const ushort_t* __restrict__ B1t, const ushort_t* __restrict__ B2t,
          const float* __restrict__ dts_p,
          float* __restrict__ out) {
    __shared__ ushort_t xin_s[64 * 40];    // bf16 LN output (5120 B)
    __shared__ ushort_t g_s[64 * 40];      // bf16 grads
    __shared__ ushort_t pg_s[64 * 40];     // bf16 Pg
    __shared__ ushort_t A_s[64 * 136];     // t bf16 (17408 B); aliased: LN scratch, upd f32

    int tid = threadIdx.x;
    int bt = blockIdx.x >> 6;
    int pix0 = (blockIdx.x & 63) << 6;
    int p = tid & 63, qt = tid >> 6;
    const float2* fbase = field + ((size_t)bt * 16) * NPIX + pix0 + p;

    // ---- Phase 1: load field (4 planes per thread-quarter), LayerNorm -> xin_s ----
    float2 xv[4];
    float s1 = 0.f, s2 = 0.f;
    #pragma unroll
    for (int j = 0; j < 4; ++j) {
        xv[j] = fbase[(qt * 4 + j) * NPIX];
        s1 += xv[j].x + xv[j].y;
        s2 += xv[j].x * xv[j].x + xv[j].y * xv[j].y;
    }
    float2* red = (float2*)A_s;
    red[p * 4 + qt] = make_float2(s1, s2);
    __syncthreads();
    float2 r0 = red[p * 4], r1 = red[p * 4 + 1], r2 = red[p * 4 + 2], r3 = red[p * 4 + 3];
    float mu = (r0.x + r1.x + r2.x + r3.x) * 0.03125f;
    float var = (r0.y + r1.y + r2.y + r3.y) * 0.03125f - mu * mu;
    float rs = rsqrtf(var + 1e-5f);
    #pragma unroll
    for (int j = 0; j < 4; ++j) {
        int cf = qt * 4 + j;
        xin_s[p * 40 + cf]      = f2bf((xv[j].x - mu) * rs * ln_g[cf] + ln_b[cf]);
        xin_s[p * 40 + cf + 16] = f2bf((xv[j].y - mu) * rs * ln_g[cf + 16] + ln_b[cf + 16]);
    }
    __syncthreads();

    int lane = tid & 63, wv = tid >> 6;
    int quad = lane >> 4, l15 = lane & 15;
    int m0 = wv * 16;
    const f32x4 zero4 = {0.f, 0.f, 0.f, 0.f};

    // ---- z GEMM: z[16][128] = xin @ W1 (K=32) ----
    f32x4 zacc[8];
    #pragma unroll
    for (int nt = 0; nt < 8; ++nt) zacc[nt] = zero4;
    U16 az;
    az.u = *(const uint4*)&xin_s[(m0 + l15) * 40 + quad * 8];
    #pragma unroll
    for (int nt = 0; nt < 8; ++nt) {
        U16 bz;
        bz.u = *(const uint4*)&w1t[(nt * 16 + l15) * 32 + quad * 8];
        zacc[nt] = MFMA16(az.s, bz.s, zacc[nt]);
    }
    // t = silu'(z + b1) * w2 -> A_s rows m0..m0+15 (own wave)
    #pragma unroll
    for (int nt = 0; nt < 8; ++nt) {
        int col = nt * 16 + l15;
        float b1v = b1[col], w2v = w2[col];
        #pragma unroll
        for (int r = 0; r < 4; ++r) {
            int row = m0 + quad * 4 + r;
            float z = zacc[nt][r] + b1v;
            float s = 1.f / (1.f + expf(-z));
            float t = s * (1.f + z * (1.f - s)) * w2v;
            A_s[row * 136 + col] = f2bf(t);
        }
    }

    // ---- g GEMM: g[16][32] = t @ W1^T (K=128), own-wave rows, no sync needed ----
    f32x4 gacc[2];
    gacc[0] = zero4; gacc[1] = zero4;
    #pragma unroll
    for (int q = 0; q < 4; ++q) {
        U16 ag;
        ag.u = *(const uint4*)&A_s[(m0 + l15) * 136 + q * 32 + quad * 8];
        #pragma unroll
        for (int nt = 0; nt < 2; ++nt) {
            U16 bg;
            bg.u = *(const uint4*)&w1n[(nt * 16 + l15) * 128 + q * 32 + quad * 8];
            gacc[nt] = MFMA16(ag.s, bg.s, gacc[nt]);
        }
    }
    #pragma unroll
    for (int nt = 0; nt < 2; ++nt)
        #pragma unroll
        for (int r = 0; r < 4; ++r)
            g_s[(m0 + quad * 4 + r) * 40 + nt * 16 + l15] = f2bf(gacc[nt][r]);

    // ---- register-cache the xin row (32 bf16 = 16 uints) ----
    int xrow = m0 + l15;
    uint_t xw[16];
    *(uint4*)&xw[0]  = *(const uint4*)&xin_s[xrow * 40 + 0];
    *(uint4*)&xw[4]  = *(const uint4*)&xin_s[xrow * 40 + 8];
    *(uint4*)&xw[8]  = *(const uint4*)&xin_s[xrow * 40 + 16];
    *(uint4*)&xw[12] = *(const uint4*)&xin_s[xrow * 40 + 24];
    uint4 gv = *(const uint4*)&g_s[xrow * 40 + quad * 8];

    // ---- pass 1: out96 = o @ B1t^T -> [mg | mtg | pg], K-steps s=0..32 ----
    f32x4 acc1[6];
    #pragma unroll
    for (int nt = 0; nt < 6; ++nt) acc1[nt] = zero4;
    #pragma unroll
    for (int s = 0; s < 33; ++s) {
        U16 a0;
        if (s < 32) {
            uint_t u = xw[s >> 1];
            float xs = (s & 1) ? __uint_as_float(u & 0xffff0000u)
                               : __uint_as_float(u << 16);
            a0.u.x = mulpack(gv.x, xs); a0.u.y = mulpack(gv.y, xs);
            a0.u.z = mulpack(gv.z, xs); a0.u.w = mulpack(gv.w, xs);
        } else {
            a0.u = gv;
        }
        U16 b[6];
        #pragma unroll
        for (int nt = 0; nt < 6; ++nt)
            b[nt].u = *(const uint4*)&B1t[(nt * 16 + l15) * 1152 + s * 32 + quad * 8];
        #pragma unroll
        for (int nt = 0; nt < 6; ++nt)
            acc1[nt] = MFMA16(a0.s, b[nt].s, acc1[nt]);
    }
    // um = mg - mtg; pg -> pg_s (own rows)
    f32x4 um[2];
    #pragma unroll
    for (int nt = 0; nt < 2; ++nt) {
        um[nt] = acc1[nt] - acc1[nt + 2];
        #pragma unroll
        for (int r = 0; r < 4; ++r)
            pg_s[(m0 + quad * 4 + r) * 40 + nt * 16 + l15] = f2bf(acc1[nt + 4][r]);
    }

    // ---- pass 2: ptpg = v @ B2t^T, v_{dk} = x_d * pg_k ----
    uint4 pgv = *(const uint4*)&pg_s[xrow * 40 + quad * 8];
    f32x4 acc2[2];
    acc2[0] = zero4; acc2[1] = zero4;
    #pragma unroll
    for (int s = 0; s < 33; ++s) {
        U16 a0;
        if (s < 32) {
            uint_t u = xw[s >> 1];
            float xs = (s & 1) ? __uint_as_float(u & 0xffff0000u)
                               : __uint_as_float(u << 16);
            a0.u.x = mulpack(pgv.x, xs); a0.u.y = mulpack(pgv.y, xs);
            a0.u.z = mulpack(pgv.z, xs); a0.u.w = mulpack(pgv.w, xs);
        } else {
            a0.u = pgv;
        }
        U16 b[2];
        #pragma unroll
        for (int nt = 0; nt < 2; ++nt)
            b[nt].u = *(const uint4*)&B2t[(nt * 16 + l15) * 1152 + s * 32 + quad * 8];
        #pragma unroll
        for (int nt = 0; nt < 2; ++nt)
            acc2[nt] = MFMA16(a0.s, b[nt].s, acc2[nt]);
    }

    // ---- epilogue: upd = um - ptpg - 1e-4 g -> LDS f32 [64][33] (aliases A_s) ----
    __syncthreads();               // everyone done with t region of A_s
    float* upd = (float*)A_s;
    #pragma unroll
    for (int nt = 0; nt < 2; ++nt) {
        int col = nt * 16 + l15;
        #pragma unroll
        for (int r = 0; r < 4; ++r) {
            int row = m0 + quad * 4 + r;
            float gval = bf2f(g_s[row * 40 + col]);
            upd[row * 33 + col] = um[nt][r] - acc2[nt][r] - 1e-4f * gval;
        }
    }
    __syncthreads();
    float dts = dts_p[0];
    #pragma unroll
    for (int cc = 0; cc < 8; ++cc) {
        int c = qt * 8 + cc;
        float2 v = fbase[(c & 15) * NPIX];
        float xcv = (c < 16) ? v.x : v.y;
        out[((size_t)bt * 32 + c) * NPIX + pix0 + p] = xcv + dts * upd[p * 33 + c];
    }
}

extern "C" void kernel_launch(void* const* d_in, const int* in_sizes, int n_in,
                              void* d_out, int out_size, void* d_ws, size_t ws_size,
                              hipStream_t stream) {
    const float* x_real   = (const float*)d_in[0];
    const float* x_imag   = (const float*)d_in[1];
    const float* dt       = (const float*)d_in[2];
    const float* conv_w   = (const float*)d_in[3];
    const float* conv_b   = (const float*)d_in[4];
    const float* spec_re  = (const float*)d_in[5];
    const float* spec_im  = (const float*)d_in[6];
    const float* lam_re   = (const float*)d_in[7];
    const float* lam_im   = (const float*)d_in[8];
    const float* dt_param = (const float*)d_in[9];
    const float* sigma    = (const float*)d_in[10];
    const float* noise_r  = (const float*)d_in[11];
    const float* noise_i  = (const float*)d_in[12];
    const float* ln_g     = (const float*)d_in[13];
    const float* ln_b     = (const float*)d_in[14];
    const float* W1       = (const float*)d_in[15];
    const float* b1       = (const float*)d_in[16];
    const float* w2       = (const float*)d_in[17];
    const float* Jg_W     = (const float*)d_in[19];
    const float* Jg_b     = (const float*)d_in[20];
    const float* Rg_W     = (const float*)d_in[21];
    const float* Rg_b     = (const float*)d_in[22];

    float2* wsA = (float2*)d_ws;              // x1, later final field (1048576 float2)
    float2* wsB = wsA + 1048576;              // X2f spectrum
    float2* wsC = wsB + 1048576;              // Gre (540672 float2)
    float2* wsD = wsC + 540672;               // Gim

    ushort_t* B1t = (ushort_t*)(wsD + 540672);
    ushort_t* B2t = B1t + 96 * 1152;
    ushort_t* w1n = B2t + 32 * 1152;
    ushort_t* w1t = w1n + 4096;
    float*    dts = (float*)(w1t + 4096);

    k_prep<<<160, 256, 0, stream>>>(Jg_W, Jg_b, Rg_W, Rg_b, W1, dt, dt_param,
                                    B1t, B2t, w1n, w1t, dts);
    k_conv<<<512, 256, 0, stream>>>(x_real, x_imag, conv_w, conv_b, wsA);
    k_fft_fwd<<<NIMG, 256, 0, stream>>>(wsA, spec_re, spec_im, wsB);
    k_scan<<<264, 256, 0, stream>>>(wsB, lam_re, lam_im, dt_param, dt, wsC, wsD);
    k_fft_inv<<<NIMG, 256, 0, stream>>>(wsB, wsC, wsD, noise_r, noise_i, sigma, dts, wsA);
    k_ph<<<1024, 256, 0, stream>>>(wsA, ln_g, ln_b, b1, w2, w1n, w1t, B1t, B2t, dts,
                                   (float*)d_out);
}

// Round 4
// 247.535 us; speedup vs baseline: 4.4006x; 1.2579x over previous
//
#include <hip/hip_runtime.h>
#include <math.h>

#define Bb 2
#define Tt 8
#define Cc 16
#define Hh 64
#define Ww 64
#define Dd 32
#define HID 128
#define WF 33
#define NPIX 4096
#define NIMG 256   // B*T*C

typedef unsigned short ushort_t;
typedef unsigned int uint_t;
typedef __attribute__((ext_vector_type(8))) short short8;
typedef __attribute__((ext_vector_type(4))) float f32x4;
union U16 { uint4 u; short8 s; };

__device__ __forceinline__ float sp_f(float x) {           // softplus
    return (x > 20.f) ? x : log1pf(expf(x));
}

__device__ __forceinline__ ushort_t f2bf(float f) {        // round-to-nearest-even
    uint_t u = __float_as_uint(f);
    uint_t r = (u + 0x7fffu + ((u >> 16) & 1u)) >> 16;
    return (ushort_t)r;
}
__device__ __forceinline__ float bf2f(ushort_t h) { return __uint_as_float(((uint_t)h) << 16); }

__device__ __forceinline__ int rev6(int x) { return (int)(__brev((unsigned)x) >> 26); }

// pack two f32 (truncate) into bf16 pair: low16 = lo, high16 = hi  (v_perm_b32)
__device__ __forceinline__ uint_t packbf(float hi, float lo) {
    return __builtin_amdgcn_perm(__float_as_uint(hi), __float_as_uint(lo), 0x07060302u);
}
__device__ __forceinline__ uint4 synth8(const float* gf, float xs) {
    uint4 r;
    r.x = packbf(gf[1] * xs, gf[0] * xs);
    r.y = packbf(gf[3] * xs, gf[2] * xs);
    r.z = packbf(gf[5] * xs, gf[4] * xs);
    r.w = packbf(gf[7] * xs, gf[6] * xs);
    return r;
}
__device__ __forceinline__ void expand8(uint4 v, float* f) {
    f[0] = __uint_as_float(v.x << 16); f[1] = __uint_as_float(v.x & 0xffff0000u);
    f[2] = __uint_as_float(v.y << 16); f[3] = __uint_as_float(v.y & 0xffff0000u);
    f[4] = __uint_as_float(v.z << 16); f[5] = __uint_as_float(v.z & 0xffff0000u);
    f[6] = __uint_as_float(v.w << 16); f[7] = __uint_as_float(v.w & 0xffff0000u);
}

typedef __attribute__((address_space(1))) const void cgvoid;
typedef __attribute__((address_space(3))) void svoid;
__device__ __forceinline__ void gload_lds16(const void* g, void* l) {
    __builtin_amdgcn_global_load_lds((cgvoid*)g, (svoid*)l, 16, 0, 0);
}

#define MFMA16(a, b, c) __builtin_amdgcn_mfma_f32_16x16x32_bf16((a), (b), (c), 0, 0, 0)

// ---------------- K1: x1 = x + conv3x3(x) + b (applied to re and im) ----------------
__global__ __launch_bounds__(256)
void k_conv(const float* __restrict__ xr, const float* __restrict__ xi,
            const float* __restrict__ cw, const float* __restrict__ cb,
            float2* __restrict__ x1) {
    int blk = blockIdx.x;
    int bt = blk >> 5;
    int sub = blk & 31;
    int tile = sub >> 1, cohalf = sub & 1;
    int ty0 = (tile >> 2) * 16, tx0 = (tile & 3) * 16;
    __shared__ float sre[Cc][18][18];
    __shared__ float sim[Cc][18][18];
    __shared__ float swt[8 * 16 * 12];
    __shared__ float sb[8];
    int tid = threadIdx.x;
    for (int i = tid; i < 8 * 16 * 9; i += 256) {
        int g = i / 9, k = i % 9;
        swt[g * 12 + k] = cw[cohalf * 8 * 144 + i];
    }
    if (tid < 8) sb[tid] = cb[cohalf * 8 + tid];
    for (int i = tid; i < Cc * 18 * 18; i += 256) {
        int ci = i / 324; int r = i % 324; int y = r / 18, x = r % 18;
        int gy = ty0 + y - 1, gx = tx0 + x - 1;
        float vr = 0.f, vi = 0.f;
        if (gy >= 0 && gy < Hh && gx >= 0 && gx < Ww) {
            int gidx = (bt * Cc + ci) * NPIX + gy * Ww + gx;
            vr = xr[gidx]; vi = xi[gidx];
        }
        sre[ci][y][x] = vr; sim[ci][y][x] = vi;
    }
    __syncthreads();
    int py = tid >> 4, px = tid & 15;
    int gy = ty0 + py, gx = tx0 + px;
    float ar[8], ai[8];
    #pragma unroll
    for (int oc = 0; oc < 8; ++oc) {
        int cg = cohalf * 8 + oc;
        ar[oc] = sre[cg][py + 1][px + 1] + sb[oc];
        ai[oc] = sim[cg][py + 1][px + 1] + sb[oc];
    }
    for (int ci = 0; ci < Cc; ++ci) {
        float nr[9], ni[9];
        #pragma unroll
        for (int dy = 0; dy < 3; ++dy)
            #pragma unroll
            for (int dx = 0; dx < 3; ++dx) {
                nr[dy * 3 + dx] = sre[ci][py + dy][px + dx];
                ni[dy * 3 + dx] = sim[ci][py + dy][px + dx];
            }
        #pragma unroll
        for (int oc = 0; oc < 8; ++oc) {
            const float* wp = &swt[(oc * 16 + ci) * 12];
            float4 w0 = *(const float4*)&wp[0];
            float4 w1 = *(const float4*)&wp[4];
            float w8 = wp[8];
            ar[oc] += w0.x * nr[0] + w0.y * nr[1] + w0.z * nr[2]
                    + w0.w * nr[3] + w1.x * nr[4] + w1.y * nr[5]
                    + w1.z * nr[6] + w1.w * nr[7] + w8 * nr[8];
            ai[oc] += w0.x * ni[0] + w0.y * ni[1] + w0.z * ni[2]
                    + w0.w * ni[3] + w1.x * ni[4] + w1.y * ni[5]
                    + w1.z * ni[6] + w1.w * ni[7] + w8 * ni[8];
        }
    }
    #pragma unroll
    for (int oc = 0; oc < 8; ++oc)
        x1[(bt * Cc + cohalf * 8 + oc) * NPIX + gy * Ww + gx] = make_float2(ar[oc], ai[oc]);
}

// ---------------- 2D 64x64 complex FFT core, 256 threads -----------------------------
__device__ __forceinline__ void fft2d_256(float* re, float* im,
                                          const float* twr, const float* twi, int tid) {
    int lane = tid & 63;
    int wv = tid >> 6;
    for (int s = 0; s <= 5; ++s) {           // row pass: DIT
        __syncthreads();
        int hm = 1 << s;
        #pragma unroll
        for (int jj = 0; jj < 8; ++jj) {
            int j = wv * 8 + jj;
            int g = j >> s;
            int pos = j & (hm - 1);
            int i1 = g * (hm << 1) + pos;
            int i2 = i1 + hm;
            int twx = pos << (5 - s);
            float wr = twr[twx], wi = twi[twx];
            int a1 = lane * 65 + i1, a2 = lane * 65 + i2;
            float ar = re[a1], ai = im[a1];
            float br = re[a2], bi = im[a2];
            float tr = br * wr - bi * wi;
            float ti = br * wi + bi * wr;
            re[a1] = ar + tr; im[a1] = ai + ti;
            re[a2] = ar - tr; im[a2] = ai - ti;
        }
    }
    for (int s = 0; s <= 5; ++s) {           // column pass: DIF
        __syncthreads();
        int hm = 32 >> s;
        #pragma unroll
        for (int jj = 0; jj < 8; ++jj) {
            int j = wv * 8 + jj;
            int g = j >> (5 - s);
            int pos = j & (hm - 1);
            int i1 = g * (hm << 1) + pos;
            int i2 = i1 + hm;
            int twx = pos << s;
            float wr = twr[twx], wi = twi[twx];
            int a1 = i1 * 65 + lane, a2 = i2 * 65 + lane;
            float ar = re[a1], ai = im[a1];
            float br = re[a2], bi = im[a2];
            float sr = ar - br, si = ai - bi;
            re[a1] = ar + br; im[a1] = ai + bi;
            re[a2] = sr * wr - si * wi;
            im[a2] = sr * wi + si * wr;
        }
    }
    __syncthreads();
}

// ---------------- K2: X2f = fft2_std(x1) * (1 + filt) ----------------
__global__ __launch_bounds__(256)
void k_fft_fwd(const float2* __restrict__ x1,
               const float* __restrict__ spec_re, const float* __restrict__ spec_im,
               float2* __restrict__ X2f) {
    int img = blockIdx.x;
    int c = img % Cc;
    int tid = threadIdx.x;
    __shared__ float re[64 * 65], im[64 * 65];
    __shared__ float twr[32], twi[32];
    if (tid < 32) {
        float ang = -0.098174770424681038798f * (float)tid;
        twr[tid] = cosf(ang); twi[tid] = sinf(ang);
    }
    const float2* src = x1 + (size_t)img * NPIX;
    for (int idx = tid; idx < NPIX; idx += 256) {
        int h = idx >> 6, w = idx & 63;
        float2 v = src[idx];
        int wr_ = rev6(w);
        re[h * 65 + wr_] = v.x; im[h * 65 + wr_] = v.y;
    }
    fft2d_256(re, im, twr, twi, tid);
    const float* fr = spec_re + c * NPIX;
    const float* fi = spec_im + c * NPIX;
    float2* dst = X2f + (size_t)img * NPIX;
    for (int idx = tid; idx < NPIX; idx += 256) {
        int h = idx >> 6, w = idx & 63;
        int hr = rev6(h);
        float xr_ = re[hr * 65 + w], xi_ = im[hr * 65 + w];
        float gr = 1.f + fr[idx], gi = fi[idx];
        dst[idx] = make_float2(xr_ * gr - xi_ * gi, xi_ * gr + xr_ * gi);
    }
}

// ---------------- K3: Hermitian split + diagonal SSM scan over T ----------------------
__global__ __launch_bounds__(256)
void k_scan(const float2* __restrict__ X2f,
            const float* __restrict__ lam_re, const float* __restrict__ lam_im,
            const float* __restrict__ dt_param, const float* __restrict__ dtp,
            float2* __restrict__ Gre, float2* __restrict__ Gim) {
    int id = blockIdx.x * 256 + threadIdx.x;
    const int NB = Bb * Cc * Hh * WF;
    if (id >= NB) return;
    int w = id % WF; int r = id / WF;
    int h = r % Hh; r /= Hh;
    int c = r % Cc; int b = r / Cc;
    float dte = dtp[0] * sp_f(dt_param[c]);
    float ea = expf(-sp_f(lam_re[c]) * dte);
    float ph = lam_im[c] * dte;
    float Ar = ea * cosf(ph), Ai = ea * sinf(ph);
    int hm = (64 - h) & 63, wm = (64 - w) & 63;
    float gr_r = 0.f, gr_i = 0.f, gi_r = 0.f, gi_i = 0.f;
    for (int t = 0; t < Tt; ++t) {
        int ib = ((b * Tt + t) * Cc + c) * NPIX;
        float2 Z = X2f[ib + h * 64 + w];
        float2 Zm = X2f[ib + hm * 64 + wm];
        float ur_r = 0.5f * (Z.x + Zm.x), ur_i = 0.5f * (Z.y - Zm.y);
        float ui_r = 0.5f * (Z.y + Zm.y), ui_i = 0.5f * (Zm.x - Z.x);
        float nr = Ar * gr_r - Ai * gr_i + ur_r;
        float ni = Ar * gr_i + Ai * gr_r + ur_i;
        gr_r = nr; gr_i = ni;
        nr = Ar * gi_r - Ai * gi_i + ui_r;
        ni = Ar * gi_i + Ai * gi_r + ui_i;
        gi_r = nr; gi_i = ni;
        int ig = ((b * Tt + t) * Cc + c) * (Hh * WF) + h * WF + w;
        Gre[ig] = make_float2(gr_r, gr_i);
        Gim[ig] = make_float2(gi_r, gi_i);
    }
}

// ---------------- K5: field = ifft2_std(X2f + HermExt(sym(G))) + noise ----------------
__global__ __launch_bounds__(256)
void k_fft_inv(const float2* __restrict__ X2f,
               const float2* __restrict__ Gre, const float2* __restrict__ Gim,
               const float* __restrict__ noise_r, const float* __restrict__ noise_i,
               const float* __restrict__ sigma_p, const float* __restrict__ dts_p,
               float2* __restrict__ xf) {
    int img = blockIdx.x; int tid = threadIdx.x;
    __shared__ float re[64 * 65], im[64 * 65];
    __shared__ float twr[32], twi[32];
    if (tid < 32) {
        float ang = 0.098174770424681038798f * (float)tid;
        twr[tid] = cosf(ang); twi[tid] = sinf(ang);
    }
    const float2* src = X2f + (size_t)img * NPIX;
    int base = img * (Hh * WF);
    for (int idx = tid; idx < NPIX; idx += 256) {
        int h = idx >> 6, w = idx & 63;
        int hm = (64 - h) & 63;
        float zr, zi;
        if (w <= 32) {
            float2 a = Gre[base + h * WF + w];
            float2 bb = Gim[base + h * WF + w];
            if (w == 0 || w == 32) {
                float2 a2 = Gre[base + hm * WF + w];
                float2 b2 = Gim[base + hm * WF + w];
                a = make_float2(0.5f * (a.x + a2.x), 0.5f * (a.y - a2.y));
                bb = make_float2(0.5f * (bb.x + b2.x), 0.5f * (bb.y - b2.y));
            }
            zr = a.x - bb.y; zi = a.y + bb.x;
        } else {
            int wf = 64 - w;
            float2 a = Gre[base + hm * WF + wf];
            float2 bb = Gim[base + hm * WF + wf];
            zr = a.x + bb.y; zi = bb.x - a.y;
        }
        float2 s = src[idx];
        int wr_ = rev6(w);
        re[h * 65 + wr_] = s.x + zr; im[h * 65 + wr_] = s.y + zi;
    }
    fft2d_256(re, im, twr, twi, tid);
    float ns = sigma_p[0] * sqrtf(dts_p[0]);
    const float inv = 1.f / 4096.f;
    float2* dst = xf + (size_t)img * NPIX;
    const float* nr = noise_r + (size_t)img * NPIX;
    const float* ni = noise_i + (size_t)img * NPIX;
    for (int idx = tid; idx < NPIX; idx += 256) {
        int h = idx >> 6, w = idx & 63;
        int hr = rev6(h);
        dst[idx] = make_float2(re[hr * 65 + w] * inv + ns * nr[idx],
                               im[hr * 65 + w] * inv + ns * ni[idx]);
    }
}

// ---------------- K_prep: bf16 weight repack for MFMA PH layer ----------------
__global__ __launch_bounds__(256)
void k_prep(const float* __restrict__ JW, const float* __restrict__ Jb,
            const float* __restrict__ RW, const float* __restrict__ Rb,
            const float* __restrict__ W1, const float* __restrict__ dtp,
            const float* __restrict__ dt_param,
            ushort_t* __restrict__ B1t, ushort_t* __restrict__ B2t,
            ushort_t* __restrict__ w1n, ushort_t* __restrict__ w1t,
            float* __restrict__ dts_out) {
    const int N1 = 96 * 1152, N2 = 32 * 1152, N3 = 4096;
    int i = blockIdx.x * 256 + threadIdx.x;
    for (; i < N1 + N2 + N3; i += gridDim.x * 256) {
        if (i < N1) {
            int n = i / 1152, k = i % 1152;
            float v = 0.f;
            if (k < 1024) {
                int d = k >> 5, r = k & 31;
                if (n < 32)      v = JW[d * 1024 + n * 32 + r];
                else if (n < 64) v = JW[d * 1024 + r * 32 + (n - 32)];
                else             v = RW[d * 1024 + (n - 64) * 32 + r];
            } else if (k < 1056) {
                int r = k - 1024;
                if (n < 32)      v = Jb[n * 32 + r];
                else if (n < 64) v = Jb[r * 32 + (n - 32)];
                else             v = Rb[(n - 64) * 32 + r];
            }
            B1t[i] = f2bf(v);
        } else if (i < N1 + N2) {
            int i2 = i - N1;
            int n = i2 / 1152, k = i2 % 1152;
            float v = 0.f;
            if (k < 1024) {
                int d = k >> 5, kk = k & 31;
                v = RW[d * 1024 + kk * 32 + n];
            } else if (k < 1056) {
                v = Rb[(k - 1024) * 32 + n];
            }
            B2t[i2] = f2bf(v);
        } else {
            int i3 = i - N1 - N2;
            int d = i3 >> 7, h = i3 & 127;
            ushort_t v = f2bf(W1[i3]);
            w1n[i3] = v;
            w1t[h * 32 + d] = v;
        }
    }
    if (blockIdx.x == 0 && threadIdx.x == 0) {
        float s = 0.f;
        for (int c = 0; c < Cc; ++c) s += sp_f(dt_param[c]);
        dts_out[0] = dtp[0] * s * (1.f / Cc);
    }
}

// ---------------- K6: PH layer — M=128/block, LDS-staged B, 2x2 wave split ------------
__global__ __launch_bounds__(256, 2)
void k_ph(const float2* __restrict__ field,
          const float* __restrict__ ln_g, const float* __restrict__ ln_b,
          const float* __restrict__ b1, const float* __restrict__ w2,
          const ushort_t* __restrict__ w1n, const ushort_t* __restrict__ w1t,
          const ushort_t* __restrict__ B1t, const ushort_t* __restrict__ B2t,
          const float* __restrict__ dts_p,
          float* __restrict__ out) {
    __shared__ ushort_t xin_s[128 * 40];   // bf16 LN output (10240 B)
    __shared__ ushort_t g_s[128 * 40];     // bf16 grads
    __shared__ ushort_t pg_s[128 * 40];    // bf16 Pg
    __shared__ ushort_t A_s[128 * 136];    // t; aliases: LN red, B-stage [0,12288)B, upd f32 @16384B

    int tid = threadIdx.x;
    int bt = blockIdx.x >> 5;
    int pix0 = (blockIdx.x & 31) << 7;

    // ---- Phase 1: load field, LayerNorm -> xin_s (bf16) ----
    int p = tid & 127, half = tid >> 7;
    const float2* fbase = field + ((size_t)bt * 16) * NPIX + pix0 + p;
    float2 xv[8];
    float s1 = 0.f, s2 = 0.f;
    #pragma unroll
    for (int j = 0; j < 8; ++j) {
        xv[j] = fbase[(half * 8 + j) * NPIX];
        s1 += xv[j].x + xv[j].y;
        s2 += xv[j].x * xv[j].x + xv[j].y * xv[j].y;
    }
    float2* red = (float2*)A_s;
    red[p * 2 + half] = make_float2(s1, s2);
    __syncthreads();
    float2 r0 = red[p * 2], r1 = red[p * 2 + 1];
    float mu = (r0.x + r1.x) * 0.03125f;
    float var = (r0.y + r1.y) * 0.03125f - mu * mu;
    float rs = rsqrtf(var + 1e-5f);
    #pragma unroll
    for (int j = 0; j < 8; ++j) {
        int cf = half * 8 + j;
        xin_s[p * 40 + cf]      = f2bf((xv[j].x - mu) * rs * ln_g[cf] + ln_b[cf]);
        xin_s[p * 40 + cf + 16] = f2bf((xv[j].y - mu) * rs * ln_g[cf + 16] + ln_b[cf + 16]);
    }
    __syncthreads();

    int lane = tid & 63, wv = tid >> 6;
    int quad = lane >> 4, l15 = lane & 15;
    const f32x4 zero4 = {0.f, 0.f, 0.f, 0.f};

    // ---- z GEMM: z[128][128] = xin @ W1 (K=32); each wave owns rows wv*32..+31 ----
    int m0z = wv * 32;
    f32x4 zacc[2][8];
    #pragma unroll
    for (int mt = 0; mt < 2; ++mt)
        #pragma unroll
        for (int nt = 0; nt < 8; ++nt) zacc[mt][nt] = zero4;
    U16 az[2];
    #pragma unroll
    for (int mt = 0; mt < 2; ++mt)
        az[mt].u = *(const uint4*)&xin_s[(m0z + mt * 16 + l15) * 40 + quad * 8];
    #pragma unroll
    for (int nt = 0; nt < 8; ++nt) {
        U16 bz;
        bz.u = *(const uint4*)&w1t[(nt * 16 + l15) * 32 + quad * 8];
        zacc[0][nt] = MFMA16(az[0].s, bz.s, zacc[0][nt]);
        zacc[1][nt] = MFMA16(az[1].s, bz.s, zacc[1][nt]);
    }
    #pragma unroll
    for (int nt = 0; nt < 8; ++nt) {
        int col = nt * 16 + l15;
        float b1v = b1[col], w2v = w2[col];
        #pragma unroll
        for (int mt = 0; mt < 2; ++mt) {
            #pragma unroll
            for (int r = 0; r < 4; ++r) {
                int row = m0z + mt * 16 + quad * 4 + r;
                float z = zacc[mt][nt][r] + b1v;
                float s = 1.f / (1.f + expf(-z));
                float t = s * (1.f + z * (1.f - s)) * w2v;
                A_s[row * 136 + col] = f2bf(t);
            }
        }
    }

    // ---- g GEMM: g[128][32] = t @ W1^T (K=128), own-wave rows ----
    f32x4 gacc[2][2];
    #pragma unroll
    for (int mt = 0; mt < 2; ++mt)
        #pragma unroll
        for (int nt = 0; nt < 2; ++nt) gacc[mt][nt] = zero4;
    #pragma unroll
    for (int q = 0; q < 4; ++q) {
        U16 ag[2];
        #pragma unroll
        for (int mt = 0; mt < 2; ++mt)
            ag[mt].u = *(const uint4*)&A_s[(m0z + mt * 16 + l15) * 136 + q * 32 + quad * 8];
        #pragma unroll
        for (int nt = 0; nt < 2; ++nt) {
            U16 bg;
            bg.u = *(const uint4*)&w1n[(nt * 16 + l15) * 128 + q * 32 + quad * 8];
            gacc[0][nt] = MFMA16(ag[0].s, bg.s, gacc[0][nt]);
            gacc[1][nt] = MFMA16(ag[1].s, bg.s, gacc[1][nt]);
        }
    }
    #pragma unroll
    for (int mt = 0; mt < 2; ++mt)
        #pragma unroll
        for (int nt = 0; nt < 2; ++nt)
            #pragma unroll
            for (int r = 0; r < 4; ++r)
                g_s[(m0z + mt * 16 + quad * 4 + r) * 40 + nt * 16 + l15] = f2bf(gacc[mt][nt][r]);
    __syncthreads();   // g_s/xin_s cross-wave visible; t dead -> staging may reuse A_s

    // ---- pass setup: wave = (mh, nh); cache x rows + g rows in registers ----
    int mh = wv & 1, nh = wv >> 1;
    ushort_t* stage = A_s;                     // 2 x 3072 ushorts (6 KB each buffer)
    uint_t xw[4][16];
    uint4 gvp[4];
    float gf[4][8];
    #pragma unroll
    for (int mt = 0; mt < 4; ++mt) {
        int row = mh * 64 + mt * 16 + l15;
        #pragma unroll
        for (int q = 0; q < 4; ++q)
            *(uint4*)&xw[mt][q * 4] = *(const uint4*)&xin_s[row * 40 + q * 8];
        gvp[mt] = *(const uint4*)&g_s[row * 40 + quad * 8];
        expand8(gvp[mt], gf[mt]);
    }

    // ---- pass 1: [Mg | Mt g | Pg] = o @ B1t^T, s = 0..32 (32 = bias), B staged in LDS --
    // staging: chunk nt covers rows nt*16..+15, 64 B/row; one wave-issue per chunk
    {   // prestage s=0
        int s = 0;
        const ushort_t* gp;
        if (wv == 0) {
            gp = B1t + (0 * 16 + l15) * 1152 + s * 32 + quad * 8;  // lane: row=l15,kq=quad
            gload_lds16(gp, stage + 0 * 512);
            gp = B1t + (4 * 16 + (lane & 15)) * 1152 + s * 32 + (lane >> 4) * 8;
            gload_lds16(gp, stage + 4 * 512);
        } else if (wv == 1) {
            gp = B1t + (1 * 16 + (lane & 15)) * 1152 + s * 32 + (lane >> 4) * 8;
            gload_lds16(gp, stage + 1 * 512);
            gp = B1t + (5 * 16 + (lane & 15)) * 1152 + s * 32 + (lane >> 4) * 8;
            gload_lds16(gp, stage + 5 * 512);
        } else if (wv == 2) {
            gp = B1t + (2 * 16 + (lane & 15)) * 1152 + s * 32 + (lane >> 4) * 8;
            gload_lds16(gp, stage + 2 * 512);
        } else {
            gp = B1t + (3 * 16 + (lane & 15)) * 1152 + s * 32 + (lane >> 4) * 8;
            gload_lds16(gp, stage + 3 * 512);
        }
    }
    f32x4 acc1[3][4];
    #pragma unroll
    for (int j = 0; j < 3; ++j)
        #pragma unroll
        for (int mt = 0; mt < 4; ++mt) acc1[j][mt] = zero4;
    #pragma unroll
    for (int s = 0; s < 33; ++s) {
        __syncthreads();                        // staging of step s complete
        int par = s & 1;
        if (s < 32) {                           // prefetch s+1 into other buffer
            int sn = s + 1, pn = sn & 1;
            const ushort_t* gp;
            if (wv == 0) {
                gp = B1t + (0 * 16 + (lane & 15)) * 1152 + sn * 32 + (lane >> 4) * 8;
                gload_lds16(gp, stage + pn * 3072 + 0 * 512);
                gp = B1t + (4 * 16 + (lane & 15)) * 1152 + sn * 32 + (lane >> 4) * 8;
                gload_lds16(gp, stage + pn * 3072 + 4 * 512);
            } else if (wv == 1) {
                gp = B1t + (1 * 16 + (lane & 15)) * 1152 + sn * 32 + (lane >> 4) * 8;
                gload_lds16(gp, stage + pn * 3072 + 1 * 512);
                gp = B1t + (5 * 16 + (lane & 15)) * 1152 + sn * 32 + (lane >> 4) * 8;
                gload_lds16(gp, stage + pn * 3072 + 5 * 512);
            } else if (wv == 2) {
                gp = B1t + (2 * 16 + (lane & 15)) * 1152 + sn * 32 + (lane >> 4) * 8;
                gload_lds16(gp, stage + pn * 3072 + 2 * 512);
            } else {
                gp = B1t + (3 * 16 + (lane & 15)) * 1152 + sn * 32 + (lane >> 4) * 8;
                gload_lds16(gp, stage + pn * 3072 + 3 * 512);
            }
        }
        U16 bfr[3];
        #pragma unroll
        for (int j = 0; j < 3; ++j)
            bfr[j].u = *(const uint4*)&stage[par * 3072 + (nh + 2 * j) * 512 + lane * 8];
        #pragma unroll
        for (int mt = 0; mt < 4; ++mt) {
            U16 a;
            if (s < 32) {
                uint_t u = xw[mt][s >> 1];
                float xs = (s & 1) ? __uint_as_float(u & 0xffff0000u)
                                   : __uint_as_float(u << 16);
                a.u = synth8(gf[mt], xs);
            } else {
                a.u = gvp[mt];
            }
            #pragma unroll
            for (int j = 0; j < 3; ++j)
                acc1[j][mt] = MFMA16(a.s, bfr[j].s, acc1[j][mt]);
        }
    }
    // um = Mg - Mt g (this wave's 16 cols); Pg -> pg_s
    f32x4 um[4];
    #pragma unroll
    for (int mt = 0; mt < 4; ++mt) {
        um[mt] = acc1[0][mt] - acc1[1][mt];
        #pragma unroll
        for (int r = 0; r < 4; ++r)
            pg_s[(mh * 64 + mt * 16 + quad * 4 + r) * 40 + nh * 16 + l15] = f2bf(acc1[2][mt][r]);
    }
    __syncthreads();                            // pg_s visible; pass-1 staging reads done

    // ---- pass 2: ptpg = v @ B2t^T, v = x (x) pg ----
    uint4 pgp[4];
    float pgf[4][8];
    #pragma unroll
    for (int mt = 0; mt < 4; ++mt) {
        int row = mh * 64 + mt * 16 + l15;
        pgp[mt] = *(const uint4*)&pg_s[row * 40 + quad * 8];
        expand8(pgp[mt], pgf[mt]);
    }
    {   // prestage s=0 (chunks 0,1 by waves 2,3)
        if (wv == 2) {
            const ushort_t* gp = B2t + (0 * 16 + (lane & 15)) * 1152 + 0 + (lane >> 4) * 8;
            gload_lds16(gp, stage + 0 * 512);
        } else if (wv == 3) {
            const ushort_t* gp = B2t + (1 * 16 + (lane & 15)) * 1152 + 0 + (lane >> 4) * 8;
            gload_lds16(gp, stage + 1 * 512);
        }
    }
    f32x4 acc2[4];
    #pragma unroll
    for (int mt = 0; mt < 4; ++mt) acc2[mt] = zero4;
    #pragma unroll
    for (int s = 0; s < 33; ++s) {
        __syncthreads();
        int par = s & 1;
        if (s < 32) {
            int sn = s + 1, pn = sn & 1;
            if (wv == 2) {
                const ushort_t* gp = B2t + (0 * 16 + (lane & 15)) * 1152 + sn * 32 + (lane >> 4) * 8;
                gload_lds16(gp, stage + pn * 3072 + 0 * 512);
            } else if (wv == 3) {
                const ushort_t* gp = B2t + (1 * 16 + (lane & 15)) * 1152 + sn * 32 + (lane >> 4) * 8;
                gload_lds16(gp, stage + pn * 3072 + 1 * 512);
            }
        }
        U16 bfr;
        bfr.u = *(const uint4*)&stage[par * 3072 + nh * 512 + lane * 8];
        #pragma unroll
        for (int mt = 0; mt < 4; ++mt) {
            U16 a;
            if (s < 32) {
                uint_t u = xw[mt][s >> 1];
                float xs = (s & 1) ? __uint_as_float(u & 0xffff0000u)
                                   : __uint_as_float(u << 16);
                a.u = synth8(pgf[mt], xs);
            } else {
                a.u = pgp[mt];
            }
            acc2[mt] = MFMA16(a.s, bfr.s, acc2[mt]);
        }
    }

    // ---- epilogue: upd = um - ptpg - 1e-4 g -> LDS f32, combine + write ----
    __syncthreads();                            // all staging reads done; reuse region
    float* upd = (float*)&A_s[8192];            // byte offset 16384, past stage (12288)
    #pragma unroll
    for (int mt = 0; mt < 4; ++mt) {
        int col = nh * 16 + l15;
        #pragma unroll
        for (int r = 0; r < 4; ++r) {
            int row = mh * 64 + mt * 16 + quad * 4 + r;
            float gval = bf2f(g_s[row * 40 + col]);
            upd[row * 33 + col] = um[mt][r] - acc2[mt][r] - 1e-4f * gval;
        }
    }
    __syncthreads();
    float dts = dts_p[0];
    #pragma unroll
    for (int cc = 0; cc < 16; ++cc) {
        int c = half * 16 + cc;
        float2 v = fbase[cc * NPIX];
        float xcv = half ? v.y : v.x;
        out[((size_t)bt * 32 + c) * NPIX + pix0 + p] = xcv + dts * upd[p * 33 + c];
    }
}

extern "C" void kernel_launch(void* const* d_in, const int* in_sizes, int n_in,
                              void* d_out, int out_size, void* d_ws, size_t ws_size,
                              hipStream_t stream) {
    const float* x_real   = (const float*)d_in[0];
    const float* x_imag   = (const float*)d_in[1];
    const float* dt       = (const float*)d_in[2];
    const float* conv_w   = (const float*)d_in[3];
    const float* conv_b   = (const float*)d_in[4];
    const float* spec_re  = (const float*)d_in[5];
    const float* spec_im  = (const float*)d_in[6];
    const float* lam_re   = (const float*)d_in[7];
    const float* lam_im   = (const float*)d_in[8];
    const float* dt_param = (const float*)d_in[9];
    const float* sigma    = (const float*)d_in[10];
    const float* noise_r  = (const float*)d_in[11];
    const float* noise_i  = (const float*)d_in[12];
    const float* ln_g     = (const float*)d_in[13];
    const float* ln_b     = (const float*)d_in[14];
    const float* W1       = (const float*)d_in[15];
    const float* b1       = (const float*)d_in[16];
    const float* w2       = (const float*)d_in[17];
    const float* Jg_W     = (const float*)d_in[19];
    const float* Jg_b     = (const float*)d_in[20];
    const float* Rg_W     = (const float*)d_in[21];
    const float* Rg_b     = (const float*)d_in[22];

    float2* wsA = (float2*)d_ws;              // x1, later final field (1048576 float2)
    float2* wsB = wsA + 1048576;              // X2f spectrum
    float2* wsC = wsB + 1048576;              // Gre (540672 float2)
    float2* wsD = wsC + 540672;               // Gim

    ushort_t* B1t = (ushort_t*)(wsD + 540672);
    ushort_t* B2t = B1t + 96 * 1152;
    ushort_t* w1n = B2t + 32 * 1152;
    ushort_t* w1t = w1n + 4096;
    float*    dts = (float*)(w1t + 4096);

    k_prep<<<160, 256, 0, stream>>>(Jg_W, Jg_b, Rg_W, Rg_b, W1, dt, dt_param,
                                    B1t, B2t, w1n, w1t, dts);
    k_conv<<<512, 256, 0, stream>>>(x_real, x_imag, conv_w, conv_b, wsA);
    k_fft_fwd<<<NIMG, 256, 0, stream>>>(wsA, spec_re, spec_im, wsB);
    k_scan<<<264, 256, 0, stream>>>(wsB, lam_re, lam_im, dt_param, dt, wsC, wsD);
    k_fft_inv<<<NIMG, 256, 0, stream>>>(wsB, wsC, wsD, noise_r, noise_i, sigma, dts, wsA);
    k_ph<<<512, 256, 0, stream>>>(wsA, ln_g, ln_b, b1, w2, w1n, w1t, B1t, B2t, dts,
                                  (float*)d_out);
}

// Round 5
// 213.744 us; speedup vs baseline: 5.0963x; 1.1581x over previous
//
#include <hip/hip_runtime.h>
#include <math.h>

#define Bb 2
#define Tt 8
#define Cc 16
#define Hh 64
#define Ww 64
#define Dd 32
#define HID 128
#define NPIX 4096
#define NIMG 256   // B*T*C

typedef unsigned short ushort_t;
typedef unsigned int uint_t;
typedef __attribute__((ext_vector_type(8))) short short8;
typedef __attribute__((ext_vector_type(4))) float f32x4;
union U16 { uint4 u; short8 s; };

__device__ __forceinline__ float sp_f(float x) {           // softplus
    return (x > 20.f) ? x : log1pf(expf(x));
}

__device__ __forceinline__ ushort_t f2bf(float f) {        // round-to-nearest-even
    uint_t u = __float_as_uint(f);
    uint_t r = (u + 0x7fffu + ((u >> 16) & 1u)) >> 16;
    return (ushort_t)r;
}
__device__ __forceinline__ float bf2f(ushort_t h) { return __uint_as_float(((uint_t)h) << 16); }

// pack two f32 (truncate) into bf16 pair via v_perm_b32
__device__ __forceinline__ uint_t packbf(float hi, float lo) {
    return __builtin_amdgcn_perm(__float_as_uint(hi), __float_as_uint(lo), 0x07060302u);
}
__device__ __forceinline__ uint4 synth8(const float* gf, float xs) {
    uint4 r;
    r.x = packbf(gf[1] * xs, gf[0] * xs);
    r.y = packbf(gf[3] * xs, gf[2] * xs);
    r.z = packbf(gf[5] * xs, gf[4] * xs);
    r.w = packbf(gf[7] * xs, gf[6] * xs);
    return r;
}
__device__ __forceinline__ void expand8(uint4 v, float* f) {
    f[0] = __uint_as_float(v.x << 16); f[1] = __uint_as_float(v.x & 0xffff0000u);
    f[2] = __uint_as_float(v.y << 16); f[3] = __uint_as_float(v.y & 0xffff0000u);
    f[4] = __uint_as_float(v.z << 16); f[5] = __uint_as_float(v.z & 0xffff0000u);
    f[6] = __uint_as_float(v.w << 16); f[7] = __uint_as_float(v.w & 0xffff0000u);
}

typedef __attribute__((address_space(1))) const void cgvoid;
typedef __attribute__((address_space(3))) void svoid;
__device__ __forceinline__ void gload_lds16(const void* g, void* l) {
    __builtin_amdgcn_global_load_lds((cgvoid*)g, (svoid*)l, 16, 0, 0);
}

#define MFMA16(a, b, c) __builtin_amdgcn_mfma_f32_16x16x32_bf16((a), (b), (c), 0, 0, 0)

// ---------------- complex helpers + DFT8 ----------------
struct cpx { float r, i; };
__device__ __forceinline__ cpx cadd(cpx a, cpx b) { return {a.r + b.r, a.i + b.i}; }
__device__ __forceinline__ cpx csub(cpx a, cpx b) { return {a.r - b.r, a.i - b.i}; }
__device__ __forceinline__ cpx cmulw(cpx a, float wr, float wi) {
    return {a.r * wr - a.i * wi, a.r * wi + a.i * wr};
}
template<int S>
__device__ __forceinline__ cpx cmulSi(cpx a) {   // a * (S*i)
    return {-(float)S * a.i, (float)S * a.r};
}
// Y[k] = sum_n y[n] e^{S*2pi*i*n*k/8}, in place
template<int S>
__device__ __forceinline__ void dft8(cpx* y) {
    const float C = 0.70710678118654752f;
    cpx t0 = cadd(y[0], y[4]), t1 = csub(y[0], y[4]);
    cpx t2 = cadd(y[2], y[6]), t3 = csub(y[2], y[6]);
    cpx e0 = cadd(t0, t2), e2 = csub(t0, t2);
    cpx t3i = cmulSi<S>(t3);
    cpx e1 = cadd(t1, t3i), e3 = csub(t1, t3i);
    cpx u0 = cadd(y[1], y[5]), u1 = csub(y[1], y[5]);
    cpx u2 = cadd(y[3], y[7]), u3 = csub(y[3], y[7]);
    cpx o0 = cadd(u0, u2), o2 = csub(u0, u2);
    cpx u3i = cmulSi<S>(u3);
    cpx o1 = cadd(u1, u3i), o3 = csub(u1, u3i);
    o1 = cmulw(o1, C, (float)S * C);
    o2 = cmulSi<S>(o2);
    o3 = cmulw(o3, -C, (float)S * C);
    y[0] = cadd(e0, o0); y[4] = csub(e0, o0);
    y[1] = cadd(e1, o1); y[5] = csub(e1, o1);
    y[2] = cadd(e2, o2); y[6] = csub(e2, o2);
    y[3] = cadd(e3, o3); y[7] = csub(e3, o3);
}

// 2D 64x64 radix-8 FFT, 256 threads, natural in / natural out, in-place in reM/imM.
// tw[m] = e^{S*2pi*i*m/64}. 7 barriers total (incl. caller's post-load one = entry state).
template<int S>
__device__ __forceinline__ void fft2d_r8(float* reM, float* imM,
                                         const float* twr, const float* twi, int tid) {
    int j = tid & 63, q = tid >> 6;
    // ---- row pass, stage A (in-place: each thread owns residue class n2) ----
    #pragma unroll
    for (int nn = 0; nn < 2; ++nn) {
        int n2 = q * 2 + nn;
        cpx y[8];
        #pragma unroll
        for (int n1 = 0; n1 < 8; ++n1) {
            int a = j * 65 + n1 * 8 + n2;
            y[n1] = {reM[a], imM[a]};
        }
        dft8<S>(y);
        #pragma unroll
        for (int k1 = 0; k1 < 8; ++k1) {
            int m = (n2 * k1) & 63;
            cpx b = cmulw(y[k1], twr[m], twi[m]);
            int a = j * 65 + k1 * 8 + n2;
            reM[a] = b.r; imM[a] = b.i;
        }
    }
    __syncthreads();
    // ---- row pass, stage B (read -> barrier -> write) ----
    cpx yb[2][8];
    #pragma unroll
    for (int kk = 0; kk < 2; ++kk) {
        int k1 = q * 2 + kk;
        #pragma unroll
        for (int n2 = 0; n2 < 8; ++n2) {
            int a = j * 65 + k1 * 8 + n2;
            yb[kk][n2] = {reM[a], imM[a]};
        }
        dft8<S>(yb[kk]);
    }
    __syncthreads();
    #pragma unroll
    for (int kk = 0; kk < 2; ++kk) {
        int k1 = q * 2 + kk;
        #pragma unroll
        for (int k2 = 0; k2 < 8; ++k2) {
            int a = j * 65 + k1 + k2 * 8;
            reM[a] = yb[kk][k2].r; imM[a] = yb[kk][k2].i;
        }
    }
    __syncthreads();
    // ---- column pass, stage A (in-place) ----
    #pragma unroll
    for (int nn = 0; nn < 2; ++nn) {
        int n2 = q * 2 + nn;
        cpx y[8];
        #pragma unroll
        for (int n1 = 0; n1 < 8; ++n1) {
            int a = (n1 * 8 + n2) * 65 + j;
            y[n1] = {reM[a], imM[a]};
        }
        dft8<S>(y);
        #pragma unroll
        for (int k1 = 0; k1 < 8; ++k1) {
            int m = (n2 * k1) & 63;
            cpx b = cmulw(y[k1], twr[m], twi[m]);
            int a = (k1 * 8 + n2) * 65 + j;
            reM[a] = b.r; imM[a] = b.i;
        }
    }
    __syncthreads();
    // ---- column pass, stage B ----
    #pragma unroll
    for (int kk = 0; kk < 2; ++kk) {
        int k1 = q * 2 + kk;
        #pragma unroll
        for (int n2 = 0; n2 < 8; ++n2) {
            int a = (k1 * 8 + n2) * 65 + j;
            yb[kk][n2] = {reM[a], imM[a]};
        }
        dft8<S>(yb[kk]);
    }
    __syncthreads();
    #pragma unroll
    for (int kk = 0; kk < 2; ++kk) {
        int k1 = q * 2 + kk;
        #pragma unroll
        for (int k2 = 0; k2 < 8; ++k2) {
            int a = (k1 + k2 * 8) * 65 + j;
            reM[a] = yb[kk][k2].r; imM[a] = yb[kk][k2].i;
        }
    }
    __syncthreads();
}

// ---------------- K1: conv (blocks 0..511) + weight prep (blocks 512..551) -----------
__global__ __launch_bounds__(256)
void k_conv(const float* __restrict__ xr, const float* __restrict__ xi,
            const float* __restrict__ cw, const float* __restrict__ cb,
            float2* __restrict__ x1,
            const float* __restrict__ JW, const float* __restrict__ Jb,
            const float* __restrict__ RW, const float* __restrict__ Rb,
            const float* __restrict__ W1, const float* __restrict__ dtp,
            const float* __restrict__ dt_param,
            ushort_t* __restrict__ B1t, ushort_t* __restrict__ B2t,
            ushort_t* __restrict__ w1n, ushort_t* __restrict__ w1t,
            float* __restrict__ dts_out) {
    __shared__ float sre[Cc][18][18];
    __shared__ float sim[Cc][18][18];
    __shared__ float swt[8 * 16 * 12];
    __shared__ float sb[8];
    int tid = threadIdx.x;
    if (blockIdx.x >= 512) {                   // ---- prep path ----
        const int N1 = 96 * 1152, N2 = 32 * 1152, N3 = 4096;
        int i = (blockIdx.x - 512) * 256 + tid;
        for (; i < N1 + N2 + N3; i += 40 * 256) {
            if (i < N1) {
                int n = i / 1152, k = i % 1152;
                float v = 0.f;
                if (k < 1024) {
                    int d = k >> 5, r = k & 31;
                    if (n < 32)      v = JW[d * 1024 + n * 32 + r];
                    else if (n < 64) v = JW[d * 1024 + r * 32 + (n - 32)];
                    else             v = RW[d * 1024 + (n - 64) * 32 + r];
                } else if (k < 1056) {
                    int r = k - 1024;
                    if (n < 32)      v = Jb[n * 32 + r];
                    else if (n < 64) v = Jb[r * 32 + (n - 32)];
                    else             v = Rb[(n - 64) * 32 + r];
                }
                B1t[i] = f2bf(v);
            } else if (i < N1 + N2) {
                int i2 = i - N1;
                int n = i2 / 1152, k = i2 % 1152;
                float v = 0.f;
                if (k < 1024) {
                    int d = k >> 5, kk = k & 31;
                    v = RW[d * 1024 + kk * 32 + n];
                } else if (k < 1056) {
                    v = Rb[(k - 1024) * 32 + n];
                }
                B2t[i2] = f2bf(v);
            } else {
                int i3 = i - N1 - N2;
                int d = i3 >> 7, h = i3 & 127;
                ushort_t v = f2bf(W1[i3]);
                w1n[i3] = v;
                w1t[h * 32 + d] = v;
            }
        }
        if (blockIdx.x == 512 && tid == 0) {
            float s = 0.f;
            for (int c = 0; c < Cc; ++c) s += sp_f(dt_param[c]);
            dts_out[0] = dtp[0] * s * (1.f / Cc);
        }
        return;
    }
    // ---- conv path ----
    int blk = blockIdx.x;
    int bt = blk >> 5;
    int sub = blk & 31;
    int tile = sub >> 1, cohalf = sub & 1;
    int ty0 = (tile >> 2) * 16, tx0 = (tile & 3) * 16;
    for (int i = tid; i < 8 * 16 * 9; i += 256) {
        int g = i / 9, k = i % 9;
        swt[g * 12 + k] = cw[cohalf * 8 * 144 + i];
    }
    if (tid < 8) sb[tid] = cb[cohalf * 8 + tid];
    for (int i = tid; i < Cc * 18 * 18; i += 256) {
        int ci = i / 324; int r = i % 324; int y = r / 18, x = r % 18;
        int gy = ty0 + y - 1, gx = tx0 + x - 1;
        float vr = 0.f, vi = 0.f;
        if (gy >= 0 && gy < Hh && gx >= 0 && gx < Ww) {
            int gidx = (bt * Cc + ci) * NPIX + gy * Ww + gx;
            vr = xr[gidx]; vi = xi[gidx];
        }
        sre[ci][y][x] = vr; sim[ci][y][x] = vi;
    }
    __syncthreads();
    int py = tid >> 4, px = tid & 15;
    int gy = ty0 + py, gx = tx0 + px;
    float ar[8], ai[8];
    #pragma unroll
    for (int oc = 0; oc < 8; ++oc) {
        int cg = cohalf * 8 + oc;
        ar[oc] = sre[cg][py + 1][px + 1] + sb[oc];
        ai[oc] = sim[cg][py + 1][px + 1] + sb[oc];
    }
    for (int ci = 0; ci < Cc; ++ci) {
        float nr[9], ni[9];
        #pragma unroll
        for (int dy = 0; dy < 3; ++dy)
            #pragma unroll
            for (int dx = 0; dx < 3; ++dx) {
                nr[dy * 3 + dx] = sre[ci][py + dy][px + dx];
                ni[dy * 3 + dx] = sim[ci][py + dy][px + dx];
            }
        #pragma unroll
        for (int oc = 0; oc < 8; ++oc) {
            const float* wp = &swt[(oc * 16 + ci) * 12];
            float4 w0 = *(const float4*)&wp[0];
            float4 w1 = *(const float4*)&wp[4];
            float w8 = wp[8];
            ar[oc] += w0.x * nr[0] + w0.y * nr[1] + w0.z * nr[2]
                    + w0.w * nr[3] + w1.x * nr[4] + w1.y * nr[5]
                    + w1.z * nr[6] + w1.w * nr[7] + w8 * nr[8];
            ai[oc] += w0.x * ni[0] + w0.y * ni[1] + w0.z * ni[2]
                    + w0.w * ni[3] + w1.x * ni[4] + w1.y * ni[5]
                    + w1.z * ni[6] + w1.w * ni[7] + w8 * ni[8];
        }
    }
    #pragma unroll
    for (int oc = 0; oc < 8; ++oc)
        x1[(bt * Cc + cohalf * 8 + oc) * NPIX + gy * Ww + gx] = make_float2(ar[oc], ai[oc]);
}

// ---------------- K2: X2f = fft2_std(x1) * (1 + filt), natural order ------------------
__global__ __launch_bounds__(256)
void k_fft_fwd(const float2* __restrict__ x1,
               const float* __restrict__ spec_re, const float* __restrict__ spec_im,
               float2* __restrict__ X2f) {
    int img = blockIdx.x;
    int c = img % Cc;
    int tid = threadIdx.x;
    __shared__ float re[64 * 65], im[64 * 65];
    __shared__ float twr[64], twi[64];
    if (tid < 64) {
        float ang = -0.098174770424681038798f * (float)tid;  // S=-1
        twr[tid] = cosf(ang); twi[tid] = sinf(ang);
    }
    const float2* src = x1 + (size_t)img * NPIX;
    for (int idx = tid; idx < NPIX; idx += 256) {
        int h = idx >> 6, w = idx & 63;
        float2 v = src[idx];
        re[h * 65 + w] = v.x; im[h * 65 + w] = v.y;
    }
    __syncthreads();
    fft2d_r8<-1>(re, im, twr, twi, tid);
    const float* fr = spec_re + c * NPIX;
    const float* fi = spec_im + c * NPIX;
    float2* dst = X2f + (size_t)img * NPIX;
    for (int idx = tid; idx < NPIX; idx += 256) {
        int h = idx >> 6, w = idx & 63;
        float xr_ = re[h * 65 + w], xi_ = im[h * 65 + w];
        float gr = 1.f + fr[idx], gi = fi[idx];
        dst[idx] = make_float2(xr_ * gr - xi_ * gi, xi_ * gr + xr_ * gi);
    }
}

// ---------------- K3: scan2 — S = Z + z, z = per-half conj-coeff scan of Z ------------
// w in 1..31: z = scan_A(Z); w in 33..63: z = scan_conj(A)(Z); w in {0,32}: mean of both.
__global__ __launch_bounds__(256)
void k_scan2(const float2* __restrict__ Z,
             const float* __restrict__ lam_re, const float* __restrict__ lam_im,
             const float* __restrict__ dt_param, const float* __restrict__ dtp,
             float2* __restrict__ S) {
    int id = blockIdx.x * 256 + threadIdx.x;      // 131072 = B*C*H*W
    int w = id & 63;
    int c = (id >> 12) & 15;
    int b = id >> 16;
    float dte = dtp[0] * sp_f(dt_param[c]);
    float ea = expf(-sp_f(lam_re[c]) * dte);
    float ph = lam_im[c] * dte;
    float Ar = ea * cosf(ph), Ai = ea * sinf(ph);
    if (w > 32) Ai = -Ai;
    bool sc = (w == 0) || (w == 32);
    int pix = id & (NPIX - 1);
    int base = (b * Tt * Cc + c) * NPIX + pix;
    float s1r = 0.f, s1i = 0.f, s2r = 0.f, s2i = 0.f;
    #pragma unroll
    for (int t = 0; t < Tt; ++t) {
        int idx = base + t * (Cc * NPIX);
        float2 zv = Z[idx];
        float nr = Ar * s1r - Ai * s1i + zv.x;
        float ni = Ar * s1i + Ai * s1r + zv.y;
        s1r = nr; s1i = ni;
        float zr, zi;
        if (sc) {
            nr = Ar * s2r + Ai * s2i + zv.x;      // conjugate coefficient
            ni = Ar * s2i - Ai * s2r + zv.y;
            s2r = nr; s2i = ni;
            zr = 0.5f * (s1r + s2r); zi = 0.5f * (s1i + s2i);
        } else { zr = s1r; zi = s1i; }
        S[idx] = make_float2(zv.x + zr, zv.y + zi);
    }
}

// ---------------- K5: field = ifft2_std(S) + noise ----------------
__global__ __launch_bounds__(256)
void k_fft_inv(const float2* __restrict__ Sp,
               const float* __restrict__ noise_r, const float* __restrict__ noise_i,
               const float* __restrict__ sigma_p, const float* __restrict__ dts_p,
               float2* __restrict__ xf) {
    int img = blockIdx.x; int tid = threadIdx.x;
    __shared__ float re[64 * 65], im[64 * 65];
    __shared__ float twr[64], twi[64];
    if (tid < 64) {
        float ang = 0.098174770424681038798f * (float)tid;   // S=+1
        twr[tid] = cosf(ang); twi[tid] = sinf(ang);
    }
    const float2* src = Sp + (size_t)img * NPIX;
    for (int idx = tid; idx < NPIX; idx += 256) {
        int h = idx >> 6, w = idx & 63;
        float2 v = src[idx];
        re[h * 65 + w] = v.x; im[h * 65 + w] = v.y;
    }
    __syncthreads();
    fft2d_r8<1>(re, im, twr, twi, tid);
    float ns = sigma_p[0] * sqrtf(dts_p[0]);
    const float inv = 1.f / 4096.f;
    float2* dst = xf + (size_t)img * NPIX;
    const float* nr = noise_r + (size_t)img * NPIX;
    const float* ni = noise_i + (size_t)img * NPIX;
    for (int idx = tid; idx < NPIX; idx += 256) {
        int h = idx >> 6, w = idx & 63;
        dst[idx] = make_float2(re[h * 65 + w] * inv + ns * nr[idx],
                               im[h * 65 + w] * inv + ns * ni[idx]);
    }
}

// ---------------- K6: PH layer — M=128/block, LDS-staged B, 2x2 wave split ------------
__global__ __launch_bounds__(256, 2)
void k_ph(const float2* __restrict__ field,
          const float* __restrict__ ln_g, const float* __restrict__ ln_b,
          const float* __restrict__ b1, const float* __restrict__ w2,
          const ushort_t* __restrict__ w1n, const ushort_t* __restrict__ w1t,
          const ushort_t* __restrict__ B1t, const ushort_t* __restrict__ B2t,
          const float* __restrict__ dts_p,
          float* __restrict__ out) {
    __shared__ ushort_t xin_s[128 * 40];
    __shared__ ushort_t g_s[128 * 40];
    __shared__ ushort_t pg_s[128 * 40];
    __shared__ ushort_t A_s[128 * 136];

    int tid = threadIdx.x;
    int bt = blockIdx.x >> 5;
    int pix0 = (blockIdx.x & 31) << 7;

    int p = tid & 127, half = tid >> 7;
    const float2* fbase = field + ((size_t)bt * 16) * NPIX + pix0 + p;
    float2 xv[8];
    float s1 = 0.f, s2 = 0.f;
    #pragma unroll
    for (int j = 0; j < 8; ++j) {
        xv[j] = fbase[(half * 8 + j) * NPIX];
        s1 += xv[j].x + xv[j].y;
        s2 += xv[j].x * xv[j].x + xv[j].y * xv[j].y;
    }
    float2* red = (float2*)A_s;
    red[p * 2 + half] = make_float2(s1, s2);
    __syncthreads();
    float2 r0 = red[p * 2], r1 = red[p * 2 + 1];
    float mu = (r0.x + r1.x) * 0.03125f;
    float var = (r0.y + r1.y) * 0.03125f - mu * mu;
    float rs = rsqrtf(var + 1e-5f);
    #pragma unroll
    for (int j = 0; j < 8; ++j) {
        int cf = half * 8 + j;
        xin_s[p * 40 + cf]      = f2bf((xv[j].x - mu) * rs * ln_g[cf] + ln_b[cf]);
        xin_s[p * 40 + cf + 16] = f2bf((xv[j].y - mu) * rs * ln_g[cf + 16] + ln_b[cf + 16]);
    }
    __syncthreads();

    int lane = tid & 63, wv = tid >> 6;
    int quad = lane >> 4, l15 = lane & 15;
    const f32x4 zero4 = {0.f, 0.f, 0.f, 0.f};

    int m0z = wv * 32;
    f32x4 zacc[2][8];
    #pragma unroll
    for (int mt = 0; mt < 2; ++mt)
        #pragma unroll
        for (int nt = 0; nt < 8; ++nt) zacc[mt][nt] = zero4;
    U16 az[2];
    #pragma unroll
    for (int mt = 0; mt < 2; ++mt)
        az[mt].u = *(const uint4*)&xin_s[(m0z + mt * 16 + l15) * 40 + quad * 8];
    #pragma unroll
    for (int nt = 0; nt < 8; ++nt) {
        U16 bz;
        bz.u = *(const uint4*)&w1t[(nt * 16 + l15) * 32 + quad * 8];
        zacc[0][nt] = MFMA16(az[0].s, bz.s, zacc[0][nt]);
        zacc[1][nt] = MFMA16(az[1].s, bz.s, zacc[1][nt]);
    }
    #pragma unroll
    for (int nt = 0; nt < 8; ++nt) {
        int col = nt * 16 + l15;
        float b1v = b1[col], w2v = w2[col];
        #pragma unroll
        for (int mt = 0; mt < 2; ++mt) {
            #pragma unroll
            for (int r = 0; r < 4; ++r) {
                int row = m0z + mt * 16 + quad * 4 + r;
                float z = zacc[mt][nt][r] + b1v;
                float s = 1.f / (1.f + expf(-z));
                float t = s * (1.f + z * (1.f - s)) * w2v;
                A_s[row * 136 + col] = f2bf(t);
            }
        }
    }

    f32x4 gacc[2][2];
    #pragma unroll
    for (int mt = 0; mt < 2; ++mt)
        #pragma unroll
        for (int nt = 0; nt < 2; ++nt) gacc[mt][nt] = zero4;
    #pragma unroll
    for (int q = 0; q < 4; ++q) {
        U16 ag[2];
        #pragma unroll
        for (int mt = 0; mt < 2; ++mt)
            ag[mt].u = *(const uint4*)&A_s[(m0z + mt * 16 + l15) * 136 + q * 32 + quad * 8];
        #pragma unroll
        for (int nt = 0; nt < 2; ++nt) {
            U16 bg;
            bg.u = *(const uint4*)&w1n[(nt * 16 + l15) * 128 + q * 32 + quad * 8];
            gacc[0][nt] = MFMA16(ag[0].s, bg.s, gacc[0][nt]);
            gacc[1][nt] = MFMA16(ag[1].s, bg.s, gacc[1][nt]);
        }
    }
    #pragma unroll
    for (int mt = 0; mt < 2; ++mt)
        #pragma unroll
        for (int nt = 0; nt < 2; ++nt)
            #pragma unroll
            for (int r = 0; r < 4; ++r)
                g_s[(m0z + mt * 16 + quad * 4 + r) * 40 + nt * 16 + l15] = f2bf(gacc[mt][nt][r]);
    __syncthreads();

    int mh = wv & 1, nh = wv >> 1;
    ushort_t* stage = A_s;
    uint_t xw[4][16];
    uint4 gvp[4];
    float gf[4][8];
    #pragma unroll
    for (int mt = 0; mt < 4; ++mt) {
        int row = mh * 64 + mt * 16 + l15;
        #pragma unroll
        for (int q = 0; q < 4; ++q)
            *(uint4*)&xw[mt][q * 4] = *(const uint4*)&xin_s[row * 40 + q * 8];
        gvp[mt] = *(const uint4*)&g_s[row * 40 + quad * 8];
        expand8(gvp[mt], gf[mt]);
    }

    {   // prestage s=0
        const ushort_t* gp;
        if (wv == 0) {
            gp = B1t + (0 * 16 + (lane & 15)) * 1152 + (lane >> 4) * 8;
            gload_lds16(gp, stage + 0 * 512);
            gp = B1t + (4 * 16 + (lane & 15)) * 1152 + (lane >> 4) * 8;
            gload_lds16(gp, stage + 4 * 512);
        } else if (wv == 1) {
            gp = B1t + (1 * 16 + (lane & 15)) * 1152 + (lane >> 4) * 8;
            gload_lds16(gp, stage + 1 * 512);
            gp = B1t + (5 * 16 + (lane & 15)) * 1152 + (lane >> 4) * 8;
            gload_lds16(gp, stage + 5 * 512);
        } else if (wv == 2) {
            gp = B1t + (2 * 16 + (lane & 15)) * 1152 + (lane >> 4) * 8;
            gload_lds16(gp, stage + 2 * 512);
        } else {
            gp = B1t + (3 * 16 + (lane & 15)) * 1152 + (lane >> 4) * 8;
            gload_lds16(gp, stage + 3 * 512);
        }
    }
    f32x4 acc1[3][4];
    #pragma unroll
    for (int j = 0; j < 3; ++j)
        #pragma unroll
        for (int mt = 0; mt < 4; ++mt) acc1[j][mt] = zero4;
    #pragma unroll
    for (int s = 0; s < 33; ++s) {
        __syncthreads();
        int par = s & 1;
        if (s < 32) {
            int sn = s + 1, pn = sn & 1;
            const ushort_t* gp;
            if (wv == 0) {
                gp = B1t + (0 * 16 + (lane & 15)) * 1152 + sn * 32 + (lane >> 4) * 8;
                gload_lds16(gp, stage + pn * 3072 + 0 * 512);
                gp = B1t + (4 * 16 + (lane & 15)) * 1152 + sn * 32 + (lane >> 4) * 8;
                gload_lds16(gp, stage + pn * 3072 + 4 * 512);
            } else if (wv == 1) {
                gp = B1t + (1 * 16 + (lane & 15)) * 1152 + sn * 32 + (lane >> 4) * 8;
                gload_lds16(gp, stage + pn * 3072 + 1 * 512);
                gp = B1t + (5 * 16 + (lane & 15)) * 1152 + sn * 32 + (lane >> 4) * 8;
                gload_lds16(gp, stage + pn * 3072 + 5 * 512);
            } else if (wv == 2) {
                gp = B1t + (2 * 16 + (lane & 15)) * 1152 + sn * 32 + (lane >> 4) * 8;
                gload_lds16(gp, stage + pn * 3072 + 2 * 512);
            } else {
                gp = B1t + (3 * 16 + (lane & 15)) * 1152 + sn * 32 + (lane >> 4) * 8;
                gload_lds16(gp, stage + pn * 3072 + 3 * 512);
            }
        }
        U16 bfr[3];
        #pragma unroll
        for (int j = 0; j < 3; ++j)
            bfr[j].u = *(const uint4*)&stage[par * 3072 + (nh + 2 * j) * 512 + lane * 8];
        #pragma unroll
        for (int mt = 0; mt < 4; ++mt) {
            U16 a;
            if (s < 32) {
                uint_t u = xw[mt][s >> 1];
                float xs = (s & 1) ? __uint_as_float(u & 0xffff0000u)
                                   : __uint_as_float(u << 16);
                a.u = synth8(gf[mt], xs);
            } else {
                a.u = gvp[mt];
            }
            #pragma unroll
            for (int j = 0; j < 3; ++j)
                acc1[j][mt] = MFMA16(a.s, bfr[j].s, acc1[j][mt]);
        }
    }
    f32x4 um[4];
    #pragma unroll
    for (int mt = 0; mt < 4; ++mt) {
        um[mt] = acc1[0][mt] - acc1[1][mt];
        #pragma unroll
        for (int r = 0; r < 4; ++r)
            pg_s[(mh * 64 + mt * 16 + quad * 4 + r) * 40 + nh * 16 + l15] = f2bf(acc1[2][mt][r]);
    }
    __syncthreads();

    uint4 pgp[4];
    float pgf[4][8];
    #pragma unroll
    for (int mt = 0; mt < 4; ++mt) {
        int row = mh * 64 + mt * 16 + l15;
        pgp[mt] = *(const uint4*)&pg_s[row * 40 + quad * 8];
        expand8(pgp[mt], pgf[mt]);
    }
    {
        if (wv == 2) {
            const ushort_t* gp = B2t + (0 * 16 + (lane & 15)) * 1152 + (lane >> 4) * 8;
            gload_lds16(gp, stage + 0 * 512);
        } else if (wv == 3) {
            const ushort_t* gp = B2t + (1 * 16 + (lane & 15)) * 1152 + (lane >> 4) * 8;
            gload_lds16(gp, stage + 1 * 512);
        }
    }
    f32x4 acc2[4];
    #pragma unroll
    for (int mt = 0; mt < 4; ++mt) acc2[mt] = zero4;
    #pragma unroll
    for (int s = 0; s < 33; ++s) {
        __syncthreads();
        int par = s & 1;
        if (s < 32) {
            int sn = s + 1, pn = sn & 1;
            if (wv == 2) {
                const ushort_t* gp = B2t + (0 * 16 + (lane & 15)) * 1152 + sn * 32 + (lane >> 4) * 8;
                gload_lds16(gp, stage + pn * 3072 + 0 * 512);
            } else if (wv == 3) {
                const ushort_t* gp = B2t + (1 * 16 + (lane & 15)) * 1152 + sn * 32 + (lane >> 4) * 8;
                gload_lds16(gp, stage + pn * 3072 + 1 * 512);
            }
        }
        U16 bfr;
        bfr.u = *(const uint4*)&stage[par * 3072 + nh * 512 + lane * 8];
        #pragma unroll
        for (int mt = 0; mt < 4; ++mt) {
            U16 a;
            if (s < 32) {
                uint_t u = xw[mt][s >> 1];
                float xs = (s & 1) ? __uint_as_float(u & 0xffff0000u)
                                   : __uint_as_float(u << 16);
                a.u = synth8(pgf[mt], xs);
            } else {
                a.u = pgp[mt];
            }
            acc2[mt] = MFMA16(a.s, bfr.s, acc2[mt]);
        }
    }

    __syncthreads();
    float* upd = (float*)&A_s[8192];
    #pragma unroll
    for (int mt = 0; mt < 4; ++mt) {
        int col = nh * 16 + l15;
        #pragma unroll
        for (int r = 0; r < 4; ++r) {
            int row = mh * 64 + mt * 16 + quad * 4 + r;
            float gval = bf2f(g_s[row * 40 + col]);
            upd[row * 33 + col] = um[mt][r] - acc2[mt][r] - 1e-4f * gval;
        }
    }
    __syncthreads();
    float dts = dts_p[0];
    #pragma unroll
    for (int cc = 0; cc < 16; ++cc) {
        int c = half * 16 + cc;
        float2 v = fbase[cc * NPIX];
        float xcv = half ? v.y : v.x;
        out[((size_t)bt * 32 + c) * NPIX + pix0 + p] = xcv + dts * upd[p * 33 + c];
    }
}

extern "C" void kernel_launch(void* const* d_in, const int* in_sizes, int n_in,
                              void* d_out, int out_size, void* d_ws, size_t ws_size,
                              hipStream_t stream) {
    const float* x_real   = (const float*)d_in[0];
    const float* x_imag   = (const float*)d_in[1];
    const float* dt       = (const float*)d_in[2];
    const float* conv_w   = (const float*)d_in[3];
    const float* conv_b   = (const float*)d_in[4];
    const float* spec_re  = (const float*)d_in[5];
    const float* spec_im  = (const float*)d_in[6];
    const float* lam_re   = (const float*)d_in[7];
    const float* lam_im   = (const float*)d_in[8];
    const float* dt_param = (const float*)d_in[9];
    const float* sigma    = (const float*)d_in[10];
    const float* noise_r  = (const float*)d_in[11];
    const float* noise_i  = (const float*)d_in[12];
    const float* ln_g     = (const float*)d_in[13];
    const float* ln_b     = (const float*)d_in[14];
    const float* W1       = (const float*)d_in[15];
    const float* b1       = (const float*)d_in[16];
    const float* w2       = (const float*)d_in[17];
    const float* Jg_W     = (const float*)d_in[19];
    const float* Jg_b     = (const float*)d_in[20];
    const float* Rg_W     = (const float*)d_in[21];
    const float* Rg_b     = (const float*)d_in[22];

    float2* wsA = (float2*)d_ws;              // x1, later final field
    float2* wsB = wsA + 1048576;              // Z spectrum
    float2* wsS = wsB + 1048576;              // assembled spectrum S

    ushort_t* B1t = (ushort_t*)(wsS + 1048576);
    ushort_t* B2t = B1t + 96 * 1152;
    ushort_t* w1n = B2t + 32 * 1152;
    ushort_t* w1t = w1n + 4096;
    float*    dts = (float*)(w1t + 4096);

    k_conv<<<552, 256, 0, stream>>>(x_real, x_imag, conv_w, conv_b, wsA,
                                    Jg_W, Jg_b, Rg_W, Rg_b, W1, dt, dt_param,
                                    B1t, B2t, w1n, w1t, dts);
    k_fft_fwd<<<NIMG, 256, 0, stream>>>(wsA, spec_re, spec_im, wsB);
    k_scan2<<<512, 256, 0, stream>>>(wsB, lam_re, lam_im, dt_param, dt, wsS);
    k_fft_inv<<<NIMG, 256, 0, stream>>>(wsS, noise_r, noise_i, sigma, dts, wsA);
    k_ph<<<512, 256, 0, stream>>>(wsA, ln_g, ln_b, b1, w2, w1n, w1t, B1t, B2t, dts,
                                  (float*)d_out);
}

// Round 6
// 200.999 us; speedup vs baseline: 5.4194x; 1.0634x over previous
//
#include <hip/hip_runtime.h>
#include <math.h>

#define Bb 2
#define Tt 8
#define Cc 16
#define Hh 64
#define Ww 64
#define Dd 32
#define HID 128
#define NPIX 4096
#define NIMG 256   // B*T*C

typedef unsigned short ushort_t;
typedef unsigned int uint_t;
typedef __attribute__((ext_vector_type(8))) short short8;
typedef __attribute__((ext_vector_type(4))) float f32x4;
union U16 { uint4 u; short8 s; };

__device__ __forceinline__ float sp_f(float x) {           // softplus
    return (x > 20.f) ? x : log1pf(expf(x));
}

__device__ __forceinline__ ushort_t f2bf(float f) {        // round-to-nearest-even
    uint_t u = __float_as_uint(f);
    uint_t r = (u + 0x7fffu + ((u >> 16) & 1u)) >> 16;
    return (ushort_t)r;
}
__device__ __forceinline__ float bf2f(ushort_t h) { return __uint_as_float(((uint_t)h) << 16); }

// pack two f32 (truncate) into bf16 pair via v_perm_b32
__device__ __forceinline__ uint_t packbf(float hi, float lo) {
    return __builtin_amdgcn_perm(__float_as_uint(hi), __float_as_uint(lo), 0x07060302u);
}
__device__ __forceinline__ uint4 synth8(const float* gf, float xs) {
    uint4 r;
    r.x = packbf(gf[1] * xs, gf[0] * xs);
    r.y = packbf(gf[3] * xs, gf[2] * xs);
    r.z = packbf(gf[5] * xs, gf[4] * xs);
    r.w = packbf(gf[7] * xs, gf[6] * xs);
    return r;
}
__device__ __forceinline__ void expand8(uint4 v, float* f) {
    f[0] = __uint_as_float(v.x << 16); f[1] = __uint_as_float(v.x & 0xffff0000u);
    f[2] = __uint_as_float(v.y << 16); f[3] = __uint_as_float(v.y & 0xffff0000u);
    f[4] = __uint_as_float(v.z << 16); f[5] = __uint_as_float(v.z & 0xffff0000u);
    f[6] = __uint_as_float(v.w << 16); f[7] = __uint_as_float(v.w & 0xffff0000u);
}

#define MFMA16(a, b, c) __builtin_amdgcn_mfma_f32_16x16x32_bf16((a), (b), (c), 0, 0, 0)

// ---------------- complex helpers + DFT8 ----------------
struct cpx { float r, i; };
__device__ __forceinline__ cpx cadd(cpx a, cpx b) { return {a.r + b.r, a.i + b.i}; }
__device__ __forceinline__ cpx csub(cpx a, cpx b) { return {a.r - b.r, a.i - b.i}; }
__device__ __forceinline__ cpx cmulw(cpx a, float wr, float wi) {
    return {a.r * wr - a.i * wi, a.r * wi + a.i * wr};
}
template<int S>
__device__ __forceinline__ cpx cmulSi(cpx a) {   // a * (S*i)
    return {-(float)S * a.i, (float)S * a.r};
}
template<int S>
__device__ __forceinline__ void dft8(cpx* y) {
    const float C = 0.70710678118654752f;
    cpx t0 = cadd(y[0], y[4]), t1 = csub(y[0], y[4]);
    cpx t2 = cadd(y[2], y[6]), t3 = csub(y[2], y[6]);
    cpx e0 = cadd(t0, t2), e2 = csub(t0, t2);
    cpx t3i = cmulSi<S>(t3);
    cpx e1 = cadd(t1, t3i), e3 = csub(t1, t3i);
    cpx u0 = cadd(y[1], y[5]), u1 = csub(y[1], y[5]);
    cpx u2 = cadd(y[3], y[7]), u3 = csub(y[3], y[7]);
    cpx o0 = cadd(u0, u2), o2 = csub(u0, u2);
    cpx u3i = cmulSi<S>(u3);
    cpx o1 = cadd(u1, u3i), o3 = csub(u1, u3i);
    o1 = cmulw(o1, C, (float)S * C);
    o2 = cmulSi<S>(o2);
    o3 = cmulw(o3, -C, (float)S * C);
    y[0] = cadd(e0, o0); y[4] = csub(e0, o0);
    y[1] = cadd(e1, o1); y[5] = csub(e1, o1);
    y[2] = cadd(e2, o2); y[6] = csub(e2, o2);
    y[3] = cadd(e3, o3); y[7] = csub(e3, o3);
}

// 2D 64x64 radix-8 FFT, 512 threads (one dft8/thread/stage), natural in/out, in-place.
template<int S>
__device__ __forceinline__ void fft2d_r8(float* reM, float* imM,
                                         const float* twr, const float* twi, int tid) {
    int j = tid & 63, g = tid >> 6;     // g in 0..7
    // ---- row pass, stage A (in-place, disjoint per thread) ----
    {
        cpx y[8];
        #pragma unroll
        for (int n1 = 0; n1 < 8; ++n1) {
            int a = j * 65 + n1 * 8 + g;
            y[n1] = {reM[a], imM[a]};
        }
        dft8<S>(y);
        #pragma unroll
        for (int k1 = 0; k1 < 8; ++k1) {
            int m = (g * k1) & 63;
            cpx b = cmulw(y[k1], twr[m], twi[m]);
            int a = j * 65 + k1 * 8 + g;
            reM[a] = b.r; imM[a] = b.i;
        }
    }
    __syncthreads();
    // ---- row pass, stage B (read -> barrier -> write) ----
    {
        cpx y[8];
        #pragma unroll
        for (int n2 = 0; n2 < 8; ++n2) {
            int a = j * 65 + g * 8 + n2;
            y[n2] = {reM[a], imM[a]};
        }
        dft8<S>(y);
        __syncthreads();
        #pragma unroll
        for (int k2 = 0; k2 < 8; ++k2) {
            int a = j * 65 + g + k2 * 8;
            reM[a] = y[k2].r; imM[a] = y[k2].i;
        }
    }
    __syncthreads();
    // ---- column pass, stage A ----
    {
        cpx y[8];
        #pragma unroll
        for (int n1 = 0; n1 < 8; ++n1) {
            int a = (n1 * 8 + g) * 65 + j;
            y[n1] = {reM[a], imM[a]};
        }
        dft8<S>(y);
        #pragma unroll
        for (int k1 = 0; k1 < 8; ++k1) {
            int m = (g * k1) & 63;
            cpx b = cmulw(y[k1], twr[m], twi[m]);
            int a = (k1 * 8 + g) * 65 + j;
            reM[a] = b.r; imM[a] = b.i;
        }
    }
    __syncthreads();
    // ---- column pass, stage B ----
    {
        cpx y[8];
        #pragma unroll
        for (int n2 = 0; n2 < 8; ++n2) {
            int a = (g * 8 + n2) * 65 + j;
            y[n2] = {reM[a], imM[a]};
        }
        dft8<S>(y);
        __syncthreads();
        #pragma unroll
        for (int k2 = 0; k2 < 8; ++k2) {
            int a = (g + k2 * 8) * 65 + j;
            reM[a] = y[k2].r; imM[a] = y[k2].i;
        }
    }
    __syncthreads();
}

// ---------------- K1: conv (blocks 0..511) + weight prep (blocks 512..551) -----------
// B1f fragment order: elem ((s*6+ch)*64+lane)*8+e  (n = ch*16+(lane&15),
// k = s*32+(lane>>4)*8+e; s=32 -> bias rows). B2f: ((s*2+ch)*64+lane)*8+e.
__global__ __launch_bounds__(256)
void k_conv(const float* __restrict__ xr, const float* __restrict__ xi,
            const float* __restrict__ cw, const float* __restrict__ cb,
            float2* __restrict__ x1,
            const float* __restrict__ JW, const float* __restrict__ Jb,
            const float* __restrict__ RW, const float* __restrict__ Rb,
            const float* __restrict__ W1, const float* __restrict__ dtp,
            const float* __restrict__ dt_param,
            ushort_t* __restrict__ B1f, ushort_t* __restrict__ B2f,
            ushort_t* __restrict__ w1n, ushort_t* __restrict__ w1t,
            float* __restrict__ dts_out) {
    __shared__ float sre[Cc][18][18];
    __shared__ float sim[Cc][18][18];
    __shared__ float swt[8 * 16 * 12];
    __shared__ float sb[8];
    int tid = threadIdx.x;
    if (blockIdx.x >= 512) {                   // ---- prep path ----
        const int N1 = 33 * 3072, N2 = 33 * 1024, N3 = 4096;
        int i = (blockIdx.x - 512) * 256 + tid;
        for (; i < N1 + N2 + N3; i += 40 * 256) {
            if (i < N1) {
                int s = i / 3072; int r = i % 3072;
                int ch = r >> 9; int lane = (r >> 3) & 63; int e = i & 7;
                int n = ch * 16 + (lane & 15);
                int k = s * 32 + ((lane >> 4) << 3) + e;
                float v;
                if (k < 1024) {
                    int d = k >> 5, rr = k & 31;
                    if (n < 32)      v = JW[d * 1024 + n * 32 + rr];
                    else if (n < 64) v = JW[d * 1024 + rr * 32 + (n - 32)];
                    else             v = RW[d * 1024 + (n - 64) * 32 + rr];
                } else {
                    int rr = k - 1024;
                    if (n < 32)      v = Jb[n * 32 + rr];
                    else if (n < 64) v = Jb[rr * 32 + (n - 32)];
                    else             v = Rb[(n - 64) * 32 + rr];
                }
                B1f[i] = f2bf(v);
            } else if (i < N1 + N2) {
                int i2 = i - N1;
                int s = i2 / 1024; int r = i2 % 1024;
                int ch = r >> 9; int lane = (r >> 3) & 63; int e = i2 & 7;
                int n = ch * 16 + (lane & 15);
                int k = s * 32 + ((lane >> 4) << 3) + e;
                float v;
                if (k < 1024) {
                    int d = k >> 5, kk = k & 31;
                    v = RW[d * 1024 + kk * 32 + n];
                } else {
                    v = Rb[(k - 1024) * 32 + n];
                }
                B2f[i2] = f2bf(v);
            } else {
                int i3 = i - N1 - N2;
                int d = i3 >> 7, h = i3 & 127;
                ushort_t v = f2bf(W1[i3]);
                w1n[i3] = v;
                w1t[h * 32 + d] = v;
            }
        }
        if (blockIdx.x == 512 && tid == 0) {
            float s = 0.f;
            for (int c = 0; c < Cc; ++c) s += sp_f(dt_param[c]);
            dts_out[0] = dtp[0] * s * (1.f / Cc);
        }
        return;
    }
    // ---- conv path ----
    int blk = blockIdx.x;
    int bt = blk >> 5;
    int sub = blk & 31;
    int tile = sub >> 1, cohalf = sub & 1;
    int ty0 = (tile >> 2) * 16, tx0 = (tile & 3) * 16;
    for (int i = tid; i < 8 * 16 * 9; i += 256) {
        int g = i / 9, k = i % 9;
        swt[g * 12 + k] = cw[cohalf * 8 * 144 + i];
    }
    if (tid < 8) sb[tid] = cb[cohalf * 8 + tid];
    for (int i = tid; i < Cc * 18 * 18; i += 256) {
        int ci = i / 324; int r = i % 324; int y = r / 18, x = r % 18;
        int gy = ty0 + y - 1, gx = tx0 + x - 1;
        float vr = 0.f, vi = 0.f;
        if (gy >= 0 && gy < Hh && gx >= 0 && gx < Ww) {
            int gidx = (bt * Cc + ci) * NPIX + gy * Ww + gx;
            vr = xr[gidx]; vi = xi[gidx];
        }
        sre[ci][y][x] = vr; sim[ci][y][x] = vi;
    }
    __syncthreads();
    int py = tid >> 4, px = tid & 15;
    int gy = ty0 + py, gx = tx0 + px;
    float ar[8], ai[8];
    #pragma unroll
    for (int oc = 0; oc < 8; ++oc) {
        int cg = cohalf * 8 + oc;
        ar[oc] = sre[cg][py + 1][px + 1] + sb[oc];
        ai[oc] = sim[cg][py + 1][px + 1] + sb[oc];
    }
    for (int ci = 0; ci < Cc; ++ci) {
        float nr[9], ni[9];
        #pragma unroll
        for (int dy = 0; dy < 3; ++dy)
            #pragma unroll
            for (int dx = 0; dx < 3; ++dx) {
                nr[dy * 3 + dx] = sre[ci][py + dy][px + dx];
                ni[dy * 3 + dx] = sim[ci][py + dy][px + dx];
            }
        #pragma unroll
        for (int oc = 0; oc < 8; ++oc) {
            const float* wp = &swt[(oc * 16 + ci) * 12];
            float4 w0 = *(const float4*)&wp[0];
            float4 w1 = *(const float4*)&wp[4];
            float w8 = wp[8];
            ar[oc] += w0.x * nr[0] + w0.y * nr[1] + w0.z * nr[2]
                    + w0.w * nr[3] + w1.x * nr[4] + w1.y * nr[5]
                    + w1.z * nr[6] + w1.w * nr[7] + w8 * nr[8];
            ai[oc] += w0.x * ni[0] + w0.y * ni[1] + w0.z * ni[2]
                    + w0.w * ni[3] + w1.x * ni[4] + w1.y * ni[5]
                    + w1.z * ni[6] + w1.w * ni[7] + w8 * ni[8];
        }
    }
    #pragma unroll
    for (int oc = 0; oc < 8; ++oc)
        x1[(bt * Cc + cohalf * 8 + oc) * NPIX + gy * Ww + gx] = make_float2(ar[oc], ai[oc]);
}

// ---------------- K2: X2f = fft2_std(x1) * (1 + filt), 512 threads --------------------
__global__ __launch_bounds__(512)
void k_fft_fwd(const float2* __restrict__ x1,
               const float* __restrict__ spec_re, const float* __restrict__ spec_im,
               float2* __restrict__ X2f) {
    int img = blockIdx.x;
    int c = img % Cc;
    int tid = threadIdx.x;
    __shared__ float re[64 * 65], im[64 * 65];
    __shared__ float twr[64], twi[64];
    if (tid < 64) {
        float ang = -0.098174770424681038798f * (float)tid;  // S=-1
        twr[tid] = cosf(ang); twi[tid] = sinf(ang);
    }
    const float2* src = x1 + (size_t)img * NPIX;
    for (int idx = tid; idx < NPIX; idx += 512) {
        int h = idx >> 6, w = idx & 63;
        float2 v = src[idx];
        re[h * 65 + w] = v.x; im[h * 65 + w] = v.y;
    }
    __syncthreads();
    fft2d_r8<-1>(re, im, twr, twi, tid);
    const float* fr = spec_re + c * NPIX;
    const float* fi = spec_im + c * NPIX;
    float2* dst = X2f + (size_t)img * NPIX;
    for (int idx = tid; idx < NPIX; idx += 512) {
        int h = idx >> 6, w = idx & 63;
        float xr_ = re[h * 65 + w], xi_ = im[h * 65 + w];
        float gr = 1.f + fr[idx], gi = fi[idx];
        dst[idx] = make_float2(xr_ * gr - xi_ * gi, xi_ * gr + xr_ * gi);
    }
}

// ---------------- K3: scan2 — S = Z + z, per-half conj-coeff scan ---------------------
__global__ __launch_bounds__(256)
void k_scan2(const float2* __restrict__ Z,
             const float* __restrict__ lam_re, const float* __restrict__ lam_im,
             const float* __restrict__ dt_param, const float* __restrict__ dtp,
             float2* __restrict__ S) {
    int id = blockIdx.x * 256 + threadIdx.x;      // 131072 = B*C*H*W
    int w = id & 63;
    int c = (id >> 12) & 15;
    int b = id >> 16;
    float dte = dtp[0] * sp_f(dt_param[c]);
    float ea = expf(-sp_f(lam_re[c]) * dte);
    float ph = lam_im[c] * dte;
    float Ar = ea * cosf(ph), Ai = ea * sinf(ph);
    if (w > 32) Ai = -Ai;
    bool sc = (w == 0) || (w == 32);
    int pix = id & (NPIX - 1);
    int base = (b * Tt * Cc + c) * NPIX + pix;
    float s1r = 0.f, s1i = 0.f, s2r = 0.f, s2i = 0.f;
    #pragma unroll
    for (int t = 0; t < Tt; ++t) {
        int idx = base + t * (Cc * NPIX);
        float2 zv = Z[idx];
        float nr = Ar * s1r - Ai * s1i + zv.x;
        float ni = Ar * s1i + Ai * s1r + zv.y;
        s1r = nr; s1i = ni;
        float zr, zi;
        if (sc) {
            nr = Ar * s2r + Ai * s2i + zv.x;
            ni = Ar * s2i - Ai * s2r + zv.y;
            s2r = nr; s2i = ni;
            zr = 0.5f * (s1r + s2r); zi = 0.5f * (s1i + s2i);
        } else { zr = s1r; zi = s1i; }
        S[idx] = make_float2(zv.x + zr, zv.y + zi);
    }
}

// ---------------- K5: field = ifft2_std(S) + noise, 512 threads -----------------------
__global__ __launch_bounds__(512)
void k_fft_inv(const float2* __restrict__ Sp,
               const float* __restrict__ noise_r, const float* __restrict__ noise_i,
               const float* __restrict__ sigma_p, const float* __restrict__ dts_p,
               float2* __restrict__ xf) {
    int img = blockIdx.x; int tid = threadIdx.x;
    __shared__ float re[64 * 65], im[64 * 65];
    __shared__ float twr[64], twi[64];
    if (tid < 64) {
        float ang = 0.098174770424681038798f * (float)tid;   // S=+1
        twr[tid] = cosf(ang); twi[tid] = sinf(ang);
    }
    const float2* src = Sp + (size_t)img * NPIX;
    for (int idx = tid; idx < NPIX; idx += 512) {
        int h = idx >> 6, w = idx & 63;
        float2 v = src[idx];
        re[h * 65 + w] = v.x; im[h * 65 + w] = v.y;
    }
    __syncthreads();
    fft2d_r8<1>(re, im, twr, twi, tid);
    float ns = sigma_p[0] * sqrtf(dts_p[0]);
    const float inv = 1.f / 4096.f;
    float2* dst = xf + (size_t)img * NPIX;
    const float* nr = noise_r + (size_t)img * NPIX;
    const float* ni = noise_i + (size_t)img * NPIX;
    for (int idx = tid; idx < NPIX; idx += 512) {
        int h = idx >> 6, w = idx & 63;
        dst[idx] = make_float2(re[h * 65 + w] * inv + ns * nr[idx],
                               im[h * 65 + w] * inv + ns * ni[idx]);
    }
}

// ---------------- K6: PH layer — M=128/block, barrier-free K-loops, reg prefetch ------
__global__ __launch_bounds__(256, 2)
void k_ph(const float2* __restrict__ field,
          const float* __restrict__ ln_g, const float* __restrict__ ln_b,
          const float* __restrict__ b1, const float* __restrict__ w2,
          const ushort_t* __restrict__ w1n, const ushort_t* __restrict__ w1t,
          const ushort_t* __restrict__ B1f, const ushort_t* __restrict__ B2f,
          const float* __restrict__ dts_p,
          float* __restrict__ out) {
    __shared__ ushort_t xin_s[128 * 40];
    __shared__ ushort_t g_s[128 * 40];
    __shared__ ushort_t pg_s[128 * 40];
    __shared__ ushort_t A_s[128 * 136];    // t bf16; aliased: LN red, upd f32 @byte 16384

    int tid = threadIdx.x;
    int bt = blockIdx.x >> 5;
    int pix0 = (blockIdx.x & 31) << 7;

    int p = tid & 127, half = tid >> 7;
    const float2* fbase = field + ((size_t)bt * 16) * NPIX + pix0 + p;
    float2 xv[8];
    float s1 = 0.f, s2 = 0.f;
    #pragma unroll
    for (int j = 0; j < 8; ++j) {
        xv[j] = fbase[(half * 8 + j) * NPIX];
        s1 += xv[j].x + xv[j].y;
        s2 += xv[j].x * xv[j].x + xv[j].y * xv[j].y;
    }
    float2* red = (float2*)A_s;
    red[p * 2 + half] = make_float2(s1, s2);
    __syncthreads();
    float2 r0 = red[p * 2], r1 = red[p * 2 + 1];
    float mu = (r0.x + r1.x) * 0.03125f;
    float var = (r0.y + r1.y) * 0.03125f - mu * mu;
    float rs = rsqrtf(var + 1e-5f);
    #pragma unroll
    for (int j = 0; j < 8; ++j) {
        int cf = half * 8 + j;
        xin_s[p * 40 + cf]      = f2bf((xv[j].x - mu) * rs * ln_g[cf] + ln_b[cf]);
        xin_s[p * 40 + cf + 16] = f2bf((xv[j].y - mu) * rs * ln_g[cf + 16] + ln_b[cf + 16]);
    }
    __syncthreads();

    int lane = tid & 63, wv = tid >> 6;
    int quad = lane >> 4, l15 = lane & 15;
    const f32x4 zero4 = {0.f, 0.f, 0.f, 0.f};

    // ---- z GEMM: z[128][128] = xin @ W1 (K=32); wave owns rows wv*32..+31 ----
    int m0z = wv * 32;
    f32x4 zacc[2][8];
    #pragma unroll
    for (int mt = 0; mt < 2; ++mt)
        #pragma unroll
        for (int nt = 0; nt < 8; ++nt) zacc[mt][nt] = zero4;
    U16 az[2];
    #pragma unroll
    for (int mt = 0; mt < 2; ++mt)
        az[mt].u = *(const uint4*)&xin_s[(m0z + mt * 16 + l15) * 40 + quad * 8];
    #pragma unroll
    for (int nt = 0; nt < 8; ++nt) {
        U16 bz;
        bz.u = *(const uint4*)&w1t[(nt * 16 + l15) * 32 + quad * 8];
        zacc[0][nt] = MFMA16(az[0].s, bz.s, zacc[0][nt]);
        zacc[1][nt] = MFMA16(az[1].s, bz.s, zacc[1][nt]);
    }
    #pragma unroll
    for (int nt = 0; nt < 8; ++nt) {
        int col = nt * 16 + l15;
        float b1v = b1[col], w2v = w2[col];
        #pragma unroll
        for (int mt = 0; mt < 2; ++mt) {
            #pragma unroll
            for (int r = 0; r < 4; ++r) {
                int row = m0z + mt * 16 + quad * 4 + r;
                float z = zacc[mt][nt][r] + b1v;
                float s = 1.f / (1.f + expf(-z));
                float t = s * (1.f + z * (1.f - s)) * w2v;
                A_s[row * 136 + col] = f2bf(t);
            }
        }
    }

    // ---- g GEMM: g[128][32] = t @ W1^T (K=128), own-wave rows ----
    f32x4 gacc[2][2];
    #pragma unroll
    for (int mt = 0; mt < 2; ++mt)
        #pragma unroll
        for (int nt = 0; nt < 2; ++nt) gacc[mt][nt] = zero4;
    #pragma unroll
    for (int q = 0; q < 4; ++q) {
        U16 ag[2];
        #pragma unroll
        for (int mt = 0; mt < 2; ++mt)
            ag[mt].u = *(const uint4*)&A_s[(m0z + mt * 16 + l15) * 136 + q * 32 + quad * 8];
        #pragma unroll
        for (int nt = 0; nt < 2; ++nt) {
            U16 bg;
            bg.u = *(const uint4*)&w1n[(nt * 16 + l15) * 128 + q * 32 + quad * 8];
            gacc[0][nt] = MFMA16(ag[0].s, bg.s, gacc[0][nt]);
            gacc[1][nt] = MFMA16(ag[1].s, bg.s, gacc[1][nt]);
        }
    }
    #pragma unroll
    for (int mt = 0; mt < 2; ++mt)
        #pragma unroll
        for (int nt = 0; nt < 2; ++nt)
            #pragma unroll
            for (int r = 0; r < 4; ++r)
                g_s[(m0z + mt * 16 + quad * 4 + r) * 40 + nt * 16 + l15] = f2bf(gacc[mt][nt][r]);
    __syncthreads();                      // g_s/xin_s cross-wave visible

    // ---- pass setup: wave = (mh, nh); x rows + g rows register-cached ----
    int mh = wv & 1, nh = wv >> 1;
    const uint4* B1v = (const uint4*)B1f;     // fragment order: (s*6+ch)*64 + lane
    const uint4* B2v = (const uint4*)B2f;     // fragment order: (s*2+ch)*64 + lane
    uint_t xw[4][16];
    uint4 gvp[4];
    float gf[4][8];
    #pragma unroll
    for (int mt = 0; mt < 4; ++mt) {
        int row = mh * 64 + mt * 16 + l15;
        #pragma unroll
        for (int q = 0; q < 4; ++q)
            *(uint4*)&xw[mt][q * 4] = *(const uint4*)&xin_s[row * 40 + q * 8];
        gvp[mt] = *(const uint4*)&g_s[row * 40 + quad * 8];
        expand8(gvp[mt], gf[mt]);
    }

    // ---- pass 1: [Mg | Mt g | Pg] = o @ B1^T, K-steps s=0..32, depth-2 reg prefetch --
    uint4 br[2][3];
    #pragma unroll
    for (int pf = 0; pf < 2; ++pf)
        #pragma unroll
        for (int jj = 0; jj < 3; ++jj)
            br[pf][jj] = B1v[(pf * 6 + nh + 2 * jj) * 64 + lane];
    f32x4 acc1[3][4];
    #pragma unroll
    for (int j = 0; j < 3; ++j)
        #pragma unroll
        for (int mt = 0; mt < 4; ++mt) acc1[j][mt] = zero4;
    #pragma unroll
    for (int s = 0; s < 33; ++s) {
        int cur = s & 1;
        U16 b3[3];
        b3[0].u = br[cur][0]; b3[1].u = br[cur][1]; b3[2].u = br[cur][2];
        #pragma unroll
        for (int mt = 0; mt < 4; ++mt) {
            U16 a;
            if (s < 32) {
                uint_t u = xw[mt][s >> 1];
                float xs = (s & 1) ? __uint_as_float(u & 0xffff0000u)
                                   : __uint_as_float(u << 16);
                a.u = synth8(gf[mt], xs);
            } else {
                a.u = gvp[mt];
            }
            acc1[0][mt] = MFMA16(a.s, b3[0].s, acc1[0][mt]);
            acc1[1][mt] = MFMA16(a.s, b3[1].s, acc1[1][mt]);
            acc1[2][mt] = MFMA16(a.s, b3[2].s, acc1[2][mt]);
        }
        if (s + 2 < 33) {
            #pragma unroll
            for (int jj = 0; jj < 3; ++jj)
                br[cur][jj] = B1v[((s + 2) * 6 + nh + 2 * jj) * 64 + lane];
        }
    }
    f32x4 um[4];
    #pragma unroll
    for (int mt = 0; mt < 4; ++mt) {
        um[mt] = acc1[0][mt] - acc1[1][mt];
        #pragma unroll
        for (int r = 0; r < 4; ++r)
            pg_s[(mh * 64 + mt * 16 + quad * 4 + r) * 40 + nh * 16 + l15] = f2bf(acc1[2][mt][r]);
    }
    __syncthreads();                      // pg_s cross-wave visible

    // ---- pass 2: ptpg = (x (x) pg) @ B2^T, depth-2 reg prefetch ----
    uint4 pgp[4];
    float pgf[4][8];
    #pragma unroll
    for (int mt = 0; mt < 4; ++mt) {
        int row = mh * 64 + mt * 16 + l15;
        pgp[mt] = *(const uint4*)&pg_s[row * 40 + quad * 8];
        expand8(pgp[mt], pgf[mt]);
    }
    uint4 br2[2];
    br2[0] = B2v[(0 * 2 + nh) * 64 + lane];
    br2[1] = B2v[(1 * 2 + nh) * 64 + lane];
    f32x4 acc2[4];
    #pragma unroll
    for (int mt = 0; mt < 4; ++mt) acc2[mt] = zero4;
    #pragma unroll
    for (int s = 0; s < 33; ++s) {
        int cur = s & 1;
        U16 b;
        b.u = br2[cur];
        #pragma unroll
        for (int mt = 0; mt < 4; ++mt) {
            U16 a;
            if (s < 32) {
                uint_t u = xw[mt][s >> 1];
                float xs = (s & 1) ? __uint_as_float(u & 0xffff0000u)
                                   : __uint_as_float(u << 16);
                a.u = synth8(pgf[mt], xs);
            } else {
                a.u = pgp[mt];
            }
            acc2[mt] = MFMA16(a.s, b.s, acc2[mt]);
        }
        if (s + 2 < 33)
            br2[cur] = B2v[((s + 2) * 2 + nh) * 64 + lane];
    }

    // ---- epilogue: upd = um - ptpg - 1e-4 g -> LDS f32, combine + write ----
    __syncthreads();
    float* upd = (float*)&A_s[8192];      // byte offset 16384
    #pragma unroll
    for (int mt = 0; mt < 4; ++mt) {
        int col = nh * 16 + l15;
        #pragma unroll
        for (int r = 0; r < 4; ++r) {
            int row = mh * 64 + mt * 16 + quad * 4 + r;
            float gval = bf2f(g_s[row * 40 + col]);
            upd[row * 33 + col] = um[mt][r] - acc2[mt][r] - 1e-4f * gval;
        }
    }
    __syncthreads();
    float dts = dts_p[0];
    #pragma unroll
    for (int cc = 0; cc < 16; ++cc) {
        int c = half * 16 + cc;
        float2 v = fbase[cc * NPIX];
        float xcv = half ? v.y : v.x;
        out[((size_t)bt * 32 + c) * NPIX + pix0 + p] = xcv + dts * upd[p * 33 + c];
    }
}

extern "C" void kernel_launch(void* const* d_in, const int* in_sizes, int n_in,
                              void* d_out, int out_size, void* d_ws, size_t ws_size,
                              hipStream_t stream) {
    const float* x_real   = (const float*)d_in[0];
    const float* x_imag   = (const float*)d_in[1];
    const float* dt       = (const float*)d_in[2];
    const float* conv_w   = (const float*)d_in[3];
    const float* conv_b   = (const float*)d_in[4];
    const float* spec_re  = (const float*)d_in[5];
    const float* spec_im  = (const float*)d_in[6];
    const float* lam_re   = (const float*)d_in[7];
    const float* lam_im   = (const float*)d_in[8];
    const float* dt_param = (const float*)d_in[9];
    const float* sigma    = (const float*)d_in[10];
    const float* noise_r  = (const float*)d_in[11];
    const float* noise_i  = (const float*)d_in[12];
    const float* ln_g     = (const float*)d_in[13];
    const float* ln_b     = (const float*)d_in[14];
    const float* W1       = (const float*)d_in[15];
    const float* b1       = (const float*)d_in[16];
    const float* w2       = (const float*)d_in[17];
    const float* Jg_W     = (const float*)d_in[19];
    const float* Jg_b     = (const float*)d_in[20];
    const float* Rg_W     = (const float*)d_in[21];
    const float* Rg_b     = (const float*)d_in[22];

    float2* wsA = (float2*)d_ws;              // x1, later final field
    float2* wsB = wsA + 1048576;              // Z spectrum
    float2* wsS = wsB + 1048576;              // assembled spectrum S

    ushort_t* B1f = (ushort_t*)(wsS + 1048576);
    ushort_t* B2f = B1f + 33 * 3072;
    ushort_t* w1n = B2f + 33 * 1024;
    ushort_t* w1t = w1n + 4096;
    float*    dts = (float*)(w1t + 4096);

    k_conv<<<552, 256, 0, stream>>>(x_real, x_imag, conv_w, conv_b, wsA,
                                    Jg_W, Jg_b, Rg_W, Rg_b, W1, dt, dt_param,
                                    B1f, B2f, w1n, w1t, dts);
    k_fft_fwd<<<NIMG, 512, 0, stream>>>(wsA, spec_re, spec_im, wsB);
    k_scan2<<<512, 256, 0, stream>>>(wsB, lam_re, lam_im, dt_param, dt, wsS);
    k_fft_inv<<<NIMG, 512, 0, stream>>>(wsS, noise_r, noise_i, sigma, dts, wsA);
    k_ph<<<512, 256, 0, stream>>>(wsA, ln_g, ln_b, b1, w2, w1n, w1t, B1f, B2f, dts,
                                  (float*)d_out);
}

// Round 7
// 189.392 us; speedup vs baseline: 5.7516x; 1.0613x over previous
//
#include <hip/hip_runtime.h>
#include <math.h>
#include <utility>

#define Bb 2
#define Tt 8
#define Cc 16
#define Hh 64
#define Ww 64
#define Dd 32
#define HID 128
#define NPIX 4096
#define NIMG 256   // B*T*C

typedef unsigned short ushort_t;
typedef unsigned int uint_t;
typedef __attribute__((ext_vector_type(8))) short short8;
typedef __attribute__((ext_vector_type(4))) float f32x4;
union U16 { uint4 u; short8 s; };

__device__ __forceinline__ float sp_f(float x) {           // softplus
    return (x > 20.f) ? x : log1pf(expf(x));
}

__device__ __forceinline__ ushort_t f2bf(float f) {        // round-to-nearest-even
    uint_t u = __float_as_uint(f);
    uint_t r = (u + 0x7fffu + ((u >> 16) & 1u)) >> 16;
    return (ushort_t)r;
}
__device__ __forceinline__ float bf2f(ushort_t h) { return __uint_as_float(((uint_t)h) << 16); }

// pack two f32 (truncate) into bf16 pair via v_perm_b32
__device__ __forceinline__ uint_t packbf(float hi, float lo) {
    return __builtin_amdgcn_perm(__float_as_uint(hi), __float_as_uint(lo), 0x07060302u);
}
__device__ __forceinline__ uint4 synth8(const float* gf, float xs) {
    uint4 r;
    r.x = packbf(gf[1] * xs, gf[0] * xs);
    r.y = packbf(gf[3] * xs, gf[2] * xs);
    r.z = packbf(gf[5] * xs, gf[4] * xs);
    r.w = packbf(gf[7] * xs, gf[6] * xs);
    return r;
}
__device__ __forceinline__ void expand8(uint4 v, float* f) {
    f[0] = __uint_as_float(v.x << 16); f[1] = __uint_as_float(v.x & 0xffff0000u);
    f[2] = __uint_as_float(v.y << 16); f[3] = __uint_as_float(v.y & 0xffff0000u);
    f[4] = __uint_as_float(v.z << 16); f[5] = __uint_as_float(v.z & 0xffff0000u);
    f[6] = __uint_as_float(v.w << 16); f[7] = __uint_as_float(v.w & 0xffff0000u);
}

// compile-time-unroll helper: every loop index is a constexpr
template <typename F, int... Is>
__device__ __forceinline__ void unroll_impl(F&& f, std::integer_sequence<int, Is...>) {
    (f(std::integral_constant<int, Is>{}), ...);
}
template <int N, typename F>
__device__ __forceinline__ void cunroll(F&& f) {
    unroll_impl(f, std::make_integer_sequence<int, N>{});
}

#define MFMA16(a, b, c) __builtin_amdgcn_mfma_f32_16x16x32_bf16((a), (b), (c), 0, 0, 0)

// ---------------- complex helpers + DFT8 ----------------
struct cpx { float r, i; };
__device__ __forceinline__ cpx cadd(cpx a, cpx b) { return {a.r + b.r, a.i + b.i}; }
__device__ __forceinline__ cpx csub(cpx a, cpx b) { return {a.r - b.r, a.i - b.i}; }
__device__ __forceinline__ cpx cmulw(cpx a, float wr, float wi) {
    return {a.r * wr - a.i * wi, a.r * wi + a.i * wr};
}
template<int S>
__device__ __forceinline__ cpx cmulSi(cpx a) {   // a * (S*i)
    return {-(float)S * a.i, (float)S * a.r};
}
template<int S>
__device__ __forceinline__ void dft8(cpx* y) {
    const float C = 0.70710678118654752f;
    cpx t0 = cadd(y[0], y[4]), t1 = csub(y[0], y[4]);
    cpx t2 = cadd(y[2], y[6]), t3 = csub(y[2], y[6]);
    cpx e0 = cadd(t0, t2), e2 = csub(t0, t2);
    cpx t3i = cmulSi<S>(t3);
    cpx e1 = cadd(t1, t3i), e3 = csub(t1, t3i);
    cpx u0 = cadd(y[1], y[5]), u1 = csub(y[1], y[5]);
    cpx u2 = cadd(y[3], y[7]), u3 = csub(y[3], y[7]);
    cpx o0 = cadd(u0, u2), o2 = csub(u0, u2);
    cpx u3i = cmulSi<S>(u3);
    cpx o1 = cadd(u1, u3i), o3 = csub(u1, u3i);
    o1 = cmulw(o1, C, (float)S * C);
    o2 = cmulSi<S>(o2);
    o3 = cmulw(o3, -C, (float)S * C);
    y[0] = cadd(e0, o0); y[4] = csub(e0, o0);
    y[1] = cadd(e1, o1); y[5] = csub(e1, o1);
    y[2] = cadd(e2, o2); y[6] = csub(e2, o2);
    y[3] = cadd(e3, o3); y[7] = csub(e3, o3);
}

// 2D 64x64 radix-8 FFT, 512 threads (one dft8/thread/stage), natural in/out, in-place.
template<int S>
__device__ __forceinline__ void fft2d_r8(float* reM, float* imM,
                                         const float* twr, const float* twi, int tid) {
    int j = tid & 63, g = tid >> 6;     // g in 0..7
    {   // row pass, stage A
        cpx y[8];
        #pragma unroll
        for (int n1 = 0; n1 < 8; ++n1) {
            int a = j * 65 + n1 * 8 + g;
            y[n1] = {reM[a], imM[a]};
        }
        dft8<S>(y);
        #pragma unroll
        for (int k1 = 0; k1 < 8; ++k1) {
            int m = (g * k1) & 63;
            cpx b = cmulw(y[k1], twr[m], twi[m]);
            int a = j * 65 + k1 * 8 + g;
            reM[a] = b.r; imM[a] = b.i;
        }
    }
    __syncthreads();
    {   // row pass, stage B
        cpx y[8];
        #pragma unroll
        for (int n2 = 0; n2 < 8; ++n2) {
            int a = j * 65 + g * 8 + n2;
            y[n2] = {reM[a], imM[a]};
        }
        dft8<S>(y);
        __syncthreads();
        #pragma unroll
        for (int k2 = 0; k2 < 8; ++k2) {
            int a = j * 65 + g + k2 * 8;
            reM[a] = y[k2].r; imM[a] = y[k2].i;
        }
    }
    __syncthreads();
    {   // column pass, stage A
        cpx y[8];
        #pragma unroll
        for (int n1 = 0; n1 < 8; ++n1) {
            int a = (n1 * 8 + g) * 65 + j;
            y[n1] = {reM[a], imM[a]};
        }
        dft8<S>(y);
        #pragma unroll
        for (int k1 = 0; k1 < 8; ++k1) {
            int m = (g * k1) & 63;
            cpx b = cmulw(y[k1], twr[m], twi[m]);
            int a = (k1 * 8 + g) * 65 + j;
            reM[a] = b.r; imM[a] = b.i;
        }
    }
    __syncthreads();
    {   // column pass, stage B
        cpx y[8];
        #pragma unroll
        for (int n2 = 0; n2 < 8; ++n2) {
            int a = (g * 8 + n2) * 65 + j;
            y[n2] = {reM[a], imM[a]};
        }
        dft8<S>(y);
        __syncthreads();
        #pragma unroll
        for (int k2 = 0; k2 < 8; ++k2) {
            int a = (g + k2 * 8) * 65 + j;
            reM[a] = y[k2].r; imM[a] = y[k2].i;
        }
    }
    __syncthreads();
}

// ---------------- K1: conv (blocks 0..511) + weight prep (blocks 512..551) -----------
// B1f fragment order: elem ((s*6+ch)*64+lane)*8+e  (n = ch*16+(lane&15),
// k = s*32+(lane>>4)*8+e; s=32 -> bias rows). B2f: ((s*2+ch)*64+lane)*8+e.
__global__ __launch_bounds__(256)
void k_conv(const float* __restrict__ xr, const float* __restrict__ xi,
            const float* __restrict__ cw, const float* __restrict__ cb,
            float2* __restrict__ x1,
            const float* __restrict__ JW, const float* __restrict__ Jb,
            const float* __restrict__ RW, const float* __restrict__ Rb,
            const float* __restrict__ W1, const float* __restrict__ dtp,
            const float* __restrict__ dt_param,
            ushort_t* __restrict__ B1f, ushort_t* __restrict__ B2f,
            ushort_t* __restrict__ w1n, ushort_t* __restrict__ w1t,
            float* __restrict__ dts_out) {
    __shared__ float sre[Cc][18][18];
    __shared__ float sim[Cc][18][18];
    __shared__ float swt[8 * 16 * 12];
    __shared__ float sb[8];
    int tid = threadIdx.x;
    if (blockIdx.x >= 512) {                   // ---- prep path ----
        const int N1 = 33 * 3072, N2 = 33 * 1024, N3 = 4096;
        int i = (blockIdx.x - 512) * 256 + tid;
        for (; i < N1 + N2 + N3; i += 40 * 256) {
            if (i < N1) {
                int s = i / 3072; int r = i % 3072;
                int ch = r >> 9; int lane = (r >> 3) & 63; int e = i & 7;
                int n = ch * 16 + (lane & 15);
                int k = s * 32 + ((lane >> 4) << 3) + e;
                float v;
                if (k < 1024) {
                    int d = k >> 5, rr = k & 31;
                    if (n < 32)      v = JW[d * 1024 + n * 32 + rr];
                    else if (n < 64) v = JW[d * 1024 + rr * 32 + (n - 32)];
                    else             v = RW[d * 1024 + (n - 64) * 32 + rr];
                } else {
                    int rr = k - 1024;
                    if (n < 32)      v = Jb[n * 32 + rr];
                    else if (n < 64) v = Jb[rr * 32 + (n - 32)];
                    else             v = Rb[(n - 64) * 32 + rr];
                }
                B1f[i] = f2bf(v);
            } else if (i < N1 + N2) {
                int i2 = i - N1;
                int s = i2 / 1024; int r = i2 % 1024;
                int ch = r >> 9; int lane = (r >> 3) & 63; int e = i2 & 7;
                int n = ch * 16 + (lane & 15);
                int k = s * 32 + ((lane >> 4) << 3) + e;
                float v;
                if (k < 1024) {
                    int d = k >> 5, kk = k & 31;
                    v = RW[d * 1024 + kk * 32 + n];
                } else {
                    v = Rb[(k - 1024) * 32 + n];
                }
                B2f[i2] = f2bf(v);
            } else {
                int i3 = i - N1 - N2;
                int d = i3 >> 7, h = i3 & 127;
                ushort_t v = f2bf(W1[i3]);
                w1n[i3] = v;
                w1t[h * 32 + d] = v;
            }
        }
        if (blockIdx.x == 512 && tid == 0) {
            float s = 0.f;
            for (int c = 0; c < Cc; ++c) s += sp_f(dt_param[c]);
            dts_out[0] = dtp[0] * s * (1.f / Cc);
        }
        return;
    }
    // ---- conv path ----
    int blk = blockIdx.x;
    int bt = blk >> 5;
    int sub = blk & 31;
    int tile = sub >> 1, cohalf = sub & 1;
    int ty0 = (tile >> 2) * 16, tx0 = (tile & 3) * 16;
    for (int i = tid; i < 8 * 16 * 9; i += 256) {
        int g = i / 9, k = i % 9;
        swt[g * 12 + k] = cw[cohalf * 8 * 144 + i];
    }
    if (tid < 8) sb[tid] = cb[cohalf * 8 + tid];
    for (int i = tid; i < Cc * 18 * 18; i += 256) {
        int ci = i / 324; int r = i % 324; int y = r / 18, x = r % 18;
        int gy = ty0 + y - 1, gx = tx0 + x - 1;
        float vr = 0.f, vi = 0.f;
        if (gy >= 0 && gy < Hh && gx >= 0 && gx < Ww) {
            int gidx = (bt * Cc + ci) * NPIX + gy * Ww + gx;
            vr = xr[gidx]; vi = xi[gidx];
        }
        sre[ci][y][x] = vr; sim[ci][y][x] = vi;
    }
    __syncthreads();
    int py = tid >> 4, px = tid & 15;
    int gy = ty0 + py, gx = tx0 + px;
    float ar[8], ai[8];
    #pragma unroll
    for (int oc = 0; oc < 8; ++oc) {
        int cg = cohalf * 8 + oc;
        ar[oc] = sre[cg][py + 1][px + 1] + sb[oc];
        ai[oc] = sim[cg][py + 1][px + 1] + sb[oc];
    }
    for (int ci = 0; ci < Cc; ++ci) {
        float nr[9], ni[9];
        #pragma unroll
        for (int dy = 0; dy < 3; ++dy)
            #pragma unroll
            for (int dx = 0; dx < 3; ++dx) {
                nr[dy * 3 + dx] = sre[ci][py + dy][px + dx];
                ni[dy * 3 + dx] = sim[ci][py + dy][px + dx];
            }
        #pragma unroll
        for (int oc = 0; oc < 8; ++oc) {
            const float* wp = &swt[(oc * 16 + ci) * 12];
            float4 w0 = *(const float4*)&wp[0];
            float4 w1 = *(const float4*)&wp[4];
            float w8 = wp[8];
            ar[oc] += w0.x * nr[0] + w0.y * nr[1] + w0.z * nr[2]
                    + w0.w * nr[3] + w1.x * nr[4] + w1.y * nr[5]
                    + w1.z * nr[6] + w1.w * nr[7] + w8 * nr[8];
            ai[oc] += w0.x * ni[0] + w0.y * ni[1] + w0.z * ni[2]
                    + w0.w * ni[3] + w1.x * ni[4] + w1.y * ni[5]
                    + w1.z * ni[6] + w1.w * ni[7] + w8 * ni[8];
        }
    }
    #pragma unroll
    for (int oc = 0; oc < 8; ++oc)
        x1[(bt * Cc + cohalf * 8 + oc) * NPIX + gy * Ww + gx] = make_float2(ar[oc], ai[oc]);
}

// ---------------- K2: X2f = fft2_std(x1) * (1 + filt), 512 threads --------------------
__global__ __launch_bounds__(512)
void k_fft_fwd(const float2* __restrict__ x1,
               const float* __restrict__ spec_re, const float* __restrict__ spec_im,
               float2* __restrict__ X2f) {
    int img = blockIdx.x;
    int c = img % Cc;
    int tid = threadIdx.x;
    __shared__ float re[64 * 65], im[64 * 65];
    __shared__ float twr[64], twi[64];
    if (tid < 64) {
        float ang = -0.098174770424681038798f * (float)tid;  // S=-1
        twr[tid] = cosf(ang); twi[tid] = sinf(ang);
    }
    const float2* src = x1 + (size_t)img * NPIX;
    for (int idx = tid; idx < NPIX; idx += 512) {
        int h = idx >> 6, w = idx & 63;
        float2 v = src[idx];
        re[h * 65 + w] = v.x; im[h * 65 + w] = v.y;
    }
    __syncthreads();
    fft2d_r8<-1>(re, im, twr, twi, tid);
    const float* fr = spec_re + c * NPIX;
    const float* fi = spec_im + c * NPIX;
    float2* dst = X2f + (size_t)img * NPIX;
    for (int idx = tid; idx < NPIX; idx += 512) {
        int h = idx >> 6, w = idx & 63;
        float xr_ = re[h * 65 + w], xi_ = im[h * 65 + w];
        float gr = 1.f + fr[idx], gi = fi[idx];
        dst[idx] = make_float2(xr_ * gr - xi_ * gi, xi_ * gr + xr_ * gi);
    }
}

// ---------------- K3: scan2 — S = Z + z, per-half conj-coeff scan ---------------------
__global__ __launch_bounds__(256)
void k_scan2(const float2* __restrict__ Z,
             const float* __restrict__ lam_re, const float* __restrict__ lam_im,
             const float* __restrict__ dt_param, const float* __restrict__ dtp,
             float2* __restrict__ S) {
    int id = blockIdx.x * 256 + threadIdx.x;      // 131072 = B*C*H*W
    int w = id & 63;
    int c = (id >> 12) & 15;
    int b = id >> 16;
    float dte = dtp[0] * sp_f(dt_param[c]);
    float ea = expf(-sp_f(lam_re[c]) * dte);
    float ph = lam_im[c] * dte;
    float Ar = ea * cosf(ph), Ai = ea * sinf(ph);
    if (w > 32) Ai = -Ai;
    bool sc = (w == 0) || (w == 32);
    int pix = id & (NPIX - 1);
    int base = (b * Tt * Cc + c) * NPIX + pix;
    float s1r = 0.f, s1i = 0.f, s2r = 0.f, s2i = 0.f;
    #pragma unroll
    for (int t = 0; t < Tt; ++t) {
        int idx = base + t * (Cc * NPIX);
        float2 zv = Z[idx];
        float nr = Ar * s1r - Ai * s1i + zv.x;
        float ni = Ar * s1i + Ai * s1r + zv.y;
        s1r = nr; s1i = ni;
        float zr, zi;
        if (sc) {
            nr = Ar * s2r + Ai * s2i + zv.x;
            ni = Ar * s2i - Ai * s2r + zv.y;
            s2r = nr; s2i = ni;
            zr = 0.5f * (s1r + s2r); zi = 0.5f * (s1i + s2i);
        } else { zr = s1r; zi = s1i; }
        S[idx] = make_float2(zv.x + zr, zv.y + zi);
    }
}

// ---------------- K5: field = ifft2_std(S) + noise, 512 threads -----------------------
__global__ __launch_bounds__(512)
void k_fft_inv(const float2* __restrict__ Sp,
               const float* __restrict__ noise_r, const float* __restrict__ noise_i,
               const float* __restrict__ sigma_p, const float* __restrict__ dts_p,
               float2* __restrict__ xf) {
    int img = blockIdx.x; int tid = threadIdx.x;
    __shared__ float re[64 * 65], im[64 * 65];
    __shared__ float twr[64], twi[64];
    if (tid < 64) {
        float ang = 0.098174770424681038798f * (float)tid;   // S=+1
        twr[tid] = cosf(ang); twi[tid] = sinf(ang);
    }
    const float2* src = Sp + (size_t)img * NPIX;
    for (int idx = tid; idx < NPIX; idx += 512) {
        int h = idx >> 6, w = idx & 63;
        float2 v = src[idx];
        re[h * 65 + w] = v.x; im[h * 65 + w] = v.y;
    }
    __syncthreads();
    fft2d_r8<1>(re, im, twr, twi, tid);
    float ns = sigma_p[0] * sqrtf(dts_p[0]);
    const float inv = 1.f / 4096.f;
    float2* dst = xf + (size_t)img * NPIX;
    const float* nr = noise_r + (size_t)img * NPIX;
    const float* ni = noise_i + (size_t)img * NPIX;
    for (int idx = tid; idx < NPIX; idx += 512) {
        int h = idx >> 6, w = idx & 63;
        dst[idx] = make_float2(re[h * 65 + w] * inv + ns * nr[idx],
                               im[h * 65 + w] * inv + ns * ni[idx]);
    }
}

// ---------------- K6: PH layer — wave-independent K loops, template-unrolled ----------
// Wave wv owns rows wv*32..+31 (2 m-tiles), all 6 N-chunks. No dynamic private-array
// indexing anywhere: the per-step x scalar comes from LDS at a constexpr offset.
__global__ __launch_bounds__(256, 2)
void k_ph(const float2* __restrict__ field,
          const float* __restrict__ ln_g, const float* __restrict__ ln_b,
          const float* __restrict__ b1, const float* __restrict__ w2,
          const ushort_t* __restrict__ w1n, const ushort_t* __restrict__ w1t,
          const ushort_t* __restrict__ B1f, const ushort_t* __restrict__ B2f,
          const float* __restrict__ dts_p,
          float* __restrict__ out) {
    __shared__ ushort_t xin_s[128 * 40];
    __shared__ ushort_t g_s[128 * 40];
    __shared__ ushort_t pg_s[128 * 40];
    __shared__ ushort_t A_s[128 * 136] __attribute__((aligned(16)));

    int tid = threadIdx.x;
    int bt = blockIdx.x >> 5;
    int pix0 = (blockIdx.x & 31) << 7;

    int p = tid & 127, half = tid >> 7;
    const float2* fbase = field + ((size_t)bt * 16) * NPIX + pix0 + p;
    float2 xv[8];
    float s1 = 0.f, s2 = 0.f;
    #pragma unroll
    for (int j = 0; j < 8; ++j) {
        xv[j] = fbase[(half * 8 + j) * NPIX];
        s1 += xv[j].x + xv[j].y;
        s2 += xv[j].x * xv[j].x + xv[j].y * xv[j].y;
    }
    float2* red = (float2*)A_s;
    red[p * 2 + half] = make_float2(s1, s2);
    __syncthreads();
    float2 r0 = red[p * 2], r1 = red[p * 2 + 1];
    float mu = (r0.x + r1.x) * 0.03125f;
    float var = (r0.y + r1.y) * 0.03125f - mu * mu;
    float rs = rsqrtf(var + 1e-5f);
    #pragma unroll
    for (int j = 0; j < 8; ++j) {
        int cf = half * 8 + j;
        xin_s[p * 40 + cf]      = f2bf((xv[j].x - mu) * rs * ln_g[cf] + ln_b[cf]);
        xin_s[p * 40 + cf + 16] = f2bf((xv[j].y - mu) * rs * ln_g[cf + 16] + ln_b[cf + 16]);
    }
    __syncthreads();

    int lane = tid & 63, wv = tid >> 6;
    int quad = lane >> 4, l15 = lane & 15;
    const f32x4 zero4 = {0.f, 0.f, 0.f, 0.f};
    int m0 = wv * 32;

    // ---- z GEMM: z[rows m0..m0+31][128] = xin @ W1 (K=32) ----
    f32x4 zacc[2][8];
    #pragma unroll
    for (int mt = 0; mt < 2; ++mt)
        #pragma unroll
        for (int nt = 0; nt < 8; ++nt) zacc[mt][nt] = zero4;
    U16 az[2];
    #pragma unroll
    for (int mt = 0; mt < 2; ++mt)
        az[mt].u = *(const uint4*)&xin_s[(m0 + mt * 16 + l15) * 40 + quad * 8];
    #pragma unroll
    for (int nt = 0; nt < 8; ++nt) {
        U16 bz;
        bz.u = *(const uint4*)&w1t[(nt * 16 + l15) * 32 + quad * 8];
        zacc[0][nt] = MFMA16(az[0].s, bz.s, zacc[0][nt]);
        zacc[1][nt] = MFMA16(az[1].s, bz.s, zacc[1][nt]);
    }
    #pragma unroll
    for (int nt = 0; nt < 8; ++nt) {
        int col = nt * 16 + l15;
        float b1v = b1[col], w2v = w2[col];
        #pragma unroll
        for (int mt = 0; mt < 2; ++mt) {
            #pragma unroll
            for (int r = 0; r < 4; ++r) {
                int row = m0 + mt * 16 + quad * 4 + r;
                float z = zacc[mt][nt][r] + b1v;
                float s = 1.f / (1.f + expf(-z));
                float t = s * (1.f + z * (1.f - s)) * w2v;
                A_s[row * 136 + col] = f2bf(t);
            }
        }
    }
    __syncthreads();

    // ---- g GEMM: g[rows][32] = t @ W1^T (K=128) ----
    f32x4 gacc[2][2];
    #pragma unroll
    for (int mt = 0; mt < 2; ++mt)
        #pragma unroll
        for (int nt = 0; nt < 2; ++nt) gacc[mt][nt] = zero4;
    #pragma unroll
    for (int q = 0; q < 4; ++q) {
        U16 ag[2];
        #pragma unroll
        for (int mt = 0; mt < 2; ++mt)
            ag[mt].u = *(const uint4*)&A_s[(m0 + mt * 16 + l15) * 136 + q * 32 + quad * 8];
        #pragma unroll
        for (int nt = 0; nt < 2; ++nt) {
            U16 bg;
            bg.u = *(const uint4*)&w1n[(nt * 16 + l15) * 128 + q * 32 + quad * 8];
            gacc[0][nt] = MFMA16(ag[0].s, bg.s, gacc[0][nt]);
            gacc[1][nt] = MFMA16(ag[1].s, bg.s, gacc[1][nt]);
        }
    }
    #pragma unroll
    for (int mt = 0; mt < 2; ++mt)
        #pragma unroll
        for (int nt = 0; nt < 2; ++nt)
            #pragma unroll
            for (int r = 0; r < 4; ++r)
                g_s[(m0 + mt * 16 + quad * 4 + r) * 40 + nt * 16 + l15] = f2bf(gacc[mt][nt][r]);
    __syncthreads();

    // ---- K-loop setup: LDS row pointers (constexpr per-step offsets), g in regs ----
    const ushort_t* xr0 = &xin_s[(m0 + l15) * 40];
    const ushort_t* xr1 = &xin_s[(m0 + 16 + l15) * 40];
    uint4 gvp0 = *(const uint4*)&g_s[(m0 + l15) * 40 + quad * 8];
    uint4 gvp1 = *(const uint4*)&g_s[(m0 + 16 + l15) * 40 + quad * 8];
    float gf0[8], gf1[8];
    expand8(gvp0, gf0);
    expand8(gvp1, gf1);
    const uint4* B1v = (const uint4*)B1f;
    const uint4* B2v = (const uint4*)B2f;

    // ---- pass 1: [Mg | Mt g | Pg](96 cols) = o @ B1^T, s=0..32 (32 = bias step) ----
    uint4 br[2][6];
    #pragma unroll
    for (int pf = 0; pf < 2; ++pf)
        #pragma unroll
        for (int ch = 0; ch < 6; ++ch)
            br[pf][ch] = B1v[(pf * 6 + ch) * 64 + lane];
    f32x4 acc1[6][2];
    #pragma unroll
    for (int ch = 0; ch < 6; ++ch) { acc1[ch][0] = zero4; acc1[ch][1] = zero4; }
    cunroll<33>([&](auto Sc) {
        constexpr int s = Sc.value;
        constexpr int cur = s & 1;
        U16 a0, a1;
        if constexpr (s < 32) {
            float x0 = bf2f(xr0[s]);
            float x1 = bf2f(xr1[s]);
            a0.u = synth8(gf0, x0);
            a1.u = synth8(gf1, x1);
        } else {
            a0.u = gvp0; a1.u = gvp1;
        }
        #pragma unroll
        for (int ch = 0; ch < 6; ++ch) {
            U16 b; b.u = br[cur][ch];
            acc1[ch][0] = MFMA16(a0.s, b.s, acc1[ch][0]);
            acc1[ch][1] = MFMA16(a1.s, b.s, acc1[ch][1]);
        }
        if constexpr (s + 2 < 33) {
            #pragma unroll
            for (int ch = 0; ch < 6; ++ch)
                br[cur][ch] = B1v[((s + 2) * 6 + ch) * 64 + lane];
        }
    });
    // Pg -> pg_s (own rows)
    #pragma unroll
    for (int mt = 0; mt < 2; ++mt)
        #pragma unroll
        for (int c2 = 0; c2 < 2; ++c2)
            #pragma unroll
            for (int r = 0; r < 4; ++r)
                pg_s[(m0 + mt * 16 + quad * 4 + r) * 40 + c2 * 16 + l15] =
                    f2bf(acc1[4 + c2][mt][r]);
    __syncthreads();

    // ---- pass 2: ptpg(32 cols) = (x (x) pg) @ B2^T ----
    uint4 pgp0 = *(const uint4*)&pg_s[(m0 + l15) * 40 + quad * 8];
    uint4 pgp1 = *(const uint4*)&pg_s[(m0 + 16 + l15) * 40 + quad * 8];
    float pgf0[8], pgf1[8];
    expand8(pgp0, pgf0);
    expand8(pgp1, pgf1);
    uint4 br2[2][2];
    #pragma unroll
    for (int pf = 0; pf < 2; ++pf) {
        br2[pf][0] = B2v[(pf * 2 + 0) * 64 + lane];
        br2[pf][1] = B2v[(pf * 2 + 1) * 64 + lane];
    }
    f32x4 acc2[2][2];
    acc2[0][0] = zero4; acc2[0][1] = zero4; acc2[1][0] = zero4; acc2[1][1] = zero4;
    cunroll<33>([&](auto Sc) {
        constexpr int s = Sc.value;
        constexpr int cur = s & 1;
        U16 a0, a1;
        if constexpr (s < 32) {
            float x0 = bf2f(xr0[s]);
            float x1 = bf2f(xr1[s]);
            a0.u = synth8(pgf0, x0);
            a1.u = synth8(pgf1, x1);
        } else {
            a0.u = pgp0; a1.u = pgp1;
        }
        #pragma unroll
        for (int ch = 0; ch < 2; ++ch) {
            U16 b; b.u = br2[cur][ch];
            acc2[ch][0] = MFMA16(a0.s, b.s, acc2[ch][0]);
            acc2[ch][1] = MFMA16(a1.s, b.s, acc2[ch][1]);
        }
        if constexpr (s + 2 < 33) {
            br2[cur][0] = B2v[((s + 2) * 2 + 0) * 64 + lane];
            br2[cur][1] = B2v[((s + 2) * 2 + 1) * 64 + lane];
        }
    });

    // ---- epilogue: upd = (Mg - Mtg) - ptpg - 1e-4 g -> LDS f32, combine + write ----
    __syncthreads();
    float* upd = (float*)A_s;
    #pragma unroll
    for (int mt = 0; mt < 2; ++mt) {
        #pragma unroll
        for (int c2 = 0; c2 < 2; ++c2) {
            int col = c2 * 16 + l15;
            #pragma unroll
            for (int r = 0; r < 4; ++r) {
                int row = m0 + mt * 16 + quad * 4 + r;
                float gval = bf2f(g_s[row * 40 + col]);
                upd[row * 33 + col] = (acc1[c2][mt][r] - acc1[c2 + 2][mt][r])
                                      - acc2[c2][mt][r] - 1e-4f * gval;
            }
        }
    }
    __syncthreads();
    float dts = dts_p[0];
    #pragma unroll
    for (int cc = 0; cc < 16; ++cc) {
        int c = half * 16 + cc;
        float2 v = fbase[cc * NPIX];
        float xcv = half ? v.y : v.x;
        out[((size_t)bt * 32 + c) * NPIX + pix0 + p] = xcv + dts * upd[p * 33 + c];
    }
}

extern "C" void kernel_launch(void* const* d_in, const int* in_sizes, int n_in,
                              void* d_out, int out_size, void* d_ws, size_t ws_size,
                              hipStream_t stream) {
    const float* x_real   = (const float*)d_in[0];
    const float* x_imag   = (const float*)d_in[1];
    const float* dt       = (const float*)d_in[2];
    const float* conv_w   = (const float*)d_in[3];
    const float* conv_b   = (const float*)d_in[4];
    const float* spec_re  = (const float*)d_in[5];
    const float* spec_im  = (const float*)d_in[6];
    const float* lam_re   = (const float*)d_in[7];
    const float* lam_im   = (const float*)d_in[8];
    const float* dt_param = (const float*)d_in[9];
    const float* sigma    = (const float*)d_in[10];
    const float* noise_r  = (const float*)d_in[11];
    const float* noise_i  = (const float*)d_in[12];
    const float* ln_g     = (const float*)d_in[13];
    const float* ln_b     = (const float*)d_in[14];
    const float* W1       = (const float*)d_in[15];
    const float* b1       = (const float*)d_in[16];
    const float* w2       = (const float*)d_in[17];
    const float* Jg_W     = (const float*)d_in[19];
    const float* Jg_b     = (const float*)d_in[20];
    const float* Rg_W     = (const float*)d_in[21];
    const float* Rg_b     = (const float*)d_in[22];

    float2* wsA = (float2*)d_ws;              // x1, later final field
    float2* wsB = wsA + 1048576;              // Z spectrum
    float2* wsS = wsB + 1048576;              // assembled spectrum S

    ushort_t* B1f = (ushort_t*)(wsS + 1048576);
    ushort_t* B2f = B1f + 33 * 3072;
    ushort_t* w1n = B2f + 33 * 1024;
    ushort_t* w1t = w1n + 4096;
    float*    dts = (float*)(w1t + 4096);

    k_conv<<<552, 256, 0, stream>>>(x_real, x_imag, conv_w, conv_b, wsA,
                                    Jg_W, Jg_b, Rg_W, Rg_b, W1, dt, dt_param,
                                    B1f, B2f, w1n, w1t, dts);
    k_fft_fwd<<<NIMG, 512, 0, stream>>>(wsA, spec_re, spec_im, wsB);
    k_scan2<<<512, 256, 0, stream>>>(wsB, lam_re, lam_im, dt_param, dt, wsS);
    k_fft_inv<<<NIMG, 512, 0, stream>>>(wsS, noise_r, noise_i, sigma, dts, wsA);
    k_ph<<<512, 256, 0, stream>>>(wsA, ln_g, ln_b, b1, w2, w1n, w1t, B1f, B2f, dts,
                                  (float*)d_out);
}